// Round 12
// baseline (797.868 us; speedup 1.0000x reference)
//
#include <hip/hip_runtime.h>

// ============================================================================
// numpy RNG replication: SeedSequence + PCG64 (XSL-RR 128/64), next32 buffering
// ============================================================================
struct U128 { unsigned long long hi, lo; };

__device__ __forceinline__ U128 u128_mul(U128 a, U128 b) {
  U128 r;
  r.lo = a.lo * b.lo;
  r.hi = __umul64hi(a.lo, b.lo) + a.hi * b.lo + a.lo * b.hi;
  return r;
}
__device__ __forceinline__ U128 u128_add(U128 a, U128 b) {
  U128 r; r.lo = a.lo + b.lo; r.hi = a.hi + b.hi + (r.lo < a.lo ? 1ull : 0ull); return r;
}

struct Pcg64 {
  U128 state, inc;
};

__device__ __forceinline__ void pcg_step(Pcg64* r) {
  const U128 M = {0x2360ed051fc65da4ull, 0x4385df649fccf645ull};
  r->state = u128_add(u128_mul(r->state, M), r->inc);
}
__device__ __forceinline__ unsigned long long pcg_next64(Pcg64* r) {
  pcg_step(r);
  unsigned int rot = (unsigned int)(r->state.hi >> 58);   // state >> 122
  unsigned long long x = r->state.hi ^ r->state.lo;       // XSL
  return (x >> rot) | (x << ((64u - rot) & 63u));         // RR
}

// SeedSequence constants (numpy bit_generator.pyx)
__device__ __forceinline__ unsigned int ss_hashmix(unsigned int v, unsigned int* hc) {
  v ^= *hc; *hc = *hc * 0x931e8875u; v *= *hc; v ^= v >> 16; return v;
}
__device__ __forceinline__ unsigned int ss_mix(unsigned int x, unsigned int y) {
  unsigned int r = x * 0xca01f9ddu ^ y * 0x4973f715u; r ^= r >> 16; return r;
}
__device__ void pcg_seed(Pcg64* rng, unsigned int seed) {
  unsigned int pool[4]; unsigned int hc = 0x43b0d7e5u;   // INIT_A
  pool[0] = ss_hashmix(seed, &hc);
  for (int i = 1; i < 4; ++i) pool[i] = ss_hashmix(0u, &hc);
  for (int s = 0; s < 4; ++s)
    for (int d = 0; d < 4; ++d)
      if (s != d) pool[d] = ss_mix(pool[d], ss_hashmix(pool[s], &hc));
  unsigned int hc2 = 0x8b51f9ddu;                        // INIT_B
  unsigned long long w64[4];
  for (int i = 0; i < 4; ++i) {
    unsigned int lo = pool[(2*i) & 3];
    lo ^= hc2; hc2 *= 0x58f38dedu; lo *= hc2; lo ^= lo >> 16;
    unsigned int hi = pool[(2*i+1) & 3];
    hi ^= hc2; hc2 *= 0x58f38dedu; hi *= hc2; hi ^= hi >> 16;
    w64[i] = (unsigned long long)lo | ((unsigned long long)hi << 32);
  }
  U128 initstate = {w64[0], w64[1]};   // PCG_128BIT_CONSTANT(seed[0], seed[1]): [0] is HIGH
  U128 initseq   = {w64[2], w64[3]};
  rng->inc.hi = (initseq.hi << 1) | (initseq.lo >> 63);
  rng->inc.lo = (initseq.lo << 1) | 1ull;
  rng->state.hi = 0; rng->state.lo = 0;
  pcg_step(rng);
  rng->state = u128_add(rng->state, initstate);
  pcg_step(rng);
}

// affine jump-ahead: state <- A^delta * state + (A^delta-1)/(A-1)*inc
__device__ void pcg_advance(Pcg64* r, unsigned long long delta) {
  U128 acc_mult = {0ull, 1ull}, acc_plus = {0ull, 0ull};
  U128 cur_mult = {0x2360ed051fc65da4ull, 0x4385df649fccf645ull};
  U128 cur_plus = r->inc;
  while (delta) {
    if (delta & 1ull) {
      acc_mult = u128_mul(acc_mult, cur_mult);
      acc_plus = u128_add(u128_mul(acc_plus, cur_mult), cur_plus);
    }
    U128 one = {0ull, 1ull};
    U128 cm1 = u128_add(cur_mult, one);
    cur_plus = u128_mul(cm1, cur_plus);
    cur_mult = u128_mul(cur_mult, cur_mult);
    delta >>= 1;
  }
  r->state = u128_add(u128_mul(r->state, acc_mult), acc_plus);
}

// ============================================================================
// Problem constants
// ============================================================================
#define S_LEN   16384
#define Q_LEN   65536
#define Q_TOT   327680     // 5*65536
#define DFEAT   256
#define MAXS    256
#define CAPS64  24576
#define CAPQ64  98304
#define TILE    4096
#define STILES  (S_LEN / TILE)    // 4
#define QTILES  (Q_TOT / TILE)    // 80
#define NBLK_C  (5 * STILES + 5 * QTILES)   // 420
#define MSHARDS 8
#define MPASSES 8

// meta layout: [0..4]=ns_full, [5..9]=nq_full, [10..14]=na, [15..19]=nb

__constant__ int c_kshift[MPASSES] = {27, 23, 19, 15, 11, 7, 3, 0};

// ============================================================================
// K0: parallel draw-stream generation (exact numpy next32 sequence, lo first)
// ============================================================================
__global__ __launch_bounds__(256) void k_draws(unsigned int* __restrict__ draws) {
  int t = blockIdx.x; int cls = t % 5; int isq = t / 5;
  unsigned int seed = (unsigned)(1000 + isq * 1000 + cls + 1);
  unsigned long long cap64 = isq ? CAPQ64 : CAPS64;
  unsigned int* dst = draws + (isq ? (10ull * CAPS64 + (unsigned long long)cls * 2 * CAPQ64)
                                   : ((unsigned long long)cls * 2 * CAPS64));
  Pcg64 rng; pcg_seed(&rng, seed);
  int tid = threadIdx.x;
  unsigned long long C = cap64 / 256ull;     // 96 or 384
  unsigned long long k0 = (unsigned long long)tid * C;
  pcg_advance(&rng, k0);
  uint2* d2 = (uint2*)dst;
  for (unsigned long long m = 0; m < C; ++m) {
    unsigned long long o = pcg_next64(&rng);
    d2[k0 + m] = make_uint2((unsigned int)o, (unsigned int)(o >> 32));
  }
}

// ============================================================================
// K1a: per-tile match counts
// ============================================================================
__global__ __launch_bounds__(256) void k_count(const int* __restrict__ ls,
                                               const int* __restrict__ lq,
                                               int* __restrict__ cnts) {
  int b = blockIdx.x;
  const int* src; int matchval;
  if (b < 5 * STILES) {
    int cls = b / STILES, tl = b % STILES;
    src = ls + cls * S_LEN + tl * TILE; matchval = 1;
  } else {
    int bb = b - 5 * STILES; int cls = bb / QTILES, tl = bb % QTILES;
    src = lq + tl * TILE; matchval = cls + 1;
  }
  int tid = threadIdx.x;
  int cnt = 0;
  for (int k = 0; k < TILE; k += 256) cnt += (src[k + tid] == matchval) ? 1 : 0;
  __shared__ int red[256];
  red[tid] = cnt; __syncthreads();
  for (int s = 128; s > 0; s >>= 1) { if (tid < s) red[tid] += red[tid + s]; __syncthreads(); }
  if (tid == 0) cnts[b] = red[0];
}

// ============================================================================
// K1b: tiny scan: exclusive offsets per class + meta totals
// ============================================================================
__global__ void k_scan(const int* __restrict__ cnts, int* __restrict__ offs,
                       int* __restrict__ meta) {
  int t = threadIdx.x;
  if (t < 5) {
    int base = 0;
    for (int k = 0; k < STILES; ++k) {
      offs[t * STILES + k] = base; base += cnts[t * STILES + k];
    }
    meta[t] = base;
    meta[10 + t] = base < MAXS ? base : MAXS;
  } else if (t < 10) {
    int c = t - 5; int base = 0;
    for (int k = 0; k < QTILES; ++k) {
      int idx = 5 * STILES + c * QTILES + k;
      offs[idx] = base; base += cnts[idx];
    }
    meta[5 + c] = base;
    meta[15 + c] = base < MAXS ? base : MAXS;
  }
}

// ============================================================================
// K1c: stable compaction write at per-tile offsets (4-wave ballot prefix)
// ============================================================================
__global__ __launch_bounds__(256) void k_write(const int* __restrict__ ls,
                                               const int* __restrict__ lq,
                                               const int* __restrict__ offs,
                                               int* __restrict__ sup_list,
                                               int* __restrict__ qry_list) {
  int b = blockIdx.x;
  const int* src; int matchval; int* out; int ibase;
  if (b < 5 * STILES) {
    int cls = b / STILES, tl = b % STILES;
    src = ls + cls * S_LEN + tl * TILE; matchval = 1;
    out = sup_list + cls * S_LEN; ibase = tl * TILE;
  } else {
    int bb = b - 5 * STILES; int cls = bb / QTILES, tl = bb % QTILES;
    src = lq + tl * TILE; matchval = cls + 1;
    out = qry_list + (size_t)cls * Q_TOT; ibase = tl * TILE;
  }
  int tid = threadIdx.x; int w = tid >> 6, lane = tid & 63;
  unsigned long long lmask = (1ull << lane) - 1ull;
  __shared__ int wcnt[4];
  int base = offs[b];
  for (int k = 0; k < TILE; k += 256) {
    int i = k + tid;
    bool p = (src[i] == matchval);
    unsigned long long m = __ballot(p);
    if (lane == 0) wcnt[w] = __popcll(m);
    __syncthreads();
    int prev = 0;
    #pragma unroll
    for (int ww = 0; ww < 4; ++ww) prev += (ww < w) ? wcnt[ww] : 0;
    int tot = wcnt[0] + wcnt[1] + wcnt[2] + wcnt[3];
    if (p) out[base + prev + __popcll(m & lmask)] = ibase + i;
    __syncthreads();
    base += tot;
  }
}

// ============================================================================
// K2: BLOCK-WIDE (256-draw) masked-rejection automaton, interval-commit.
//     4 waves cooperate: per round, each wave ballots {def_rej, hard} into
//     LDS; all threads combine the 4x64-bit masks (named u64 regs, no
//     dynamic indexing). Lowest uncertain lane always resolves -> <=256
//     rounds, provably exact. Accepts staged in 8192-entry LDS ring
//     (gapless descending il), flushed 4096 at a time (coalesced).
//     Depth-4 outer prefetch (1024 draws/iter).
// ============================================================================
__global__ __launch_bounds__(256) void k_consume(const int* __restrict__ meta,
                                                 const unsigned int* __restrict__ draws,
                                                 int* Jsup, int* Jqry) {
  __shared__ unsigned long long bal[2][4];
  __shared__ unsigned int ring[8192];
  int t = blockIdx.x; int cls = t % 5; int isq = t / 5;
  int n = meta[isq * 5 + cls];
  if (n <= MAXS) return;
  const unsigned int* d = draws + (isq ? (10ull * CAPS64 + (unsigned long long)cls * 2 * CAPQ64)
                                       : ((unsigned long long)cls * 2 * CAPS64));
  int* J = isq ? (Jqry + (size_t)cls * Q_TOT) : (Jsup + cls * S_LEN);
  int tid = threadIdx.x;
  int w = tid >> 6, lane = tid & 63;
  unsigned long long lbit = 1ull << lane;
  unsigned long long lmask_w = lbit - 1ull;
  int i = n - 1;
  size_t p = 0;
  int flushed = 0;
  const int cap = n - MAXS;

  // one 256-draw step; returns true when done (accepts reached n-256)
  auto step256 = [&](unsigned int v) -> bool {
    unsigned long long r0 = 0, r1 = 0, r2 = 0, r3 = 0;
    unsigned long long a0 = 0, a1 = 0, a2 = 0, a3 = 0;
    for (;;) {
      unsigned long long u0 = ~(r0 | a0), u1 = ~(r1 | a1);
      unsigned long long u2 = ~(r2 | a2), u3 = ~(r3 | a3);
      unsigned long long myR = (w == 0) ? r0 : (w == 1) ? r1 : (w == 2) ? r2 : r3;
      unsigned long long myU = (w == 0) ? u0 : (w == 1) ? u1 : (w == 2) ? u2 : u3;
      int rb = __popcll(myR & lmask_w)
             + ((w > 0) ? __popcll(r0) : 0)
             + ((w > 1) ? __popcll(r1) : 0)
             + ((w > 2) ? __popcll(r2) : 0);
      int ub = __popcll(myU & lmask_w)
             + ((w > 0) ? __popcll(u0) : 0)
             + ((w > 1) ? __popcll(u1) : 0)
             + ((w > 2) ? __popcll(u2) : 0);
      bool unres = (myU & lbit) != 0ull;
      int il_min = i - tid + rb;               // >= 1 always (i >= 256 at step start)
      int il_max = il_min + ub;
      unsigned int mlo = 0xFFFFFFFFu >> __clz(il_min);
      unsigned int mhi = 0xFFFFFFFFu >> __clz(il_max);
      unsigned int wv = v & mlo;
      bool def_rej, hard;
      if (mlo == mhi) {
        def_rej = wv > (unsigned int)il_max;
        hard = !def_rej && (wv > (unsigned int)il_min);   // middle band
      } else if (ub == 0) {                    // octave boundary: exact resolve
        def_rej = wv > (unsigned int)il_min;
        hard = false;
      } else {
        def_rej = false;
        hard = true;                           // boundary-spanning, wait
      }
      def_rej = def_rej && unres;
      hard = hard && unres;
      unsigned long long wnr = __ballot(def_rej);
      unsigned long long whd = __ballot(hard);
      if (lane == 0) { bal[0][w] = wnr; bal[1][w] = whd; }
      __syncthreads();
      unsigned long long n0 = bal[0][0], n1 = bal[0][1], n2 = bal[0][2], n3 = bal[0][3];
      unsigned long long h0 = bal[1][0], h1 = bal[1][1], h2 = bal[1][2], h3 = bal[1][3];
      __syncthreads();                          // LDS slots reusable next round
      r0 |= n0; r1 |= n1; r2 |= n2; r3 |= n3;
      a0 |= u0 & ~n0 & ~h0; a1 |= u1 & ~n1 & ~h1;
      a2 |= u2 & ~n2 & ~h2; a3 |= u3 & ~n3 & ~h3;
      if (!(h0 | h1 | h2 | h3)) break;
    }
    unsigned long long myR = (w == 0) ? r0 : (w == 1) ? r1 : (w == 2) ? r2 : r3;
    unsigned long long myA = (w == 0) ? a0 : (w == 1) ? a1 : (w == 2) ? a2 : a3;
    int rbf = __popcll(myR & lmask_w)
            + ((w > 0) ? __popcll(r0) : 0)
            + ((w > 1) ? __popcll(r1) : 0)
            + ((w > 2) ? __popcll(r2) : 0);
    int il = i - tid + rbf;
    int totAcc = 256 - (__popcll(r0) + __popcll(r1) + __popcll(r2) + __popcll(r3));
    if ((myA & lbit) && il >= MAXS) {
      int g = (n - 1) - il;
      ring[g & 8191] = v & (0xFFFFFFFFu >> __clz(il));
    }
    int needed = i - (MAXS - 1);
    if (totAcc >= needed) return true;
    i -= totAcc;
    return false;
  };

  unsigned int v0 = d[tid],        v1 = d[256 + tid];
  unsigned int v2 = d[512 + tid],  v3 = d[768 + tid];
  for (;;) {
    unsigned int nv0 = d[p + 1024 + tid];
    unsigned int nv1 = d[p + 1280 + tid];
    unsigned int nv2 = d[p + 1536 + tid];
    unsigned int nv3 = d[p + 1792 + tid];
    bool done;
    if      (step256(v0)) done = true;
    else if (step256(v1)) done = true;
    else if (step256(v2)) done = true;
    else if (step256(v3)) done = true;
    else done = false;
    if (done) break;
    // flush full 4096-entry blocks (coalesced descending J)
    int avail = (n - 1) - i; if (avail > cap) avail = cap;
    while (avail - flushed >= 4096) {
      __syncthreads();
      #pragma unroll
      for (int k = 0; k < 16; ++k) {
        int g = flushed + k * 256 + tid;
        J[(n - 1) - g] = (int)ring[g & 8191];
      }
      flushed += 4096;
    }
    p += 1024;
    v0 = nv0; v1 = nv1; v2 = nv2; v3 = nv3;
  }
  // final flush: every il in [256, n-1] has been staged
  __syncthreads();
  for (int g = flushed + tid; g < cap; g += 256)
    J[(n - 1) - g] = (int)ring[g & 8191];
}

// ============================================================================
// K3a: next-hitter index fill.  H[v] = min{ i > v, i in [256,n) : J[i] == v }
// ============================================================================
__global__ __launch_bounds__(256) void k_hfill(const int* __restrict__ meta,
                                               const int* __restrict__ Jsup,
                                               const int* __restrict__ Jqry,
                                               unsigned int* __restrict__ Hsup,
                                               unsigned int* __restrict__ Hqry) {
  const int SB = 5 * (S_LEN / 256);
  int b = blockIdx.x;
  int cls, i; const int* J; unsigned int* H; int n;
  if (b < SB) {
    cls = b / (S_LEN / 256);
    i = (b % (S_LEN / 256)) * 256 + threadIdx.x;
    n = meta[cls];
    J = Jsup + cls * S_LEN; H = Hsup + cls * S_LEN;
  } else {
    b -= SB;
    cls = b / (Q_TOT / 256);
    i = (b % (Q_TOT / 256)) * 256 + threadIdx.x;
    n = meta[5 + cls];
    J = Jqry + (size_t)cls * Q_TOT; H = Hqry + (size_t)cls * Q_TOT;
  }
  if (i < MAXS || i >= n) return;
  int j = J[i];
  if (j != i) atomicMin(&H[j], (unsigned int)i);
}

// ============================================================================
// K3b: chase.  sel[t][s] = list[ c(s) ]
// ============================================================================
__global__ __launch_bounds__(256) void k_chase(const int* __restrict__ meta,
                                               const int* __restrict__ sup_list,
                                               const int* __restrict__ qry_list,
                                               const unsigned int* __restrict__ Hsup,
                                               const unsigned int* __restrict__ Hqry,
                                               int* sel) {
  int t = blockIdx.x; int tid = threadIdx.x;
  int cls = t % 5; int isq = t / 5;
  int n = meta[isq * 5 + cls];
  const int* list; const unsigned int* H;
  if (!isq) { list = sup_list + cls * S_LEN; H = Hsup + cls * S_LEN; }
  else      { list = qry_list + (size_t)cls * Q_TOT; H = Hqry + (size_t)cls * Q_TOT; }
  int* s = sel + t * MAXS;
  if (n <= MAXS) { if (tid < n) s[tid] = list[tid]; return; }
  unsigned int v = (unsigned int)tid;
  unsigned int h = H[v];
  while (h != 0xFFFFFFFFu) { v = h; h = H[v]; }
  s[tid] = list[v];
}

// ============================================================================
// K4: gather selected feature rows + fused row-norm (x / (||x|| + 1e-12)).
// ============================================================================
__global__ __launch_bounds__(256) void k_gather(const float* __restrict__ f_s,
                                                const float* __restrict__ f_q,
                                                const int* __restrict__ meta,
                                                const int* __restrict__ sel,
                                                float* xa, float* xb) {
  int blk = blockIdx.x;
  int t = blk >> 3;          // class-pair 0..9
  int slab = blk & 7;        // 8 slabs x 32 rows
  int cls = t % 5; int isq = t / 5;
  int n = meta[10 + isq * 5 + cls];
  int tid = threadIdx.x;
  int row = slab * 32 + (tid >> 3);
  int dg = tid & 7;          // 8 d-groups of 32
  if (row >= n) return;      // group-uniform (8 lanes share row)
  int id = sel[t * MAXS + row];
  const float* src; size_t stride; float* dst;
  if (!isq) {
    src = f_s + (size_t)cls * DFEAT * S_LEN + id; stride = S_LEN;
    dst = xa + cls * (MAXS * DFEAT) + row * DFEAT;
  } else {
    int m = id >> 16; int nn = id & 0xFFFF;
    src = f_q + (size_t)m * DFEAT * Q_LEN + nn; stride = Q_LEN;
    dst = xb + cls * (MAXS * DFEAT) + row * DFEAT;
  }
  float v[32];
  #pragma unroll
  for (int dd = 0; dd < 32; ++dd)
    v[dd] = src[(size_t)(dg * 32 + dd) * stride];
  float ss = 0.f;
  #pragma unroll
  for (int dd = 0; dd < 32; ++dd) ss += v[dd] * v[dd];
  ss += __shfl_xor(ss, 1);
  ss += __shfl_xor(ss, 2);
  ss += __shfl_xor(ss, 4);
  float inv = 1.0f / (sqrtf(ss) + 1e-12f);
  #pragma unroll
  for (int dd = 0; dd < 32; ++dd) dst[dg * 32 + dd] = v[dd] * inv;
}

// ============================================================================
// K5: 35 Gram matrices (256x256, K=256), 128x128 tiles -> 140 blocks.
// ============================================================================
__global__ __launch_bounds__(256) void k_gram(const float* __restrict__ xa,
                                              const float* __restrict__ xb,
                                              float* Ga, float* Gb, float* Gab) {
  int b = blockIdx.x;
  int j = b >> 2; int tile = b & 3;
  int tr = (tile >> 1) * 128, tc = (tile & 1) * 128;
  const float *A, *B; float* G;
  if (j < 5)       { A = xa + j * 65536; B = A; G = Ga + j * 65536; }
  else if (j < 10) { int c = j - 5; A = xb + c * 65536; B = A; G = Gb + c * 65536; }
  else             { int p = j - 10; int k = p / 5, c = p % 5;
                     A = xa + k * 65536; B = xb + c * 65536; G = Gab + p * 65536; }
  __shared__ float As[128][33];
  __shared__ float Bs[128][33];
  int tid = threadIdx.x;
  int w = tid >> 6, lane = tid & 63;
  int wr = w >> 1, wc = w & 1;
  int lr = lane >> 3, lc = lane & 7;
  int orow = wr * 64 + lr * 8;     // within-tile output row base
  int ocol = wc * 64 + lc * 8;     // within-tile output col base
  float acc[8][8];
  #pragma unroll
  for (int r = 0; r < 8; ++r)
    #pragma unroll
    for (int s = 0; s < 8; ++s) acc[r][s] = 0.f;

  for (int k0 = 0; k0 < 256; k0 += 32) {
    #pragma unroll
    for (int e = 0; e < 4; ++e) {
      int idx = tid + e * 256;          // 0..1023
      int row = idx >> 3;               // 0..127
      int c4  = idx & 7;                // float4 slot in 32-k chunk
      float4 va = *(const float4*)(A + (size_t)(tr + row) * 256 + k0 + c4 * 4);
      As[row][c4 * 4 + 0] = va.x; As[row][c4 * 4 + 1] = va.y;
      As[row][c4 * 4 + 2] = va.z; As[row][c4 * 4 + 3] = va.w;
      float4 vb = *(const float4*)(B + (size_t)(tc + row) * 256 + k0 + c4 * 4);
      Bs[row][c4 * 4 + 0] = vb.x; Bs[row][c4 * 4 + 1] = vb.y;
      Bs[row][c4 * 4 + 2] = vb.z; Bs[row][c4 * 4 + 3] = vb.w;
    }
    __syncthreads();
    #pragma unroll 4
    for (int kk = 0; kk < 32; ++kk) {
      float a[8], bv[8];
      #pragma unroll
      for (int r = 0; r < 8; ++r) a[r] = As[orow + r][kk];
      #pragma unroll
      for (int s = 0; s < 8; ++s) bv[s] = Bs[ocol + s][kk];
      #pragma unroll
      for (int r = 0; r < 8; ++r)
        #pragma unroll
        for (int s = 0; s < 8; ++s) acc[r][s] += a[r] * bv[s];
    }
    __syncthreads();
  }
  #pragma unroll
  for (int r = 0; r < 8; ++r) {
    float* grow = G + (size_t)(tr + orow + r) * 256 + tc + ocol;
    *(float4*)(grow + 0) = make_float4(acc[r][0], acc[r][1], acc[r][2], acc[r][3]);
    *(float4*)(grow + 4) = make_float4(acc[r][4], acc[r][5], acc[r][6], acc[r][7]);
  }
}

// ============================================================================
// K6: extract Gram diagonals
// ============================================================================
__global__ __launch_bounds__(256) void k_diag(const float* __restrict__ Ga,
                                              const float* __restrict__ Gb,
                                              float* diagA, float* diagB) {
  int t = blockIdx.x; int i = threadIdx.x;
  if (t < 5) diagA[t * 256 + i] = Ga[t * 65536 + i * 257];
  else { int c = t - 5; diagB[c * 256 + i] = Gb[c * 65536 + i * 257]; }
}

// ============================================================================
// K7: G -> D in place (280 blocks: 35 matrices x 8 row-slabs)
// ============================================================================
__global__ __launch_bounds__(256) void k_conv(float* Ga, float* Gb, float* Gab,
                                              const float* __restrict__ diagA,
                                              const float* __restrict__ diagB) {
  int b = blockIdx.x; int j = b >> 3; int slab = b & 7; int tid = threadIdx.x;
  float* G; const float *dA, *dB;
  if (j < 5)       { G = Ga + j * 65536; dA = diagA + j * 256; dB = dA; }
  else if (j < 10) { int c = j - 5; G = Gb + c * 65536; dA = diagB + c * 256; dB = dA; }
  else             { int p = j - 10; int k = p / 5, c = p % 5;
                     G = Gab + p * 65536; dA = diagA + k * 256; dB = diagB + c * 256; }
  float db = dB[tid];
  for (int i = slab * 32; i < slab * 32 + 32; ++i) {
    float g = G[i * 256 + tid];
    float d = dA[i] + db - 2.0f * g;
    G[i * 256 + tid] = d > 0.f ? d : 0.f;
  }
}

// ============================================================================
// K8: grid-parallel 16-ary exact radix-select, one kernel per pass.
// ============================================================================
__device__ __forceinline__ void med_select(const unsigned int* __restrict__ c,
                                           unsigned int lprev, unsigned int bprev,
                                           unsigned int r, int kprev,
                                           unsigned int* lo, unsigned int* base) {
  int j = 15;
  #pragma unroll
  for (int q = 14; q >= 0; --q)
    if (bprev + c[q] > r) j = q;
  *lo = lprev + ((unsigned int)j << kprev);
  *base = (j == 0) ? bprev : bprev + c[j - 1];
}

__global__ __launch_bounds__(256) void k_medpass(int t,
                                                 const int* __restrict__ meta,
                                                 const float* __restrict__ Da_all,
                                                 const float* __restrict__ Db_all,
                                                 const float* __restrict__ Dab_all,
                                                 unsigned int* __restrict__ bufAll,  // [MPASSES][25][16]
                                                 unsigned int* __restrict__ loArr,   // [MPASSES][25]
                                                 unsigned int* __restrict__ baseArr, // [MPASSES][25]
                                                 unsigned int* __restrict__ zcArr) { // [25]
  int b = blockIdx.x;
  int p = b / MSHARDS, sh = b % MSHARDS;
  int kcl = p / 5, ccl = p % 5;
  int tid = threadIdx.x;
  int nsf = meta[kcl], nqf = meta[5 + ccl];
  if (nsf < 2 || nqf < 2) return;
  int na = meta[10 + kcl], nb = meta[15 + ccl];
  const float4* A4 = (const float4*)(Da_all + kcl * 65536);
  const float4* B4 = (const float4*)(Db_all + ccl * 65536);
  const float4* C4 = (const float4*)(Dab_all + p * 65536);

  __shared__ unsigned int sh_lo[1], sh_base[1];
  __shared__ unsigned int wred[4][16];
  __shared__ unsigned int wzc[4];

  int ks = c_kshift[t];
  unsigned int N = (unsigned int)(na + nb) * (unsigned int)(na + nb);

  if (tid == 0) {
    unsigned int lo = 0, base = 0;
    if (t > 0) {
      unsigned int nz = zcArr[p];
      if (nz < N) {
        unsigned int r = nz + (N - nz - 1u) / 2u;
        unsigned int cprev[15];
        const unsigned int* cp = bufAll + ((size_t)(t - 1) * 25 + p) * 16;
        #pragma unroll
        for (int q = 0; q < 15; ++q) cprev[q] = cp[q];
        med_select(cprev, loArr[(t - 1) * 25 + p], baseArr[(t - 1) * 25 + p],
                   r, c_kshift[t - 1], &lo, &base);
      }
    }
    sh_lo[0] = lo; sh_base[0] = base;
    if (sh == 0) { loArr[t * 25 + p] = lo; baseArr[t * 25 + p] = base; }
  }
  __syncthreads();
  unsigned int lo = sh_lo[0];

  unsigned int cnt[15];
  #pragma unroll
  for (int j = 0; j < 15; ++j) cnt[j] = 0;
  unsigned int zc = 0;
  unsigned int span = 16u << ks;   // ks<=27 -> fits u32 (16<<27 = 2^31)

  #define PROC_MAT(M4, nr, nc, W)                                             \
    for (int m = 0; m < 8; ++m) {                                             \
      int fidx = sh * 2048 + m * 256 + tid;                                   \
      float4 v = M4[fidx];                                                    \
      int row = fidx >> 6; int col0 = (fidx & 63) << 2;                       \
      unsigned int kb[4] = {__float_as_uint(v.x), __float_as_uint(v.y),       \
                            __float_as_uint(v.z), __float_as_uint(v.w)};      \
      _Pragma("unroll")                                                       \
      for (int cc = 0; cc < 4; ++cc) {                                        \
        bool valid = (row < (nr)) && (col0 + cc < (nc));                      \
        unsigned int key = kb[cc];                                            \
        if (t == 0) zc += (valid && key == 0u) ? (W) : 0u;                    \
        unsigned int d = key - lo;                                            \
        bool in = valid && (key >= lo) && (d < span);                         \
        _Pragma("unroll")                                                     \
        for (int j = 0; j < 15; ++j)                                          \
          cnt[j] += (in && d < ((unsigned int)(j + 1) << ks)) ? (W) : 0u;     \
      }                                                                       \
    }

  PROC_MAT(A4, na, na, 1u)
  PROC_MAT(B4, nb, nb, 1u)
  PROC_MAT(C4, na, nb, 2u)
  #undef PROC_MAT

  // wave-level reduce then cross-wave
  #pragma unroll
  for (int j = 0; j < 15; ++j)
    for (int o = 32; o > 0; o >>= 1) cnt[j] += __shfl_down(cnt[j], o);
  if (t == 0)
    for (int o = 32; o > 0; o >>= 1) zc += __shfl_down(zc, o);
  int w = tid >> 6, lane = tid & 63;
  if (lane == 0) {
    #pragma unroll
    for (int j = 0; j < 15; ++j) wred[w][j] = cnt[j];
    wzc[w] = zc;
  }
  __syncthreads();
  if (tid < 15) {
    unsigned int s = wred[0][tid] + wred[1][tid] + wred[2][tid] + wred[3][tid];
    atomicAdd(&bufAll[((size_t)t * 25 + p) * 16 + tid], s);
  }
  if (t == 0 && tid == 15) {
    unsigned int s = wzc[0] + wzc[1] + wzc[2] + wzc[3];
    atomicAdd(&zcArr[p], s);
  }
}

// ============================================================================
// K8b: RBF partial sums (200 blocks), sigma from final select
// ============================================================================
__global__ __launch_bounds__(256) void k_rbf(const int* __restrict__ meta,
                                             const float* __restrict__ Da_all,
                                             const float* __restrict__ Db_all,
                                             const float* __restrict__ Dab_all,
                                             const unsigned int* __restrict__ bufAll,
                                             const unsigned int* __restrict__ loArr,
                                             const unsigned int* __restrict__ baseArr,
                                             const unsigned int* __restrict__ zcArr,
                                             double* __restrict__ mmdsum) { // [25][3]
  int b = blockIdx.x;
  int p = b / MSHARDS, sh = b % MSHARDS;
  int kcl = p / 5, ccl = p % 5;
  int tid = threadIdx.x;
  int nsf = meta[kcl], nqf = meta[5 + ccl];
  if (nsf < 2 || nqf < 2) return;
  int na = meta[10 + kcl], nb = meta[15 + ccl];
  const float4* A4 = (const float4*)(Da_all + kcl * 65536);
  const float4* B4 = (const float4*)(Db_all + ccl * 65536);
  const float4* C4 = (const float4*)(Dab_all + p * 65536);

  unsigned int N = (unsigned int)(na + nb) * (unsigned int)(na + nb);
  unsigned int nz = zcArr[p];
  float base_s;
  if (nz >= N) base_s = 1.0f;
  else {
    unsigned int r = nz + (N - nz - 1u) / 2u;
    unsigned int cprev[15];
    const unsigned int* cp = bufAll + ((size_t)(MPASSES - 1) * 25 + p) * 16;
    #pragma unroll
    for (int q = 0; q < 15; ++q) cprev[q] = cp[q];
    unsigned int lo, bs;
    med_select(cprev, loArr[(MPASSES - 1) * 25 + p], baseArr[(MPASSES - 1) * 25 + p],
               r, 0, &lo, &bs);
    base_s = sqrtf(__uint_as_float(lo) + 1e-6f);
  }
  float g2 = base_s * base_s;
  float c0 = 1.0f / (2.0f * g2 * 0.25f);
  float c1 = 1.0f / (2.0f * g2 * 1.0f);
  float c2 = 1.0f / (2.0f * g2 * 4.0f);
  float c3 = 1.0f / (2.0f * g2 * 16.0f);

  double accA = 0.0, accB = 0.0, accAB = 0.0;
  #define RBF_MAT(M4, nr, nc, ACC)                                            \
    for (int m = 0; m < 8; ++m) {                                             \
      int fidx = sh * 2048 + m * 256 + tid;                                   \
      float4 v = M4[fidx];                                                    \
      int row = fidx >> 6; int col0 = (fidx & 63) << 2;                       \
      float vv[4] = {v.x, v.y, v.z, v.w};                                     \
      _Pragma("unroll")                                                       \
      for (int cc = 0; cc < 4; ++cc) {                                        \
        if ((row < (nr)) && (col0 + cc < (nc))) {                             \
          float d = vv[cc];                                                   \
          ACC += (double)(expf(-d * c0) + expf(-d * c1)                       \
                        + expf(-d * c2) + expf(-d * c3));                     \
        }                                                                     \
      }                                                                       \
    }
  RBF_MAT(A4, na, na, accA)
  RBF_MAT(B4, nb, nb, accB)
  RBF_MAT(C4, na, nb, accAB)
  #undef RBF_MAT

  for (int o = 32; o > 0; o >>= 1) {
    accA += __shfl_down(accA, o);
    accB += __shfl_down(accB, o);
    accAB += __shfl_down(accAB, o);
  }
  __shared__ double wsum[4][3];
  int w = tid >> 6, lane = tid & 63;
  if (lane == 0) { wsum[w][0] = accA; wsum[w][1] = accB; wsum[w][2] = accAB; }
  __syncthreads();
  if (tid == 0) {
    double sA = wsum[0][0] + wsum[1][0] + wsum[2][0] + wsum[3][0];
    double sB = wsum[0][1] + wsum[1][1] + wsum[2][1] + wsum[3][1];
    double sC = wsum[0][2] + wsum[1][2] + wsum[2][2] + wsum[3][2];
    atomicAdd(&mmdsum[p * 3 + 0], sA);
    atomicAdd(&mmdsum[p * 3 + 1], sB);
    atomicAdd(&mmdsum[p * 3 + 2], sC);
  }
}

// ============================================================================
// K9: final weighted loss (mmd assembled from sums)
// ============================================================================
__global__ void k_final(const int* __restrict__ meta, const double* __restrict__ mmdsum,
                        float* out) {
  if (threadIdx.x != 0 || blockIdx.x != 0) return;
  double total = 0.0, vw = 0.0;
  for (int c = 0; c < 5; ++c) {
    int nsf = meta[c], nqf = meta[5 + c];
    if (nsf < 2 || nqf < 2) continue;
    int nbq = meta[15 + c];
    double mm[5];
    for (int k = 0; k < 5; ++k) {
      if (meta[k] < 2) { mm[k] = 0.0; continue; }
      int naa = meta[10 + k];
      int pp = k * 5 + c;
      double meanA  = mmdsum[pp * 3 + 0] / ((double)naa * (double)naa);
      double meanB  = mmdsum[pp * 3 + 1] / ((double)nbq * (double)nbq);
      double meanAB = mmdsum[pp * 3 + 2] / ((double)naa * (double)nbq);
      double m = meanA + meanB - 2.0 * meanAB;
      mm[k] = m > 0.0 ? m : 0.0;
    }
    double pos = mm[c];
    bool any = false; double best = 0.0;
    for (int k = 0; k < 5; ++k) {
      if (k == c || meta[k] < 2) continue;
      if (!any || mm[k] < best) { best = mm[k]; any = true; }
    }
    double lc = any ? fmax(pos - best + 0.1, 0.0) : pos;
    double w = sqrt((double)nsf * (double)nqf);
    total += w * lc; vw += w;
  }
  out[0] = (float)(0.1 * total / fmax(vw, 1e-12));
}

// ============================================================================
// host launcher
// ============================================================================
extern "C" void kernel_launch(void* const* d_in, const int* in_sizes, int n_in,
                              void* d_out, int out_size, void* d_ws, size_t ws_size,
                              hipStream_t stream) {
  const float* f_s = (const float*)d_in[0];
  const int*   l_s = (const int*)d_in[1];
  const float* f_q = (const float*)d_in[2];
  const int*   l_q = (const int*)d_in[3];
  float* out = (float*)d_out;
  char* ws = (char*)d_ws;

  size_t off = 0;
  auto take = [&](size_t bytes) -> void* {
    void* p = ws + off;
    off = (off + bytes + 255) & ~(size_t)255;
    return p;
  };
  int*   meta     = (int*)take(32 * 4);
  int*   cnts     = (int*)take(NBLK_C * 4);
  int*   offs     = (int*)take(NBLK_C * 4);
  int*   sup_list = (int*)take((size_t)5 * S_LEN * 4);
  int*   qry_list = (int*)take((size_t)5 * Q_TOT * 4);
  int*   Jsup     = (int*)take((size_t)5 * S_LEN * 4);
  int*   Jqry     = (int*)take((size_t)5 * Q_TOT * 4);
  unsigned int* draws = (unsigned int*)take((10ull * CAPS64 + 10ull * CAPQ64) * 4);
  int*   sel      = (int*)take((size_t)10 * MAXS * 4);
  float* xa       = (float*)take((size_t)5 * 65536 * 4);
  float* xb       = (float*)take((size_t)5 * 65536 * 4);
  float* Ga       = (float*)take((size_t)5 * 65536 * 4);
  float* Gb       = (float*)take((size_t)5 * 65536 * 4);
  float* Gab      = (float*)take((size_t)25 * 65536 * 4);
  float* diagA    = (float*)take((size_t)5 * 256 * 4);
  float* diagB    = (float*)take((size_t)5 * 256 * 4);
  unsigned int* bufAll  = (unsigned int*)take((size_t)MPASSES * 25 * 16 * 4);
  unsigned int* loArr   = (unsigned int*)take((size_t)MPASSES * 25 * 4);
  unsigned int* baseArr = (unsigned int*)take((size_t)MPASSES * 25 * 4);
  unsigned int* zcArr   = (unsigned int*)take(25 * 4);
  double* mmdsum  = (double*)take(25 * 3 * 8);
  if (off > ws_size) return;

  // H (next-hitter) arrays alias the draws buffer — draws dead after k_consume.
  unsigned int* Hsup = draws;
  unsigned int* Hqry = draws + (size_t)5 * S_LEN;
  size_t hbytes = ((size_t)5 * S_LEN + (size_t)5 * Q_TOT) * 4;

  k_draws<<<10, 256, 0, stream>>>(draws);
  k_count<<<NBLK_C, 256, 0, stream>>>(l_s, l_q, cnts);
  k_scan<<<1, 64, 0, stream>>>(cnts, offs, meta);
  k_write<<<NBLK_C, 256, 0, stream>>>(l_s, l_q, offs, sup_list, qry_list);
  k_consume<<<10, 256, 0, stream>>>(meta, draws, Jsup, Jqry);
  hipMemsetAsync(Hsup, 0xFF, hbytes, stream);
  {
    int nblk = 5 * (S_LEN / 256) + 5 * (Q_TOT / 256);   // 320 + 6400
    k_hfill<<<nblk, 256, 0, stream>>>(meta, Jsup, Jqry, Hsup, Hqry);
  }
  k_chase<<<10, 256, 0, stream>>>(meta, sup_list, qry_list, Hsup, Hqry, sel);
  k_gather<<<80, 256, 0, stream>>>(f_s, f_q, meta, sel, xa, xb);
  k_gram<<<140, 256, 0, stream>>>(xa, xb, Ga, Gb, Gab);
  k_diag<<<10, 256, 0, stream>>>(Ga, Gb, diagA, diagB);
  k_conv<<<280, 256, 0, stream>>>(Ga, Gb, Gab, diagA, diagB);

  hipMemsetAsync(bufAll, 0, (size_t)MPASSES * 25 * 16 * 4, stream);
  hipMemsetAsync(zcArr, 0, 25 * 4, stream);
  hipMemsetAsync(mmdsum, 0, 25 * 3 * 8, stream);
  for (int t = 0; t < MPASSES; ++t)
    k_medpass<<<25 * MSHARDS, 256, 0, stream>>>(t, meta, Ga, Gb, Gab,
                                                bufAll, loArr, baseArr, zcArr);
  k_rbf<<<25 * MSHARDS, 256, 0, stream>>>(meta, Ga, Gb, Gab,
                                          bufAll, loArr, baseArr, zcArr, mmdsum);
  k_final<<<1, 64, 0, stream>>>(meta, mmdsum, out);
}

// Round 13
// 772.551 us; speedup vs baseline: 1.0328x; 1.0328x over previous
//
#include <hip/hip_runtime.h>

// ============================================================================
// numpy RNG replication: SeedSequence + PCG64 (XSL-RR 128/64), next32 buffering
// ============================================================================
struct U128 { unsigned long long hi, lo; };

__device__ __forceinline__ U128 u128_mul(U128 a, U128 b) {
  U128 r;
  r.lo = a.lo * b.lo;
  r.hi = __umul64hi(a.lo, b.lo) + a.hi * b.lo + a.lo * b.hi;
  return r;
}
__device__ __forceinline__ U128 u128_add(U128 a, U128 b) {
  U128 r; r.lo = a.lo + b.lo; r.hi = a.hi + b.hi + (r.lo < a.lo ? 1ull : 0ull); return r;
}

struct Pcg64 {
  U128 state, inc;
};

__device__ __forceinline__ void pcg_step(Pcg64* r) {
  const U128 M = {0x2360ed051fc65da4ull, 0x4385df649fccf645ull};
  r->state = u128_add(u128_mul(r->state, M), r->inc);
}
__device__ __forceinline__ unsigned long long pcg_next64(Pcg64* r) {
  pcg_step(r);
  unsigned int rot = (unsigned int)(r->state.hi >> 58);   // state >> 122
  unsigned long long x = r->state.hi ^ r->state.lo;       // XSL
  return (x >> rot) | (x << ((64u - rot) & 63u));         // RR
}

// SeedSequence constants (numpy bit_generator.pyx)
__device__ __forceinline__ unsigned int ss_hashmix(unsigned int v, unsigned int* hc) {
  v ^= *hc; *hc = *hc * 0x931e8875u; v *= *hc; v ^= v >> 16; return v;
}
__device__ __forceinline__ unsigned int ss_mix(unsigned int x, unsigned int y) {
  unsigned int r = x * 0xca01f9ddu ^ y * 0x4973f715u; r ^= r >> 16; return r;
}
__device__ void pcg_seed(Pcg64* rng, unsigned int seed) {
  unsigned int pool[4]; unsigned int hc = 0x43b0d7e5u;   // INIT_A
  pool[0] = ss_hashmix(seed, &hc);
  for (int i = 1; i < 4; ++i) pool[i] = ss_hashmix(0u, &hc);
  for (int s = 0; s < 4; ++s)
    for (int d = 0; d < 4; ++d)
      if (s != d) pool[d] = ss_mix(pool[d], ss_hashmix(pool[s], &hc));
  unsigned int hc2 = 0x8b51f9ddu;                        // INIT_B
  unsigned long long w64[4];
  for (int i = 0; i < 4; ++i) {
    unsigned int lo = pool[(2*i) & 3];
    lo ^= hc2; hc2 *= 0x58f38dedu; lo *= hc2; lo ^= lo >> 16;
    unsigned int hi = pool[(2*i+1) & 3];
    hi ^= hc2; hc2 *= 0x58f38dedu; hi *= hc2; hi ^= hi >> 16;
    w64[i] = (unsigned long long)lo | ((unsigned long long)hi << 32);
  }
  U128 initstate = {w64[0], w64[1]};   // PCG_128BIT_CONSTANT(seed[0], seed[1]): [0] is HIGH
  U128 initseq   = {w64[2], w64[3]};
  rng->inc.hi = (initseq.hi << 1) | (initseq.lo >> 63);
  rng->inc.lo = (initseq.lo << 1) | 1ull;
  rng->state.hi = 0; rng->state.lo = 0;
  pcg_step(rng);
  rng->state = u128_add(rng->state, initstate);
  pcg_step(rng);
}

// affine jump-ahead: state <- A^delta * state + (A^delta-1)/(A-1)*inc
__device__ void pcg_advance(Pcg64* r, unsigned long long delta) {
  U128 acc_mult = {0ull, 1ull}, acc_plus = {0ull, 0ull};
  U128 cur_mult = {0x2360ed051fc65da4ull, 0x4385df649fccf645ull};
  U128 cur_plus = r->inc;
  while (delta) {
    if (delta & 1ull) {
      acc_mult = u128_mul(acc_mult, cur_mult);
      acc_plus = u128_add(u128_mul(acc_plus, cur_mult), cur_plus);
    }
    U128 one = {0ull, 1ull};
    U128 cm1 = u128_add(cur_mult, one);
    cur_plus = u128_mul(cm1, cur_plus);
    cur_mult = u128_mul(cur_mult, cur_mult);
    delta >>= 1;
  }
  r->state = u128_add(u128_mul(r->state, acc_mult), acc_plus);
}

// ============================================================================
// Problem constants
// ============================================================================
#define S_LEN   16384
#define Q_LEN   65536
#define Q_TOT   327680     // 5*65536
#define DFEAT   256
#define MAXS    256
#define CAPS64  24576
#define CAPQ64  98304
#define TILE    4096
#define STILES  (S_LEN / TILE)    // 4
#define QTILES  (Q_TOT / TILE)    // 80
#define NBLK_C  (5 * STILES + 5 * QTILES)   // 420
#define MSHARDS 8
#define MPASSES 8

// meta layout: [0..4]=ns_full, [5..9]=nq_full, [10..14]=na, [15..19]=nb

__constant__ int c_kshift[MPASSES] = {27, 23, 19, 15, 11, 7, 3, 0};

// ============================================================================
// K0: parallel draw-stream generation (exact numpy next32 sequence, lo first)
// ============================================================================
__global__ __launch_bounds__(256) void k_draws(unsigned int* __restrict__ draws) {
  int t = blockIdx.x; int cls = t % 5; int isq = t / 5;
  unsigned int seed = (unsigned)(1000 + isq * 1000 + cls + 1);
  unsigned long long cap64 = isq ? CAPQ64 : CAPS64;
  unsigned int* dst = draws + (isq ? (10ull * CAPS64 + (unsigned long long)cls * 2 * CAPQ64)
                                   : ((unsigned long long)cls * 2 * CAPS64));
  Pcg64 rng; pcg_seed(&rng, seed);
  int tid = threadIdx.x;
  unsigned long long C = cap64 / 256ull;     // 96 or 384
  unsigned long long k0 = (unsigned long long)tid * C;
  pcg_advance(&rng, k0);
  uint2* d2 = (uint2*)dst;
  for (unsigned long long m = 0; m < C; ++m) {
    unsigned long long o = pcg_next64(&rng);
    d2[k0 + m] = make_uint2((unsigned int)o, (unsigned int)(o >> 32));
  }
}

// ============================================================================
// K1a: per-tile match counts
// ============================================================================
__global__ __launch_bounds__(256) void k_count(const int* __restrict__ ls,
                                               const int* __restrict__ lq,
                                               int* __restrict__ cnts) {
  int b = blockIdx.x;
  const int* src; int matchval;
  if (b < 5 * STILES) {
    int cls = b / STILES, tl = b % STILES;
    src = ls + cls * S_LEN + tl * TILE; matchval = 1;
  } else {
    int bb = b - 5 * STILES; int cls = bb / QTILES, tl = bb % QTILES;
    src = lq + tl * TILE; matchval = cls + 1;
  }
  int tid = threadIdx.x;
  int cnt = 0;
  for (int k = 0; k < TILE; k += 256) cnt += (src[k + tid] == matchval) ? 1 : 0;
  __shared__ int red[256];
  red[tid] = cnt; __syncthreads();
  for (int s = 128; s > 0; s >>= 1) { if (tid < s) red[tid] += red[tid + s]; __syncthreads(); }
  if (tid == 0) cnts[b] = red[0];
}

// ============================================================================
// K1b: tiny scan: exclusive offsets per class + meta totals
// ============================================================================
__global__ void k_scan(const int* __restrict__ cnts, int* __restrict__ offs,
                       int* __restrict__ meta) {
  int t = threadIdx.x;
  if (t < 5) {
    int base = 0;
    for (int k = 0; k < STILES; ++k) {
      offs[t * STILES + k] = base; base += cnts[t * STILES + k];
    }
    meta[t] = base;
    meta[10 + t] = base < MAXS ? base : MAXS;
  } else if (t < 10) {
    int c = t - 5; int base = 0;
    for (int k = 0; k < QTILES; ++k) {
      int idx = 5 * STILES + c * QTILES + k;
      offs[idx] = base; base += cnts[idx];
    }
    meta[5 + c] = base;
    meta[15 + c] = base < MAXS ? base : MAXS;
  }
}

// ============================================================================
// K1c: stable compaction write at per-tile offsets (4-wave ballot prefix)
// ============================================================================
__global__ __launch_bounds__(256) void k_write(const int* __restrict__ ls,
                                               const int* __restrict__ lq,
                                               const int* __restrict__ offs,
                                               int* __restrict__ sup_list,
                                               int* __restrict__ qry_list) {
  int b = blockIdx.x;
  const int* src; int matchval; int* out; int ibase;
  if (b < 5 * STILES) {
    int cls = b / STILES, tl = b % STILES;
    src = ls + cls * S_LEN + tl * TILE; matchval = 1;
    out = sup_list + cls * S_LEN; ibase = tl * TILE;
  } else {
    int bb = b - 5 * STILES; int cls = bb / QTILES, tl = bb % QTILES;
    src = lq + tl * TILE; matchval = cls + 1;
    out = qry_list + (size_t)cls * Q_TOT; ibase = tl * TILE;
  }
  int tid = threadIdx.x; int w = tid >> 6, lane = tid & 63;
  unsigned long long lmask = (1ull << lane) - 1ull;
  __shared__ int wcnt[4];
  int base = offs[b];
  for (int k = 0; k < TILE; k += 256) {
    int i = k + tid;
    bool p = (src[i] == matchval);
    unsigned long long m = __ballot(p);
    if (lane == 0) wcnt[w] = __popcll(m);
    __syncthreads();
    int prev = 0;
    #pragma unroll
    for (int ww = 0; ww < 4; ++ww) prev += (ww < w) ? wcnt[ww] : 0;
    int tot = wcnt[0] + wcnt[1] + wcnt[2] + wcnt[3];
    if (p) out[base + prev + __popcll(m & lmask)] = ibase + i;
    __syncthreads();
    base += tot;
  }
}

// ============================================================================
// K2: wave-parallel masked-rejection automaton (R10 config: depth-8 register
//     pipeline + LDS-staged J ring; best measured 336 us).
// ============================================================================
__device__ __forceinline__ bool consume_chunk(unsigned int v, int& i, int n, int lane,
                                              unsigned long long lmask,
                                              unsigned long long lbit,
                                              unsigned int* __restrict__ ring) {
  unsigned long long rej = 0ull, acc = 0ull;
  for (;;) {
    unsigned long long unc = ~(rej | acc);
    int rbelow = __popcll(rej & lmask);
    int ubelow = __popcll(unc & lmask);
    int il_min = i - lane + rbelow;          // >= 193 always
    int il_max = il_min + ubelow;
    bool unres = (unc & lbit) != 0ull;
    unsigned int mlo = 0xFFFFFFFFu >> __clz(il_min);
    unsigned int mhi = 0xFFFFFFFFu >> __clz(il_max);
    unsigned int w = v & mlo;
    bool def_rej, hard;
    if (mlo == mhi) {
      def_rej = w > (unsigned int)il_max;
      hard = !def_rej && (w > (unsigned int)il_min);   // middle band
    } else if (ubelow == 0) {                // octave boundary: exact resolve
      def_rej = w > (unsigned int)il_min;
      hard = false;
    } else {
      def_rej = false;
      hard = true;                           // boundary-spanning, wait
    }
    def_rej = def_rej && unres;
    hard = hard && unres;
    unsigned long long nr = __ballot(def_rej);
    unsigned long long hd = __ballot(hard);
    rej |= nr;
    acc |= unc & ~nr & ~hd;
    if (!hd) break;
  }
  int rbelow = __popcll(rej & lmask);
  int il = i - lane + rbelow;
  int totAcc = 64 - __popcll(rej);
  if ((acc & lbit) && il >= MAXS) {
    int g = (n - 1) - il;
    ring[g & 4095] = v & (0xFFFFFFFFu >> __clz(il));
  }
  int needed = i - (MAXS - 1);
  if (totAcc >= needed) return true;
  i -= totAcc;
  return false;
}

__global__ __launch_bounds__(64) void k_consume(const int* __restrict__ meta,
                                                const unsigned int* __restrict__ draws,
                                                int* Jsup, int* Jqry) {
  __shared__ unsigned int ring[4096];
  int t = blockIdx.x; int cls = t % 5; int isq = t / 5;
  int n = meta[isq * 5 + cls];
  if (n <= MAXS) return;
  const unsigned int* d = draws + (isq ? (10ull * CAPS64 + (unsigned long long)cls * 2 * CAPQ64)
                                       : ((unsigned long long)cls * 2 * CAPS64));
  int* J = isq ? (Jqry + (size_t)cls * Q_TOT) : (Jsup + cls * S_LEN);
  int lane = threadIdx.x;
  unsigned long long lmask = (1ull << lane) - 1ull;
  unsigned long long lbit  = (1ull << lane);
  int i = n - 1;
  size_t p = 0;
  int flushed = 0;
  const int cap = n - MAXS;                 // J entries with il in [256, n-1]
  unsigned int v0 = d[lane],       v1 = d[64 + lane];
  unsigned int v2 = d[128 + lane], v3 = d[192 + lane];
  unsigned int v4 = d[256 + lane], v5 = d[320 + lane];
  unsigned int v6 = d[384 + lane], v7 = d[448 + lane];
  for (;;) {
    unsigned int nv0 = d[p + 512 + lane];
    unsigned int nv1 = d[p + 576 + lane];
    unsigned int nv2 = d[p + 640 + lane];
    unsigned int nv3 = d[p + 704 + lane];
    unsigned int nv4 = d[p + 768 + lane];
    unsigned int nv5 = d[p + 832 + lane];
    unsigned int nv6 = d[p + 896 + lane];
    unsigned int nv7 = d[p + 960 + lane];
    bool done;
    if      (consume_chunk(v0, i, n, lane, lmask, lbit, ring)) done = true;
    else if (consume_chunk(v1, i, n, lane, lmask, lbit, ring)) done = true;
    else if (consume_chunk(v2, i, n, lane, lmask, lbit, ring)) done = true;
    else if (consume_chunk(v3, i, n, lane, lmask, lbit, ring)) done = true;
    else if (consume_chunk(v4, i, n, lane, lmask, lbit, ring)) done = true;
    else if (consume_chunk(v5, i, n, lane, lmask, lbit, ring)) done = true;
    else if (consume_chunk(v6, i, n, lane, lmask, lbit, ring)) done = true;
    else if (consume_chunk(v7, i, n, lane, lmask, lbit, ring)) done = true;
    else done = false;
    if (done) break;
    // flush full 2048-entry blocks (coalesced descending J, fire-and-forget)
    int avail = (n - 1) - i; if (avail > cap) avail = cap;
    while (avail - flushed >= 2048) {
      #pragma unroll
      for (int k = 0; k < 32; ++k) {
        int g = flushed + k * 64 + lane;
        J[(n - 1) - g] = (int)ring[g & 4095];
      }
      flushed += 2048;
    }
    p += 512;
    v0 = nv0; v1 = nv1; v2 = nv2; v3 = nv3;
    v4 = nv4; v5 = nv5; v6 = nv6; v7 = nv7;
  }
  // final flush: every il in [256, n-1] has been staged
  for (int g = flushed + lane; g < cap; g += 64)
    J[(n - 1) - g] = (int)ring[g & 4095];
}

// ============================================================================
// K3a: next-hitter index fill.  H[v] = min{ i > v, i in [256,n) : J[i] == v }
// ============================================================================
__global__ __launch_bounds__(256) void k_hfill(const int* __restrict__ meta,
                                               const int* __restrict__ Jsup,
                                               const int* __restrict__ Jqry,
                                               unsigned int* __restrict__ Hsup,
                                               unsigned int* __restrict__ Hqry) {
  const int SB = 5 * (S_LEN / 256);
  int b = blockIdx.x;
  int cls, i; const int* J; unsigned int* H; int n;
  if (b < SB) {
    cls = b / (S_LEN / 256);
    i = (b % (S_LEN / 256)) * 256 + threadIdx.x;
    n = meta[cls];
    J = Jsup + cls * S_LEN; H = Hsup + cls * S_LEN;
  } else {
    b -= SB;
    cls = b / (Q_TOT / 256);
    i = (b % (Q_TOT / 256)) * 256 + threadIdx.x;
    n = meta[5 + cls];
    J = Jqry + (size_t)cls * Q_TOT; H = Hqry + (size_t)cls * Q_TOT;
  }
  if (i < MAXS || i >= n) return;
  int j = J[i];
  if (j != i) atomicMin(&H[j], (unsigned int)i);
}

// ============================================================================
// K4: gather + fused chase + fused row-norm.
//     Each block chases its own rows through H (expected ~2 hops), then
//     gathers and normalizes.  sel buffer and k_chase kernel eliminated.
// ============================================================================
__global__ __launch_bounds__(256) void k_gather(const float* __restrict__ f_s,
                                                const float* __restrict__ f_q,
                                                const int* __restrict__ meta,
                                                const int* __restrict__ sup_list,
                                                const int* __restrict__ qry_list,
                                                const unsigned int* __restrict__ Hsup,
                                                const unsigned int* __restrict__ Hqry,
                                                float* xa, float* xb) {
  int blk = blockIdx.x;
  int t = blk >> 3;          // class-pair 0..9
  int slab = blk & 7;        // 8 slabs x 32 rows
  int cls = t % 5; int isq = t / 5;
  int nfull = meta[isq * 5 + cls];
  int n = meta[10 + isq * 5 + cls];
  int tid = threadIdx.x;
  int row = slab * 32 + (tid >> 3);
  int dg = tid & 7;          // 8 d-groups of 32
  if (row >= n) return;      // group-uniform (8 lanes share row)
  const int* list; const unsigned int* H;
  if (!isq) { list = sup_list + cls * S_LEN; H = Hsup + cls * S_LEN; }
  else      { list = qry_list + (size_t)cls * Q_TOT; H = Hqry + (size_t)cls * Q_TOT; }
  unsigned int v = (unsigned int)row;
  if (nfull > MAXS) {
    unsigned int h = H[v];
    while (h != 0xFFFFFFFFu) { v = h; h = H[v]; }
  }
  int id = list[v];
  const float* src; size_t stride; float* dst;
  if (!isq) {
    src = f_s + (size_t)cls * DFEAT * S_LEN + id; stride = S_LEN;
    dst = xa + cls * (MAXS * DFEAT) + row * DFEAT;
  } else {
    int m = id >> 16; int nn = id & 0xFFFF;
    src = f_q + (size_t)m * DFEAT * Q_LEN + nn; stride = Q_LEN;
    dst = xb + cls * (MAXS * DFEAT) + row * DFEAT;
  }
  float vv[32];
  #pragma unroll
  for (int dd = 0; dd < 32; ++dd)
    vv[dd] = src[(size_t)(dg * 32 + dd) * stride];
  float ss = 0.f;
  #pragma unroll
  for (int dd = 0; dd < 32; ++dd) ss += vv[dd] * vv[dd];
  ss += __shfl_xor(ss, 1);
  ss += __shfl_xor(ss, 2);
  ss += __shfl_xor(ss, 4);
  float inv = 1.0f / (sqrtf(ss) + 1e-12f);
  #pragma unroll
  for (int dd = 0; dd < 32; ++dd) dst[dg * 32 + dd] = vv[dd] * inv;
}

// ============================================================================
// K5: 35 Gram matrices (256x256, K=256), 128x128 tiles -> 140 blocks.
//     Fused diag extraction: diagonal tiles write diagA/diagB (squared norms).
// ============================================================================
__global__ __launch_bounds__(256) void k_gram(const float* __restrict__ xa,
                                              const float* __restrict__ xb,
                                              float* Ga, float* Gb, float* Gab,
                                              float* diagA, float* diagB) {
  int b = blockIdx.x;
  int j = b >> 2; int tile = b & 3;
  int tr = (tile >> 1) * 128, tc = (tile & 1) * 128;
  const float *A, *B; float* G;
  if (j < 5)       { A = xa + j * 65536; B = A; G = Ga + j * 65536; }
  else if (j < 10) { int c = j - 5; A = xb + c * 65536; B = A; G = Gb + c * 65536; }
  else             { int p = j - 10; int k = p / 5, c = p % 5;
                     A = xa + k * 65536; B = xb + c * 65536; G = Gab + p * 65536; }
  __shared__ float As[128][33];
  __shared__ float Bs[128][33];
  int tid = threadIdx.x;
  int w = tid >> 6, lane = tid & 63;
  int wr = w >> 1, wc = w & 1;
  int lr = lane >> 3, lc = lane & 7;
  int orow = wr * 64 + lr * 8;     // within-tile output row base
  int ocol = wc * 64 + lc * 8;     // within-tile output col base
  float acc[8][8];
  #pragma unroll
  for (int r = 0; r < 8; ++r)
    #pragma unroll
    for (int s = 0; s < 8; ++s) acc[r][s] = 0.f;

  for (int k0 = 0; k0 < 256; k0 += 32) {
    #pragma unroll
    for (int e = 0; e < 4; ++e) {
      int idx = tid + e * 256;          // 0..1023
      int row = idx >> 3;               // 0..127
      int c4  = idx & 7;                // float4 slot in 32-k chunk
      float4 va = *(const float4*)(A + (size_t)(tr + row) * 256 + k0 + c4 * 4);
      As[row][c4 * 4 + 0] = va.x; As[row][c4 * 4 + 1] = va.y;
      As[row][c4 * 4 + 2] = va.z; As[row][c4 * 4 + 3] = va.w;
      float4 vb = *(const float4*)(B + (size_t)(tc + row) * 256 + k0 + c4 * 4);
      Bs[row][c4 * 4 + 0] = vb.x; Bs[row][c4 * 4 + 1] = vb.y;
      Bs[row][c4 * 4 + 2] = vb.z; Bs[row][c4 * 4 + 3] = vb.w;
    }
    __syncthreads();
    #pragma unroll 4
    for (int kk = 0; kk < 32; ++kk) {
      float a[8], bv[8];
      #pragma unroll
      for (int r = 0; r < 8; ++r) a[r] = As[orow + r][kk];
      #pragma unroll
      for (int s = 0; s < 8; ++s) bv[s] = Bs[ocol + s][kk];
      #pragma unroll
      for (int r = 0; r < 8; ++r)
        #pragma unroll
        for (int s = 0; s < 8; ++s) acc[r][s] += a[r] * bv[s];
    }
    __syncthreads();
  }
  #pragma unroll
  for (int r = 0; r < 8; ++r) {
    float* grow = G + (size_t)(tr + orow + r) * 256 + tc + ocol;
    *(float4*)(grow + 0) = make_float4(acc[r][0], acc[r][1], acc[r][2], acc[r][3]);
    *(float4*)(grow + 4) = make_float4(acc[r][4], acc[r][5], acc[r][6], acc[r][7]);
  }
  // fused diag extraction (squared norms) for self-Gram matrices
  if (j < 10 && tr == tc) {
    #pragma unroll
    for (int r = 0; r < 8; ++r)
      #pragma unroll
      for (int s = 0; s < 8; ++s) {
        int gr = orow + r, gc = ocol + s;
        if (gr == gc) {
          int gi = tr + gr;
          if (j < 5) diagA[j * 256 + gi] = acc[r][s];
          else       diagB[(j - 5) * 256 + gi] = acc[r][s];
        }
      }
  }
}

// ============================================================================
// K8: grid-parallel 16-ary exact radix-select over D computed ON THE FLY:
//     d = max(dA[row] + dB[col] - 2*G, 0)  (same arithmetic as old k_conv).
// ============================================================================
__device__ __forceinline__ void med_select(const unsigned int* __restrict__ c,
                                           unsigned int lprev, unsigned int bprev,
                                           unsigned int r, int kprev,
                                           unsigned int* lo, unsigned int* base) {
  int j = 15;
  #pragma unroll
  for (int q = 14; q >= 0; --q)
    if (bprev + c[q] > r) j = q;
  *lo = lprev + ((unsigned int)j << kprev);
  *base = (j == 0) ? bprev : bprev + c[j - 1];
}

__global__ __launch_bounds__(256) void k_medpass(int t,
                                                 const int* __restrict__ meta,
                                                 const float* __restrict__ Ga_all,
                                                 const float* __restrict__ Gb_all,
                                                 const float* __restrict__ Gab_all,
                                                 const float* __restrict__ diagA,
                                                 const float* __restrict__ diagB,
                                                 unsigned int* __restrict__ bufAll,  // [MPASSES][25][16]
                                                 unsigned int* __restrict__ loArr,   // [MPASSES][25]
                                                 unsigned int* __restrict__ baseArr, // [MPASSES][25]
                                                 unsigned int* __restrict__ zcArr) { // [25]
  int b = blockIdx.x;
  int p = b / MSHARDS, sh = b % MSHARDS;
  int kcl = p / 5, ccl = p % 5;
  int tid = threadIdx.x;
  int nsf = meta[kcl], nqf = meta[5 + ccl];
  if (nsf < 2 || nqf < 2) return;
  int na = meta[10 + kcl], nb = meta[15 + ccl];
  const float4* A4 = (const float4*)(Ga_all + kcl * 65536);
  const float4* B4 = (const float4*)(Gb_all + ccl * 65536);
  const float4* C4 = (const float4*)(Gab_all + p * 65536);
  const float* dAv = diagA + kcl * 256;
  const float* dBv = diagB + ccl * 256;

  __shared__ unsigned int sh_lo[1], sh_base[1];
  __shared__ unsigned int wred[4][16];
  __shared__ unsigned int wzc[4];

  int ks = c_kshift[t];
  unsigned int N = (unsigned int)(na + nb) * (unsigned int)(na + nb);

  if (tid == 0) {
    unsigned int lo = 0, base = 0;
    if (t > 0) {
      unsigned int nz = zcArr[p];
      if (nz < N) {
        unsigned int r = nz + (N - nz - 1u) / 2u;
        unsigned int cprev[15];
        const unsigned int* cp = bufAll + ((size_t)(t - 1) * 25 + p) * 16;
        #pragma unroll
        for (int q = 0; q < 15; ++q) cprev[q] = cp[q];
        med_select(cprev, loArr[(t - 1) * 25 + p], baseArr[(t - 1) * 25 + p],
                   r, c_kshift[t - 1], &lo, &base);
      }
    }
    sh_lo[0] = lo; sh_base[0] = base;
    if (sh == 0) { loArr[t * 25 + p] = lo; baseArr[t * 25 + p] = base; }
  }
  __syncthreads();
  unsigned int lo = sh_lo[0];

  unsigned int cnt[15];
  #pragma unroll
  for (int j = 0; j < 15; ++j) cnt[j] = 0;
  unsigned int zc = 0;
  unsigned int span = 16u << ks;   // ks<=27 -> fits u32

  #define PROC_MAT(M4, DR, DC, nr, nc, W)                                     \
    for (int m = 0; m < 8; ++m) {                                             \
      int fidx = sh * 2048 + m * 256 + tid;                                   \
      float4 g4 = M4[fidx];                                                   \
      int row = fidx >> 6; int col0 = (fidx & 63) << 2;                       \
      float dr = DR[row];                                                     \
      float4 dc4 = *(const float4*)((DC) + col0);                             \
      float r0_ = dr + dc4.x - 2.0f * g4.x; float e0 = r0_ > 0.f ? r0_ : 0.f; \
      float r1_ = dr + dc4.y - 2.0f * g4.y; float e1 = r1_ > 0.f ? r1_ : 0.f; \
      float r2_ = dr + dc4.z - 2.0f * g4.z; float e2 = r2_ > 0.f ? r2_ : 0.f; \
      float r3_ = dr + dc4.w - 2.0f * g4.w; float e3 = r3_ > 0.f ? r3_ : 0.f; \
      unsigned int kb[4] = {__float_as_uint(e0), __float_as_uint(e1),         \
                            __float_as_uint(e2), __float_as_uint(e3)};        \
      _Pragma("unroll")                                                       \
      for (int cc = 0; cc < 4; ++cc) {                                        \
        bool valid = (row < (nr)) && (col0 + cc < (nc));                      \
        unsigned int key = kb[cc];                                            \
        if (t == 0) zc += (valid && key == 0u) ? (W) : 0u;                    \
        unsigned int d = key - lo;                                            \
        bool in = valid && (key >= lo) && (d < span);                         \
        _Pragma("unroll")                                                     \
        for (int j = 0; j < 15; ++j)                                          \
          cnt[j] += (in && d < ((unsigned int)(j + 1) << ks)) ? (W) : 0u;     \
      }                                                                       \
    }

  PROC_MAT(A4, dAv, dAv, na, na, 1u)
  PROC_MAT(B4, dBv, dBv, nb, nb, 1u)
  PROC_MAT(C4, dAv, dBv, na, nb, 2u)
  #undef PROC_MAT

  // wave-level reduce then cross-wave
  #pragma unroll
  for (int j = 0; j < 15; ++j)
    for (int o = 32; o > 0; o >>= 1) cnt[j] += __shfl_down(cnt[j], o);
  if (t == 0)
    for (int o = 32; o > 0; o >>= 1) zc += __shfl_down(zc, o);
  int w = tid >> 6, lane = tid & 63;
  if (lane == 0) {
    #pragma unroll
    for (int j = 0; j < 15; ++j) wred[w][j] = cnt[j];
    wzc[w] = zc;
  }
  __syncthreads();
  if (tid < 15) {
    unsigned int s = wred[0][tid] + wred[1][tid] + wred[2][tid] + wred[3][tid];
    atomicAdd(&bufAll[((size_t)t * 25 + p) * 16 + tid], s);
  }
  if (t == 0 && tid == 15) {
    unsigned int s = wzc[0] + wzc[1] + wzc[2] + wzc[3];
    atomicAdd(&zcArr[p], s);
  }
}

// ============================================================================
// K8b: RBF partial sums (200 blocks), D on the fly, sigma from final select
// ============================================================================
__global__ __launch_bounds__(256) void k_rbf(const int* __restrict__ meta,
                                             const float* __restrict__ Ga_all,
                                             const float* __restrict__ Gb_all,
                                             const float* __restrict__ Gab_all,
                                             const float* __restrict__ diagA,
                                             const float* __restrict__ diagB,
                                             const unsigned int* __restrict__ bufAll,
                                             const unsigned int* __restrict__ loArr,
                                             const unsigned int* __restrict__ baseArr,
                                             const unsigned int* __restrict__ zcArr,
                                             double* __restrict__ mmdsum) { // [25][3]
  int b = blockIdx.x;
  int p = b / MSHARDS, sh = b % MSHARDS;
  int kcl = p / 5, ccl = p % 5;
  int tid = threadIdx.x;
  int nsf = meta[kcl], nqf = meta[5 + ccl];
  if (nsf < 2 || nqf < 2) return;
  int na = meta[10 + kcl], nb = meta[15 + ccl];
  const float4* A4 = (const float4*)(Ga_all + kcl * 65536);
  const float4* B4 = (const float4*)(Gb_all + ccl * 65536);
  const float4* C4 = (const float4*)(Gab_all + p * 65536);
  const float* dAv = diagA + kcl * 256;
  const float* dBv = diagB + ccl * 256;

  unsigned int N = (unsigned int)(na + nb) * (unsigned int)(na + nb);
  unsigned int nz = zcArr[p];
  float base_s;
  if (nz >= N) base_s = 1.0f;
  else {
    unsigned int r = nz + (N - nz - 1u) / 2u;
    unsigned int cprev[15];
    const unsigned int* cp = bufAll + ((size_t)(MPASSES - 1) * 25 + p) * 16;
    #pragma unroll
    for (int q = 0; q < 15; ++q) cprev[q] = cp[q];
    unsigned int lo, bs;
    med_select(cprev, loArr[(MPASSES - 1) * 25 + p], baseArr[(MPASSES - 1) * 25 + p],
               r, 0, &lo, &bs);
    base_s = sqrtf(__uint_as_float(lo) + 1e-6f);
  }
  float g2 = base_s * base_s;
  float c0 = 1.0f / (2.0f * g2 * 0.25f);
  float c1 = 1.0f / (2.0f * g2 * 1.0f);
  float c2 = 1.0f / (2.0f * g2 * 4.0f);
  float c3 = 1.0f / (2.0f * g2 * 16.0f);

  double accA = 0.0, accB = 0.0, accAB = 0.0;
  #define RBF_MAT(M4, DR, DC, nr, nc, ACC)                                    \
    for (int m = 0; m < 8; ++m) {                                             \
      int fidx = sh * 2048 + m * 256 + tid;                                   \
      float4 g4 = M4[fidx];                                                   \
      int row = fidx >> 6; int col0 = (fidx & 63) << 2;                       \
      float dr = DR[row];                                                     \
      float4 dc4 = *(const float4*)((DC) + col0);                             \
      float rw[4] = {dr + dc4.x - 2.0f * g4.x, dr + dc4.y - 2.0f * g4.y,      \
                     dr + dc4.z - 2.0f * g4.z, dr + dc4.w - 2.0f * g4.w};     \
      _Pragma("unroll")                                                       \
      for (int cc = 0; cc < 4; ++cc) {                                        \
        if ((row < (nr)) && (col0 + cc < (nc))) {                             \
          float d = rw[cc] > 0.f ? rw[cc] : 0.f;                              \
          ACC += (double)(expf(-d * c0) + expf(-d * c1)                       \
                        + expf(-d * c2) + expf(-d * c3));                     \
        }                                                                     \
      }                                                                       \
    }
  RBF_MAT(A4, dAv, dAv, na, na, accA)
  RBF_MAT(B4, dBv, dBv, nb, nb, accB)
  RBF_MAT(C4, dAv, dBv, na, nb, accAB)
  #undef RBF_MAT

  for (int o = 32; o > 0; o >>= 1) {
    accA += __shfl_down(accA, o);
    accB += __shfl_down(accB, o);
    accAB += __shfl_down(accAB, o);
  }
  __shared__ double wsum[4][3];
  int w = tid >> 6, lane = tid & 63;
  if (lane == 0) { wsum[w][0] = accA; wsum[w][1] = accB; wsum[w][2] = accAB; }
  __syncthreads();
  if (tid == 0) {
    double sA = wsum[0][0] + wsum[1][0] + wsum[2][0] + wsum[3][0];
    double sB = wsum[0][1] + wsum[1][1] + wsum[2][1] + wsum[3][1];
    double sC = wsum[0][2] + wsum[1][2] + wsum[2][2] + wsum[3][2];
    atomicAdd(&mmdsum[p * 3 + 0], sA);
    atomicAdd(&mmdsum[p * 3 + 1], sB);
    atomicAdd(&mmdsum[p * 3 + 2], sC);
  }
}

// ============================================================================
// K9: final weighted loss (mmd assembled from sums)
// ============================================================================
__global__ void k_final(const int* __restrict__ meta, const double* __restrict__ mmdsum,
                        float* out) {
  if (threadIdx.x != 0 || blockIdx.x != 0) return;
  double total = 0.0, vw = 0.0;
  for (int c = 0; c < 5; ++c) {
    int nsf = meta[c], nqf = meta[5 + c];
    if (nsf < 2 || nqf < 2) continue;
    int nbq = meta[15 + c];
    double mm[5];
    for (int k = 0; k < 5; ++k) {
      if (meta[k] < 2) { mm[k] = 0.0; continue; }
      int naa = meta[10 + k];
      int pp = k * 5 + c;
      double meanA  = mmdsum[pp * 3 + 0] / ((double)naa * (double)naa);
      double meanB  = mmdsum[pp * 3 + 1] / ((double)nbq * (double)nbq);
      double meanAB = mmdsum[pp * 3 + 2] / ((double)naa * (double)nbq);
      double m = meanA + meanB - 2.0 * meanAB;
      mm[k] = m > 0.0 ? m : 0.0;
    }
    double pos = mm[c];
    bool any = false; double best = 0.0;
    for (int k = 0; k < 5; ++k) {
      if (k == c || meta[k] < 2) continue;
      if (!any || mm[k] < best) { best = mm[k]; any = true; }
    }
    double lc = any ? fmax(pos - best + 0.1, 0.0) : pos;
    double w = sqrt((double)nsf * (double)nqf);
    total += w * lc; vw += w;
  }
  out[0] = (float)(0.1 * total / fmax(vw, 1e-12));
}

// ============================================================================
// host launcher
// ============================================================================
extern "C" void kernel_launch(void* const* d_in, const int* in_sizes, int n_in,
                              void* d_out, int out_size, void* d_ws, size_t ws_size,
                              hipStream_t stream) {
  const float* f_s = (const float*)d_in[0];
  const int*   l_s = (const int*)d_in[1];
  const float* f_q = (const float*)d_in[2];
  const int*   l_q = (const int*)d_in[3];
  float* out = (float*)d_out;
  char* ws = (char*)d_ws;

  size_t off = 0;
  auto take = [&](size_t bytes) -> void* {
    void* p = ws + off;
    off = (off + bytes + 255) & ~(size_t)255;
    return p;
  };
  int*   meta     = (int*)take(32 * 4);
  int*   cnts     = (int*)take(NBLK_C * 4);
  int*   offs     = (int*)take(NBLK_C * 4);
  int*   sup_list = (int*)take((size_t)5 * S_LEN * 4);
  int*   qry_list = (int*)take((size_t)5 * Q_TOT * 4);
  int*   Jsup     = (int*)take((size_t)5 * S_LEN * 4);
  int*   Jqry     = (int*)take((size_t)5 * Q_TOT * 4);
  unsigned int* draws = (unsigned int*)take((10ull * CAPS64 + 10ull * CAPQ64) * 4);
  float* xa       = (float*)take((size_t)5 * 65536 * 4);
  float* xb       = (float*)take((size_t)5 * 65536 * 4);
  float* Ga       = (float*)take((size_t)5 * 65536 * 4);
  float* Gb       = (float*)take((size_t)5 * 65536 * 4);
  float* Gab      = (float*)take((size_t)25 * 65536 * 4);
  float* diagA    = (float*)take((size_t)5 * 256 * 4);
  float* diagB    = (float*)take((size_t)5 * 256 * 4);
  size_t zero0 = off;
  unsigned int* bufAll  = (unsigned int*)take((size_t)MPASSES * 25 * 16 * 4);
  unsigned int* loArr   = (unsigned int*)take((size_t)MPASSES * 25 * 4);
  unsigned int* baseArr = (unsigned int*)take((size_t)MPASSES * 25 * 4);
  unsigned int* zcArr   = (unsigned int*)take(25 * 4);
  double* mmdsum  = (double*)take(25 * 3 * 8);
  size_t zero1 = off;
  if (off > ws_size) return;

  // H (next-hitter) arrays alias the draws buffer — draws dead after k_consume.
  unsigned int* Hsup = draws;
  unsigned int* Hqry = draws + (size_t)5 * S_LEN;
  size_t hbytes = ((size_t)5 * S_LEN + (size_t)5 * Q_TOT) * 4;

  k_draws<<<10, 256, 0, stream>>>(draws);
  k_count<<<NBLK_C, 256, 0, stream>>>(l_s, l_q, cnts);
  k_scan<<<1, 64, 0, stream>>>(cnts, offs, meta);
  k_write<<<NBLK_C, 256, 0, stream>>>(l_s, l_q, offs, sup_list, qry_list);
  k_consume<<<10, 64, 0, stream>>>(meta, draws, Jsup, Jqry);
  hipMemsetAsync(Hsup, 0xFF, hbytes, stream);
  {
    int nblk = 5 * (S_LEN / 256) + 5 * (Q_TOT / 256);   // 320 + 6400
    k_hfill<<<nblk, 256, 0, stream>>>(meta, Jsup, Jqry, Hsup, Hqry);
  }
  k_gather<<<80, 256, 0, stream>>>(f_s, f_q, meta, sup_list, qry_list,
                                   Hsup, Hqry, xa, xb);
  k_gram<<<140, 256, 0, stream>>>(xa, xb, Ga, Gb, Gab, diagA, diagB);

  hipMemsetAsync(ws + zero0, 0, zero1 - zero0, stream);
  for (int t = 0; t < MPASSES; ++t)
    k_medpass<<<25 * MSHARDS, 256, 0, stream>>>(t, meta, Ga, Gb, Gab, diagA, diagB,
                                                bufAll, loArr, baseArr, zcArr);
  k_rbf<<<25 * MSHARDS, 256, 0, stream>>>(meta, Ga, Gb, Gab, diagA, diagB,
                                          bufAll, loArr, baseArr, zcArr, mmdsum);
  k_final<<<1, 64, 0, stream>>>(meta, mmdsum, out);
}

// Round 15
// 762.430 us; speedup vs baseline: 1.0465x; 1.0133x over previous
//
#include <hip/hip_runtime.h>

// ============================================================================
// numpy RNG replication: SeedSequence + PCG64 (XSL-RR 128/64), next32 buffering
// ============================================================================
struct U128 { unsigned long long hi, lo; };

__device__ __forceinline__ U128 u128_mul(U128 a, U128 b) {
  U128 r;
  r.lo = a.lo * b.lo;
  r.hi = __umul64hi(a.lo, b.lo) + a.hi * b.lo + a.lo * b.hi;
  return r;
}
__device__ __forceinline__ U128 u128_add(U128 a, U128 b) {
  U128 r; r.lo = a.lo + b.lo; r.hi = a.hi + b.hi + (r.lo < a.lo ? 1ull : 0ull); return r;
}

struct Pcg64 {
  U128 state, inc;
};

__device__ __forceinline__ void pcg_step(Pcg64* r) {
  const U128 M = {0x2360ed051fc65da4ull, 0x4385df649fccf645ull};
  r->state = u128_add(u128_mul(r->state, M), r->inc);
}
__device__ __forceinline__ unsigned long long pcg_next64(Pcg64* r) {
  pcg_step(r);
  unsigned int rot = (unsigned int)(r->state.hi >> 58);   // state >> 122
  unsigned long long x = r->state.hi ^ r->state.lo;       // XSL
  return (x >> rot) | (x << ((64u - rot) & 63u));         // RR
}

// SeedSequence constants (numpy bit_generator.pyx)
__device__ __forceinline__ unsigned int ss_hashmix(unsigned int v, unsigned int* hc) {
  v ^= *hc; *hc = *hc * 0x931e8875u; v *= *hc; v ^= v >> 16; return v;
}
__device__ __forceinline__ unsigned int ss_mix(unsigned int x, unsigned int y) {
  unsigned int r = x * 0xca01f9ddu ^ y * 0x4973f715u; r ^= r >> 16; return r;
}
__device__ void pcg_seed(Pcg64* rng, unsigned int seed) {
  unsigned int pool[4]; unsigned int hc = 0x43b0d7e5u;   // INIT_A
  pool[0] = ss_hashmix(seed, &hc);
  for (int i = 1; i < 4; ++i) pool[i] = ss_hashmix(0u, &hc);
  for (int s = 0; s < 4; ++s)
    for (int d = 0; d < 4; ++d)
      if (s != d) pool[d] = ss_mix(pool[d], ss_hashmix(pool[s], &hc));
  unsigned int hc2 = 0x8b51f9ddu;                        // INIT_B
  unsigned long long w64[4];
  for (int i = 0; i < 4; ++i) {
    unsigned int lo = pool[(2*i) & 3];
    lo ^= hc2; hc2 *= 0x58f38dedu; lo *= hc2; lo ^= lo >> 16;
    unsigned int hi = pool[(2*i+1) & 3];
    hi ^= hc2; hc2 *= 0x58f38dedu; hi *= hc2; hi ^= hi >> 16;
    w64[i] = (unsigned long long)lo | ((unsigned long long)hi << 32);
  }
  U128 initstate = {w64[0], w64[1]};   // PCG_128BIT_CONSTANT(seed[0], seed[1]): [0] is HIGH
  U128 initseq   = {w64[2], w64[3]};
  rng->inc.hi = (initseq.hi << 1) | (initseq.lo >> 63);
  rng->inc.lo = (initseq.lo << 1) | 1ull;
  rng->state.hi = 0; rng->state.lo = 0;
  pcg_step(rng);
  rng->state = u128_add(rng->state, initstate);
  pcg_step(rng);
}

// affine jump-ahead: state <- A^delta * state + (A^delta-1)/(A-1)*inc
__device__ void pcg_advance(Pcg64* r, unsigned long long delta) {
  U128 acc_mult = {0ull, 1ull}, acc_plus = {0ull, 0ull};
  U128 cur_mult = {0x2360ed051fc65da4ull, 0x4385df649fccf645ull};
  U128 cur_plus = r->inc;
  while (delta) {
    if (delta & 1ull) {
      acc_mult = u128_mul(acc_mult, cur_mult);
      acc_plus = u128_add(u128_mul(acc_plus, cur_mult), cur_plus);
    }
    U128 one = {0ull, 1ull};
    U128 cm1 = u128_add(cur_mult, one);
    cur_plus = u128_mul(cm1, cur_plus);
    cur_mult = u128_mul(cur_mult, cur_mult);
    delta >>= 1;
  }
  r->state = u128_add(u128_mul(r->state, acc_mult), acc_plus);
}

// ============================================================================
// Problem constants
// ============================================================================
#define S_LEN   16384
#define Q_LEN   65536
#define Q_TOT   327680     // 5*65536
#define DFEAT   256
#define MAXS    256
#define CAPS64  24576
#define CAPQ64  98304
#define TILE    4096
#define STILES  (S_LEN / TILE)    // 4
#define QTILES  (Q_TOT / TILE)    // 80
#define NBLK_C  (5 * STILES + 5 * QTILES)   // 420
#define MSHARDS 8
#define MPASSES 8

// meta layout: [0..4]=ns_full, [5..9]=nq_full, [10..14]=na, [15..19]=nb

__constant__ int c_kshift[MPASSES] = {27, 23, 19, 15, 11, 7, 3, 0};

// ============================================================================
// K0: parallel draw-stream generation (exact numpy next32 sequence, lo first)
// ============================================================================
__global__ __launch_bounds__(256) void k_draws(unsigned int* __restrict__ draws) {
  int t = blockIdx.x; int cls = t % 5; int isq = t / 5;
  unsigned int seed = (unsigned)(1000 + isq * 1000 + cls + 1);
  unsigned long long cap64 = isq ? CAPQ64 : CAPS64;
  unsigned int* dst = draws + (isq ? (10ull * CAPS64 + (unsigned long long)cls * 2 * CAPQ64)
                                   : ((unsigned long long)cls * 2 * CAPS64));
  Pcg64 rng; pcg_seed(&rng, seed);
  int tid = threadIdx.x;
  unsigned long long C = cap64 / 256ull;     // 96 or 384
  unsigned long long k0 = (unsigned long long)tid * C;
  pcg_advance(&rng, k0);
  uint2* d2 = (uint2*)dst;
  for (unsigned long long m = 0; m < C; ++m) {
    unsigned long long o = pcg_next64(&rng);
    d2[k0 + m] = make_uint2((unsigned int)o, (unsigned int)(o >> 32));
  }
}

// ============================================================================
// K1a: per-tile match counts
// ============================================================================
__global__ __launch_bounds__(256) void k_count(const int* __restrict__ ls,
                                               const int* __restrict__ lq,
                                               int* __restrict__ cnts) {
  int b = blockIdx.x;
  const int* src; int matchval;
  if (b < 5 * STILES) {
    int cls = b / STILES, tl = b % STILES;
    src = ls + cls * S_LEN + tl * TILE; matchval = 1;
  } else {
    int bb = b - 5 * STILES; int cls = bb / QTILES, tl = bb % QTILES;
    src = lq + tl * TILE; matchval = cls + 1;
  }
  int tid = threadIdx.x;
  int cnt = 0;
  for (int k = 0; k < TILE; k += 256) cnt += (src[k + tid] == matchval) ? 1 : 0;
  __shared__ int red[256];
  red[tid] = cnt; __syncthreads();
  for (int s = 128; s > 0; s >>= 1) { if (tid < s) red[tid] += red[tid + s]; __syncthreads(); }
  if (tid == 0) cnts[b] = red[0];
}

// ============================================================================
// K1b: tiny scan: exclusive offsets per class + meta totals
// ============================================================================
__global__ void k_scan(const int* __restrict__ cnts, int* __restrict__ offs,
                       int* __restrict__ meta) {
  int t = threadIdx.x;
  if (t < 5) {
    int base = 0;
    for (int k = 0; k < STILES; ++k) {
      offs[t * STILES + k] = base; base += cnts[t * STILES + k];
    }
    meta[t] = base;
    meta[10 + t] = base < MAXS ? base : MAXS;
  } else if (t < 10) {
    int c = t - 5; int base = 0;
    for (int k = 0; k < QTILES; ++k) {
      int idx = 5 * STILES + c * QTILES + k;
      offs[idx] = base; base += cnts[idx];
    }
    meta[5 + c] = base;
    meta[15 + c] = base < MAXS ? base : MAXS;
  }
}

// ============================================================================
// K1c: stable compaction write at per-tile offsets (4-wave ballot prefix)
// ============================================================================
__global__ __launch_bounds__(256) void k_write(const int* __restrict__ ls,
                                               const int* __restrict__ lq,
                                               const int* __restrict__ offs,
                                               int* __restrict__ sup_list,
                                               int* __restrict__ qry_list) {
  int b = blockIdx.x;
  const int* src; int matchval; int* out; int ibase;
  if (b < 5 * STILES) {
    int cls = b / STILES, tl = b % STILES;
    src = ls + cls * S_LEN + tl * TILE; matchval = 1;
    out = sup_list + cls * S_LEN; ibase = tl * TILE;
  } else {
    int bb = b - 5 * STILES; int cls = bb / QTILES, tl = bb % QTILES;
    src = lq + tl * TILE; matchval = cls + 1;
    out = qry_list + (size_t)cls * Q_TOT; ibase = tl * TILE;
  }
  int tid = threadIdx.x; int w = tid >> 6, lane = tid & 63;
  unsigned long long lmask = (1ull << lane) - 1ull;
  __shared__ int wcnt[4];
  int base = offs[b];
  for (int k = 0; k < TILE; k += 256) {
    int i = k + tid;
    bool p = (src[i] == matchval);
    unsigned long long m = __ballot(p);
    if (lane == 0) wcnt[w] = __popcll(m);
    __syncthreads();
    int prev = 0;
    #pragma unroll
    for (int ww = 0; ww < 4; ++ww) prev += (ww < w) ? wcnt[ww] : 0;
    int tot = wcnt[0] + wcnt[1] + wcnt[2] + wcnt[3];
    if (p) out[base + prev + __popcll(m & lmask)] = ibase + i;
    __syncthreads();
    base += tot;
  }
}

// ============================================================================
// K2: wave-parallel masked-rejection automaton (measured best config:
//     depth-8 register pipeline + LDS-staged J ring, 336 us).
// ============================================================================
__device__ __forceinline__ bool consume_chunk(unsigned int v, int& i, int n, int lane,
                                              unsigned long long lmask,
                                              unsigned long long lbit,
                                              unsigned int* __restrict__ ring) {
  unsigned long long rej = 0ull, acc = 0ull;
  for (;;) {
    unsigned long long unc = ~(rej | acc);
    int rbelow = __popcll(rej & lmask);
    int ubelow = __popcll(unc & lmask);
    int il_min = i - lane + rbelow;          // >= 193 always
    int il_max = il_min + ubelow;
    bool unres = (unc & lbit) != 0ull;
    unsigned int mlo = 0xFFFFFFFFu >> __clz(il_min);
    unsigned int mhi = 0xFFFFFFFFu >> __clz(il_max);
    unsigned int w = v & mlo;
    bool def_rej, hard;
    if (mlo == mhi) {
      def_rej = w > (unsigned int)il_max;
      hard = !def_rej && (w > (unsigned int)il_min);   // middle band
    } else if (ubelow == 0) {                // octave boundary: exact resolve
      def_rej = w > (unsigned int)il_min;
      hard = false;
    } else {
      def_rej = false;
      hard = true;                           // boundary-spanning, wait
    }
    def_rej = def_rej && unres;
    hard = hard && unres;
    unsigned long long nr = __ballot(def_rej);
    unsigned long long hd = __ballot(hard);
    rej |= nr;
    acc |= unc & ~nr & ~hd;
    if (!hd) break;
  }
  int rbelow = __popcll(rej & lmask);
  int il = i - lane + rbelow;
  int totAcc = 64 - __popcll(rej);
  if ((acc & lbit) && il >= MAXS) {
    int g = (n - 1) - il;
    ring[g & 4095] = v & (0xFFFFFFFFu >> __clz(il));
  }
  int needed = i - (MAXS - 1);
  if (totAcc >= needed) return true;
  i -= totAcc;
  return false;
}

__global__ __launch_bounds__(64) void k_consume(const int* __restrict__ meta,
                                                const unsigned int* __restrict__ draws,
                                                int* Jsup, int* Jqry) {
  __shared__ unsigned int ring[4096];
  int t = blockIdx.x; int cls = t % 5; int isq = t / 5;
  int n = meta[isq * 5 + cls];
  if (n <= MAXS) return;
  const unsigned int* d = draws + (isq ? (10ull * CAPS64 + (unsigned long long)cls * 2 * CAPQ64)
                                       : ((unsigned long long)cls * 2 * CAPS64));
  int* J = isq ? (Jqry + (size_t)cls * Q_TOT) : (Jsup + cls * S_LEN);
  int lane = threadIdx.x;
  unsigned long long lmask = (1ull << lane) - 1ull;
  unsigned long long lbit  = (1ull << lane);
  int i = n - 1;
  size_t p = 0;
  int flushed = 0;
  const int cap = n - MAXS;                 // J entries with il in [256, n-1]
  unsigned int v0 = d[lane],       v1 = d[64 + lane];
  unsigned int v2 = d[128 + lane], v3 = d[192 + lane];
  unsigned int v4 = d[256 + lane], v5 = d[320 + lane];
  unsigned int v6 = d[384 + lane], v7 = d[448 + lane];
  for (;;) {
    unsigned int nv0 = d[p + 512 + lane];
    unsigned int nv1 = d[p + 576 + lane];
    unsigned int nv2 = d[p + 640 + lane];
    unsigned int nv3 = d[p + 704 + lane];
    unsigned int nv4 = d[p + 768 + lane];
    unsigned int nv5 = d[p + 832 + lane];
    unsigned int nv6 = d[p + 896 + lane];
    unsigned int nv7 = d[p + 960 + lane];
    bool done;
    if      (consume_chunk(v0, i, n, lane, lmask, lbit, ring)) done = true;
    else if (consume_chunk(v1, i, n, lane, lmask, lbit, ring)) done = true;
    else if (consume_chunk(v2, i, n, lane, lmask, lbit, ring)) done = true;
    else if (consume_chunk(v3, i, n, lane, lmask, lbit, ring)) done = true;
    else if (consume_chunk(v4, i, n, lane, lmask, lbit, ring)) done = true;
    else if (consume_chunk(v5, i, n, lane, lmask, lbit, ring)) done = true;
    else if (consume_chunk(v6, i, n, lane, lmask, lbit, ring)) done = true;
    else if (consume_chunk(v7, i, n, lane, lmask, lbit, ring)) done = true;
    else done = false;
    if (done) break;
    // flush full 2048-entry blocks (coalesced descending J, fire-and-forget)
    int avail = (n - 1) - i; if (avail > cap) avail = cap;
    while (avail - flushed >= 2048) {
      #pragma unroll
      for (int k = 0; k < 32; ++k) {
        int g = flushed + k * 64 + lane;
        J[(n - 1) - g] = (int)ring[g & 4095];
      }
      flushed += 2048;
    }
    p += 512;
    v0 = nv0; v1 = nv1; v2 = nv2; v3 = nv3;
    v4 = nv4; v5 = nv5; v6 = nv6; v7 = nv7;
  }
  // final flush: every il in [256, n-1] has been staged
  for (int g = flushed + lane; g < cap; g += 64)
    J[(n - 1) - g] = (int)ring[g & 4095];
}

// ============================================================================
// K3a: next-hitter index fill.  H[v] = min{ i > v, i in [256,n) : J[i] == v }
// ============================================================================
__global__ __launch_bounds__(256) void k_hfill(const int* __restrict__ meta,
                                               const int* __restrict__ Jsup,
                                               const int* __restrict__ Jqry,
                                               unsigned int* __restrict__ Hsup,
                                               unsigned int* __restrict__ Hqry) {
  const int SB = 5 * (S_LEN / 256);
  int b = blockIdx.x;
  int cls, i; const int* J; unsigned int* H; int n;
  if (b < SB) {
    cls = b / (S_LEN / 256);
    i = (b % (S_LEN / 256)) * 256 + threadIdx.x;
    n = meta[cls];
    J = Jsup + cls * S_LEN; H = Hsup + cls * S_LEN;
  } else {
    b -= SB;
    cls = b / (Q_TOT / 256);
    i = (b % (Q_TOT / 256)) * 256 + threadIdx.x;
    n = meta[5 + cls];
    J = Jqry + (size_t)cls * Q_TOT; H = Hqry + (size_t)cls * Q_TOT;
  }
  if (i < MAXS || i >= n) return;
  int j = J[i];
  if (j != i) atomicMin(&H[j], (unsigned int)i);
}

// ============================================================================
// K3b: chase.  sel[t][s] = list[ c(s) ]
// ============================================================================
__global__ __launch_bounds__(256) void k_chase(const int* __restrict__ meta,
                                               const int* __restrict__ sup_list,
                                               const int* __restrict__ qry_list,
                                               const unsigned int* __restrict__ Hsup,
                                               const unsigned int* __restrict__ Hqry,
                                               int* sel) {
  int t = blockIdx.x; int tid = threadIdx.x;
  int cls = t % 5; int isq = t / 5;
  int n = meta[isq * 5 + cls];
  const int* list; const unsigned int* H;
  if (!isq) { list = sup_list + cls * S_LEN; H = Hsup + cls * S_LEN; }
  else      { list = qry_list + (size_t)cls * Q_TOT; H = Hqry + (size_t)cls * Q_TOT; }
  int* s = sel + t * MAXS;
  if (n <= MAXS) { if (tid < n) s[tid] = list[tid]; return; }
  unsigned int v = (unsigned int)tid;
  unsigned int h = H[v];
  while (h != 0xFFFFFFFFu) { v = h; h = H[v]; }
  s[tid] = list[v];
}

// ============================================================================
// K4: gather selected feature rows + fused row-norm (x / (||x|| + 1e-12)).
// ============================================================================
__global__ __launch_bounds__(256) void k_gather(const float* __restrict__ f_s,
                                                const float* __restrict__ f_q,
                                                const int* __restrict__ meta,
                                                const int* __restrict__ sel,
                                                float* xa, float* xb) {
  int blk = blockIdx.x;
  int t = blk >> 3;          // class-pair 0..9
  int slab = blk & 7;        // 8 slabs x 32 rows
  int cls = t % 5; int isq = t / 5;
  int n = meta[10 + isq * 5 + cls];
  int tid = threadIdx.x;
  int row = slab * 32 + (tid >> 3);
  int dg = tid & 7;          // 8 d-groups of 32
  if (row >= n) return;      // group-uniform (8 lanes share row)
  int id = sel[t * MAXS + row];
  const float* src; size_t stride; float* dst;
  if (!isq) {
    src = f_s + (size_t)cls * DFEAT * S_LEN + id; stride = S_LEN;
    dst = xa + cls * (MAXS * DFEAT) + row * DFEAT;
  } else {
    int m = id >> 16; int nn = id & 0xFFFF;
    src = f_q + (size_t)m * DFEAT * Q_LEN + nn; stride = Q_LEN;
    dst = xb + cls * (MAXS * DFEAT) + row * DFEAT;
  }
  float v[32];
  #pragma unroll
  for (int dd = 0; dd < 32; ++dd)
    v[dd] = src[(size_t)(dg * 32 + dd) * stride];
  float ss = 0.f;
  #pragma unroll
  for (int dd = 0; dd < 32; ++dd) ss += v[dd] * v[dd];
  ss += __shfl_xor(ss, 1);
  ss += __shfl_xor(ss, 2);
  ss += __shfl_xor(ss, 4);
  float inv = 1.0f / (sqrtf(ss) + 1e-12f);
  #pragma unroll
  for (int dd = 0; dd < 32; ++dd) dst[dg * 32 + dd] = v[dd] * inv;
}

// ============================================================================
// K5: 35 Gram matrices (256x256, K=256), 128x128 tiles -> 140 blocks.
// ============================================================================
__global__ __launch_bounds__(256) void k_gram(const float* __restrict__ xa,
                                              const float* __restrict__ xb,
                                              float* Ga, float* Gb, float* Gab) {
  int b = blockIdx.x;
  int j = b >> 2; int tile = b & 3;
  int tr = (tile >> 1) * 128, tc = (tile & 1) * 128;
  const float *A, *B; float* G;
  if (j < 5)       { A = xa + j * 65536; B = A; G = Ga + j * 65536; }
  else if (j < 10) { int c = j - 5; A = xb + c * 65536; B = A; G = Gb + c * 65536; }
  else             { int p = j - 10; int k = p / 5, c = p % 5;
                     A = xa + k * 65536; B = xb + c * 65536; G = Gab + p * 65536; }
  __shared__ float As[128][33];
  __shared__ float Bs[128][33];
  int tid = threadIdx.x;
  int w = tid >> 6, lane = tid & 63;
  int wr = w >> 1, wc = w & 1;
  int lr = lane >> 3, lc = lane & 7;
  int orow = wr * 64 + lr * 8;     // within-tile output row base
  int ocol = wc * 64 + lc * 8;     // within-tile output col base
  float acc[8][8];
  #pragma unroll
  for (int r = 0; r < 8; ++r)
    #pragma unroll
    for (int s = 0; s < 8; ++s) acc[r][s] = 0.f;

  for (int k0 = 0; k0 < 256; k0 += 32) {
    #pragma unroll
    for (int e = 0; e < 4; ++e) {
      int idx = tid + e * 256;          // 0..1023
      int row = idx >> 3;               // 0..127
      int c4  = idx & 7;                // float4 slot in 32-k chunk
      float4 va = *(const float4*)(A + (size_t)(tr + row) * 256 + k0 + c4 * 4);
      As[row][c4 * 4 + 0] = va.x; As[row][c4 * 4 + 1] = va.y;
      As[row][c4 * 4 + 2] = va.z; As[row][c4 * 4 + 3] = va.w;
      float4 vb = *(const float4*)(B + (size_t)(tc + row) * 256 + k0 + c4 * 4);
      Bs[row][c4 * 4 + 0] = vb.x; Bs[row][c4 * 4 + 1] = vb.y;
      Bs[row][c4 * 4 + 2] = vb.z; Bs[row][c4 * 4 + 3] = vb.w;
    }
    __syncthreads();
    #pragma unroll 4
    for (int kk = 0; kk < 32; ++kk) {
      float a[8], bv[8];
      #pragma unroll
      for (int r = 0; r < 8; ++r) a[r] = As[orow + r][kk];
      #pragma unroll
      for (int s = 0; s < 8; ++s) bv[s] = Bs[ocol + s][kk];
      #pragma unroll
      for (int r = 0; r < 8; ++r)
        #pragma unroll
        for (int s = 0; s < 8; ++s) acc[r][s] += a[r] * bv[s];
    }
    __syncthreads();
  }
  #pragma unroll
  for (int r = 0; r < 8; ++r) {
    float* grow = G + (size_t)(tr + orow + r) * 256 + tc + ocol;
    *(float4*)(grow + 0) = make_float4(acc[r][0], acc[r][1], acc[r][2], acc[r][3]);
    *(float4*)(grow + 4) = make_float4(acc[r][4], acc[r][5], acc[r][6], acc[r][7]);
  }
}

// ============================================================================
// K6: extract Gram diagonals
// ============================================================================
__global__ __launch_bounds__(256) void k_diag(const float* __restrict__ Ga,
                                              const float* __restrict__ Gb,
                                              float* diagA, float* diagB) {
  int t = blockIdx.x; int i = threadIdx.x;
  if (t < 5) diagA[t * 256 + i] = Ga[t * 65536 + i * 257];
  else { int c = t - 5; diagB[c * 256 + i] = Gb[c * 65536 + i * 257]; }
}

// ============================================================================
// K7: G -> D in place (280 blocks: 35 matrices x 8 row-slabs)
// ============================================================================
__global__ __launch_bounds__(256) void k_conv(float* Ga, float* Gb, float* Gab,
                                              const float* __restrict__ diagA,
                                              const float* __restrict__ diagB) {
  int b = blockIdx.x; int j = b >> 3; int slab = b & 7; int tid = threadIdx.x;
  float* G; const float *dA, *dB;
  if (j < 5)       { G = Ga + j * 65536; dA = diagA + j * 256; dB = dA; }
  else if (j < 10) { int c = j - 5; G = Gb + c * 65536; dA = diagB + c * 256; dB = dA; }
  else             { int p = j - 10; int k = p / 5, c = p % 5;
                     G = Gab + p * 65536; dA = diagA + k * 256; dB = diagB + c * 256; }
  float db = dB[tid];
  for (int i = slab * 32; i < slab * 32 + 32; ++i) {
    float g = G[i * 256 + tid];
    float d = dA[i] + db - 2.0f * g;
    G[i * 256 + tid] = d > 0.f ? d : 0.f;
  }
}

// ============================================================================
// K8: grid-parallel 16-ary exact radix-select, one kernel per pass.
// ============================================================================
__device__ __forceinline__ void med_select(const unsigned int* __restrict__ c,
                                           unsigned int lprev, unsigned int bprev,
                                           unsigned int r, int kprev,
                                           unsigned int* lo, unsigned int* base) {
  int j = 15;
  #pragma unroll
  for (int q = 14; q >= 0; --q)
    if (bprev + c[q] > r) j = q;
  *lo = lprev + ((unsigned int)j << kprev);
  *base = (j == 0) ? bprev : bprev + c[j - 1];
}

__global__ __launch_bounds__(256) void k_medpass(int t,
                                                 const int* __restrict__ meta,
                                                 const float* __restrict__ Da_all,
                                                 const float* __restrict__ Db_all,
                                                 const float* __restrict__ Dab_all,
                                                 unsigned int* __restrict__ bufAll,  // [MPASSES][25][16]
                                                 unsigned int* __restrict__ loArr,   // [MPASSES][25]
                                                 unsigned int* __restrict__ baseArr, // [MPASSES][25]
                                                 unsigned int* __restrict__ zcArr) { // [25]
  int b = blockIdx.x;
  int p = b / MSHARDS, sh = b % MSHARDS;
  int kcl = p / 5, ccl = p % 5;
  int tid = threadIdx.x;
  int nsf = meta[kcl], nqf = meta[5 + ccl];
  if (nsf < 2 || nqf < 2) return;
  int na = meta[10 + kcl], nb = meta[15 + ccl];
  const float4* A4 = (const float4*)(Da_all + kcl * 65536);
  const float4* B4 = (const float4*)(Db_all + ccl * 65536);
  const float4* C4 = (const float4*)(Dab_all + p * 65536);

  __shared__ unsigned int sh_lo[1], sh_base[1];
  __shared__ unsigned int wred[4][16];
  __shared__ unsigned int wzc[4];

  int ks = c_kshift[t];
  unsigned int N = (unsigned int)(na + nb) * (unsigned int)(na + nb);

  if (tid == 0) {
    unsigned int lo = 0, base = 0;
    if (t > 0) {
      unsigned int nz = zcArr[p];
      if (nz < N) {
        unsigned int r = nz + (N - nz - 1u) / 2u;
        unsigned int cprev[15];
        const unsigned int* cp = bufAll + ((size_t)(t - 1) * 25 + p) * 16;
        #pragma unroll
        for (int q = 0; q < 15; ++q) cprev[q] = cp[q];
        med_select(cprev, loArr[(t - 1) * 25 + p], baseArr[(t - 1) * 25 + p],
                   r, c_kshift[t - 1], &lo, &base);
      }
    }
    sh_lo[0] = lo; sh_base[0] = base;
    if (sh == 0) { loArr[t * 25 + p] = lo; baseArr[t * 25 + p] = base; }
  }
  __syncthreads();
  unsigned int lo = sh_lo[0];

  unsigned int cnt[15];
  #pragma unroll
  for (int j = 0; j < 15; ++j) cnt[j] = 0;
  unsigned int zc = 0;
  unsigned int span = 16u << ks;   // ks<=27 -> fits u32 (16<<27 = 2^31)

  #define PROC_MAT(M4, nr, nc, W)                                             \
    for (int m = 0; m < 8; ++m) {                                             \
      int fidx = sh * 2048 + m * 256 + tid;                                   \
      float4 v = M4[fidx];                                                    \
      int row = fidx >> 6; int col0 = (fidx & 63) << 2;                       \
      unsigned int kb[4] = {__float_as_uint(v.x), __float_as_uint(v.y),       \
                            __float_as_uint(v.z), __float_as_uint(v.w)};      \
      _Pragma("unroll")                                                       \
      for (int cc = 0; cc < 4; ++cc) {                                        \
        bool valid = (row < (nr)) && (col0 + cc < (nc));                      \
        unsigned int key = kb[cc];                                            \
        if (t == 0) zc += (valid && key == 0u) ? (W) : 0u;                    \
        unsigned int d = key - lo;                                            \
        bool in = valid && (key >= lo) && (d < span);                         \
        _Pragma("unroll")                                                     \
        for (int j = 0; j < 15; ++j)                                          \
          cnt[j] += (in && d < ((unsigned int)(j + 1) << ks)) ? (W) : 0u;     \
      }                                                                       \
    }

  PROC_MAT(A4, na, na, 1u)
  PROC_MAT(B4, nb, nb, 1u)
  PROC_MAT(C4, na, nb, 2u)
  #undef PROC_MAT

  // wave-level reduce then cross-wave
  #pragma unroll
  for (int j = 0; j < 15; ++j)
    for (int o = 32; o > 0; o >>= 1) cnt[j] += __shfl_down(cnt[j], o);
  if (t == 0)
    for (int o = 32; o > 0; o >>= 1) zc += __shfl_down(zc, o);
  int w = tid >> 6, lane = tid & 63;
  if (lane == 0) {
    #pragma unroll
    for (int j = 0; j < 15; ++j) wred[w][j] = cnt[j];
    wzc[w] = zc;
  }
  __syncthreads();
  if (tid < 15) {
    unsigned int s = wred[0][tid] + wred[1][tid] + wred[2][tid] + wred[3][tid];
    atomicAdd(&bufAll[((size_t)t * 25 + p) * 16 + tid], s);
  }
  if (t == 0 && tid == 15) {
    unsigned int s = wzc[0] + wzc[1] + wzc[2] + wzc[3];
    atomicAdd(&zcArr[p], s);
  }
}

// ============================================================================
// K8b: RBF partial sums (200 blocks), sigma from final select
// ============================================================================
__global__ __launch_bounds__(256) void k_rbf(const int* __restrict__ meta,
                                             const float* __restrict__ Da_all,
                                             const float* __restrict__ Db_all,
                                             const float* __restrict__ Dab_all,
                                             const unsigned int* __restrict__ bufAll,
                                             const unsigned int* __restrict__ loArr,
                                             const unsigned int* __restrict__ baseArr,
                                             const unsigned int* __restrict__ zcArr,
                                             double* __restrict__ mmdsum) { // [25][3]
  int b = blockIdx.x;
  int p = b / MSHARDS, sh = b % MSHARDS;
  int kcl = p / 5, ccl = p % 5;
  int tid = threadIdx.x;
  int nsf = meta[kcl], nqf = meta[5 + ccl];
  if (nsf < 2 || nqf < 2) return;
  int na = meta[10 + kcl], nb = meta[15 + ccl];
  const float4* A4 = (const float4*)(Da_all + kcl * 65536);
  const float4* B4 = (const float4*)(Db_all + ccl * 65536);
  const float4* C4 = (const float4*)(Dab_all + p * 65536);

  unsigned int N = (unsigned int)(na + nb) * (unsigned int)(na + nb);
  unsigned int nz = zcArr[p];
  float base_s;
  if (nz >= N) base_s = 1.0f;
  else {
    unsigned int r = nz + (N - nz - 1u) / 2u;
    unsigned int cprev[15];
    const unsigned int* cp = bufAll + ((size_t)(MPASSES - 1) * 25 + p) * 16;
    #pragma unroll
    for (int q = 0; q < 15; ++q) cprev[q] = cp[q];
    unsigned int lo, bs;
    med_select(cprev, loArr[(MPASSES - 1) * 25 + p], baseArr[(MPASSES - 1) * 25 + p],
               r, 0, &lo, &bs);
    base_s = sqrtf(__uint_as_float(lo) + 1e-6f);
  }
  float g2 = base_s * base_s;
  float c0 = 1.0f / (2.0f * g2 * 0.25f);
  float c1 = 1.0f / (2.0f * g2 * 1.0f);
  float c2 = 1.0f / (2.0f * g2 * 4.0f);
  float c3 = 1.0f / (2.0f * g2 * 16.0f);

  double accA = 0.0, accB = 0.0, accAB = 0.0;
  #define RBF_MAT(M4, nr, nc, ACC)                                            \
    for (int m = 0; m < 8; ++m) {                                             \
      int fidx = sh * 2048 + m * 256 + tid;                                   \
      float4 v = M4[fidx];                                                    \
      int row = fidx >> 6; int col0 = (fidx & 63) << 2;                       \
      float vv[4] = {v.x, v.y, v.z, v.w};                                     \
      _Pragma("unroll")                                                       \
      for (int cc = 0; cc < 4; ++cc) {                                        \
        if ((row < (nr)) && (col0 + cc < (nc))) {                             \
          float d = vv[cc];                                                   \
          ACC += (double)(expf(-d * c0) + expf(-d * c1)                       \
                        + expf(-d * c2) + expf(-d * c3));                     \
        }                                                                     \
      }                                                                       \
    }
  RBF_MAT(A4, na, na, accA)
  RBF_MAT(B4, nb, nb, accB)
  RBF_MAT(C4, na, nb, accAB)
  #undef RBF_MAT

  for (int o = 32; o > 0; o >>= 1) {
    accA += __shfl_down(accA, o);
    accB += __shfl_down(accB, o);
    accAB += __shfl_down(accAB, o);
  }
  __shared__ double wsum[4][3];
  int w = tid >> 6, lane = tid & 63;
  if (lane == 0) { wsum[w][0] = accA; wsum[w][1] = accB; wsum[w][2] = accAB; }
  __syncthreads();
  if (tid == 0) {
    double sA = wsum[0][0] + wsum[1][0] + wsum[2][0] + wsum[3][0];
    double sB = wsum[0][1] + wsum[1][1] + wsum[2][1] + wsum[3][1];
    double sC = wsum[0][2] + wsum[1][2] + wsum[2][2] + wsum[3][2];
    atomicAdd(&mmdsum[p * 3 + 0], sA);
    atomicAdd(&mmdsum[p * 3 + 1], sB);
    atomicAdd(&mmdsum[p * 3 + 2], sC);
  }
}

// ============================================================================
// K9: final weighted loss (mmd assembled from sums)
// ============================================================================
__global__ void k_final(const int* __restrict__ meta, const double* __restrict__ mmdsum,
                        float* out) {
  if (threadIdx.x != 0 || blockIdx.x != 0) return;
  double total = 0.0, vw = 0.0;
  for (int c = 0; c < 5; ++c) {
    int nsf = meta[c], nqf = meta[5 + c];
    if (nsf < 2 || nqf < 2) continue;
    int nbq = meta[15 + c];
    double mm[5];
    for (int k = 0; k < 5; ++k) {
      if (meta[k] < 2) { mm[k] = 0.0; continue; }
      int naa = meta[10 + k];
      int pp = k * 5 + c;
      double meanA  = mmdsum[pp * 3 + 0] / ((double)naa * (double)naa);
      double meanB  = mmdsum[pp * 3 + 1] / ((double)nbq * (double)nbq);
      double meanAB = mmdsum[pp * 3 + 2] / ((double)naa * (double)nbq);
      double m = meanA + meanB - 2.0 * meanAB;
      mm[k] = m > 0.0 ? m : 0.0;
    }
    double pos = mm[c];
    bool any = false; double best = 0.0;
    for (int k = 0; k < 5; ++k) {
      if (k == c || meta[k] < 2) continue;
      if (!any || mm[k] < best) { best = mm[k]; any = true; }
    }
    double lc = any ? fmax(pos - best + 0.1, 0.0) : pos;
    double w = sqrt((double)nsf * (double)nqf);
    total += w * lc; vw += w;
  }
  out[0] = (float)(0.1 * total / fmax(vw, 1e-12));
}

// ============================================================================
// host launcher
// ============================================================================
extern "C" void kernel_launch(void* const* d_in, const int* in_sizes, int n_in,
                              void* d_out, int out_size, void* d_ws, size_t ws_size,
                              hipStream_t stream) {
  const float* f_s = (const float*)d_in[0];
  const int*   l_s = (const int*)d_in[1];
  const float* f_q = (const float*)d_in[2];
  const int*   l_q = (const int*)d_in[3];
  float* out = (float*)d_out;
  char* ws = (char*)d_ws;

  size_t off = 0;
  auto take = [&](size_t bytes) -> void* {
    void* p = ws + off;
    off = (off + bytes + 255) & ~(size_t)255;
    return p;
  };
  int*   meta     = (int*)take(32 * 4);
  int*   cnts     = (int*)take(NBLK_C * 4);
  int*   offs     = (int*)take(NBLK_C * 4);
  int*   sup_list = (int*)take((size_t)5 * S_LEN * 4);
  int*   qry_list = (int*)take((size_t)5 * Q_TOT * 4);
  int*   Jsup     = (int*)take((size_t)5 * S_LEN * 4);
  int*   Jqry     = (int*)take((size_t)5 * Q_TOT * 4);
  unsigned int* draws = (unsigned int*)take((10ull * CAPS64 + 10ull * CAPQ64) * 4);
  int*   sel      = (int*)take((size_t)10 * MAXS * 4);
  float* xa       = (float*)take((size_t)5 * 65536 * 4);
  float* xb       = (float*)take((size_t)5 * 65536 * 4);
  float* Ga       = (float*)take((size_t)5 * 65536 * 4);
  float* Gb       = (float*)take((size_t)5 * 65536 * 4);
  float* Gab      = (float*)take((size_t)25 * 65536 * 4);
  float* diagA    = (float*)take((size_t)5 * 256 * 4);
  float* diagB    = (float*)take((size_t)5 * 256 * 4);
  unsigned int* bufAll  = (unsigned int*)take((size_t)MPASSES * 25 * 16 * 4);
  unsigned int* loArr   = (unsigned int*)take((size_t)MPASSES * 25 * 4);
  unsigned int* baseArr = (unsigned int*)take((size_t)MPASSES * 25 * 4);
  unsigned int* zcArr   = (unsigned int*)take(25 * 4);
  double* mmdsum  = (double*)take(25 * 3 * 8);
  if (off > ws_size) return;

  // H (next-hitter) arrays alias the draws buffer — draws dead after k_consume.
  unsigned int* Hsup = draws;
  unsigned int* Hqry = draws + (size_t)5 * S_LEN;
  size_t hbytes = ((size_t)5 * S_LEN + (size_t)5 * Q_TOT) * 4;

  k_draws<<<10, 256, 0, stream>>>(draws);
  k_count<<<NBLK_C, 256, 0, stream>>>(l_s, l_q, cnts);
  k_scan<<<1, 64, 0, stream>>>(cnts, offs, meta);
  k_write<<<NBLK_C, 256, 0, stream>>>(l_s, l_q, offs, sup_list, qry_list);
  k_consume<<<10, 64, 0, stream>>>(meta, draws, Jsup, Jqry);
  hipMemsetAsync(Hsup, 0xFF, hbytes, stream);
  {
    int nblk = 5 * (S_LEN / 256) + 5 * (Q_TOT / 256);   // 320 + 6400
    k_hfill<<<nblk, 256, 0, stream>>>(meta, Jsup, Jqry, Hsup, Hqry);
  }
  k_chase<<<10, 256, 0, stream>>>(meta, sup_list, qry_list, Hsup, Hqry, sel);
  k_gather<<<80, 256, 0, stream>>>(f_s, f_q, meta, sel, xa, xb);
  k_gram<<<140, 256, 0, stream>>>(xa, xb, Ga, Gb, Gab);
  k_diag<<<10, 256, 0, stream>>>(Ga, Gb, diagA, diagB);
  k_conv<<<280, 256, 0, stream>>>(Ga, Gb, Gab, diagA, diagB);

  hipMemsetAsync(bufAll, 0, (size_t)MPASSES * 25 * 16 * 4, stream);
  hipMemsetAsync(zcArr, 0, 25 * 4, stream);
  hipMemsetAsync(mmdsum, 0, 25 * 3 * 8, stream);
  for (int t = 0; t < MPASSES; ++t)
    k_medpass<<<25 * MSHARDS, 256, 0, stream>>>(t, meta, Ga, Gb, Gab,
                                                bufAll, loArr, baseArr, zcArr);
  k_rbf<<<25 * MSHARDS, 256, 0, stream>>>(meta, Ga, Gb, Gab,
                                          bufAll, loArr, baseArr, zcArr, mmdsum);
  k_final<<<1, 64, 0, stream>>>(meta, mmdsum, out);
}

// Round 16
// 744.444 us; speedup vs baseline: 1.0718x; 1.0242x over previous
//
#include <hip/hip_runtime.h>

// ============================================================================
// numpy RNG replication: SeedSequence + PCG64 (XSL-RR 128/64), next32 buffering
// ============================================================================
struct U128 { unsigned long long hi, lo; };

__device__ __forceinline__ U128 u128_mul(U128 a, U128 b) {
  U128 r;
  r.lo = a.lo * b.lo;
  r.hi = __umul64hi(a.lo, b.lo) + a.hi * b.lo + a.lo * b.hi;
  return r;
}
__device__ __forceinline__ U128 u128_add(U128 a, U128 b) {
  U128 r; r.lo = a.lo + b.lo; r.hi = a.hi + b.hi + (r.lo < a.lo ? 1ull : 0ull); return r;
}

struct Pcg64 {
  U128 state, inc;
};

__device__ __forceinline__ void pcg_step(Pcg64* r) {
  const U128 M = {0x2360ed051fc65da4ull, 0x4385df649fccf645ull};
  r->state = u128_add(u128_mul(r->state, M), r->inc);
}
__device__ __forceinline__ unsigned long long pcg_next64(Pcg64* r) {
  pcg_step(r);
  unsigned int rot = (unsigned int)(r->state.hi >> 58);   // state >> 122
  unsigned long long x = r->state.hi ^ r->state.lo;       // XSL
  return (x >> rot) | (x << ((64u - rot) & 63u));         // RR
}

// SeedSequence constants (numpy bit_generator.pyx)
__device__ __forceinline__ unsigned int ss_hashmix(unsigned int v, unsigned int* hc) {
  v ^= *hc; *hc = *hc * 0x931e8875u; v *= *hc; v ^= v >> 16; return v;
}
__device__ __forceinline__ unsigned int ss_mix(unsigned int x, unsigned int y) {
  unsigned int r = x * 0xca01f9ddu ^ y * 0x4973f715u; r ^= r >> 16; return r;
}
__device__ void pcg_seed(Pcg64* rng, unsigned int seed) {
  unsigned int pool[4]; unsigned int hc = 0x43b0d7e5u;   // INIT_A
  pool[0] = ss_hashmix(seed, &hc);
  for (int i = 1; i < 4; ++i) pool[i] = ss_hashmix(0u, &hc);
  for (int s = 0; s < 4; ++s)
    for (int d = 0; d < 4; ++d)
      if (s != d) pool[d] = ss_mix(pool[d], ss_hashmix(pool[s], &hc));
  unsigned int hc2 = 0x8b51f9ddu;                        // INIT_B
  unsigned long long w64[4];
  for (int i = 0; i < 4; ++i) {
    unsigned int lo = pool[(2*i) & 3];
    lo ^= hc2; hc2 *= 0x58f38dedu; lo *= hc2; lo ^= lo >> 16;
    unsigned int hi = pool[(2*i+1) & 3];
    hi ^= hc2; hc2 *= 0x58f38dedu; hi *= hc2; hi ^= hi >> 16;
    w64[i] = (unsigned long long)lo | ((unsigned long long)hi << 32);
  }
  U128 initstate = {w64[0], w64[1]};   // PCG_128BIT_CONSTANT(seed[0], seed[1]): [0] is HIGH
  U128 initseq   = {w64[2], w64[3]};
  rng->inc.hi = (initseq.hi << 1) | (initseq.lo >> 63);
  rng->inc.lo = (initseq.lo << 1) | 1ull;
  rng->state.hi = 0; rng->state.lo = 0;
  pcg_step(rng);
  rng->state = u128_add(rng->state, initstate);
  pcg_step(rng);
}

// affine jump-ahead: state <- A^delta * state + (A^delta-1)/(A-1)*inc
__device__ void pcg_advance(Pcg64* r, unsigned long long delta) {
  U128 acc_mult = {0ull, 1ull}, acc_plus = {0ull, 0ull};
  U128 cur_mult = {0x2360ed051fc65da4ull, 0x4385df649fccf645ull};
  U128 cur_plus = r->inc;
  while (delta) {
    if (delta & 1ull) {
      acc_mult = u128_mul(acc_mult, cur_mult);
      acc_plus = u128_add(u128_mul(acc_plus, cur_mult), cur_plus);
    }
    U128 one = {0ull, 1ull};
    U128 cm1 = u128_add(cur_mult, one);
    cur_plus = u128_mul(cm1, cur_plus);
    cur_mult = u128_mul(cur_mult, cur_mult);
    delta >>= 1;
  }
  r->state = u128_add(u128_mul(r->state, acc_mult), acc_plus);
}

// ============================================================================
// Problem constants
// ============================================================================
#define S_LEN   16384
#define Q_LEN   65536
#define Q_TOT   327680     // 5*65536
#define DFEAT   256
#define MAXS    256
#define CAPS64  24576
#define CAPQ64  98304
#define TILE    4096
#define STILES  (S_LEN / TILE)    // 4
#define QTILES  (Q_TOT / TILE)    // 80
#define NBLK_C  (5 * STILES + 5 * QTILES)   // 420
#define MSHARDS 8
#define MPASSES 8

// meta layout: [0..4]=ns_full, [5..9]=nq_full, [10..14]=na, [15..19]=nb

__constant__ int c_kshift[MPASSES] = {27, 23, 19, 15, 11, 7, 3, 0};

// ============================================================================
// KA (431 blocks x 256): independent work merged for concurrency.
//   blocks 0..419  : per-tile label match counts
//   blocks 420..429: PCG draw-stream generation
//   block  430     : zero the med-select buffers
// ============================================================================
__global__ __launch_bounds__(256) void kA(const int* __restrict__ ls,
                                          const int* __restrict__ lq,
                                          int* __restrict__ cnts,
                                          unsigned int* __restrict__ draws,
                                          unsigned int* __restrict__ zbuf,
                                          int zwords) {
  int b = blockIdx.x; int tid = threadIdx.x;
  if (b < NBLK_C) {
    const int* src; int matchval;
    if (b < 5 * STILES) {
      int cls = b / STILES, tl = b % STILES;
      src = ls + cls * S_LEN + tl * TILE; matchval = 1;
    } else {
      int bb = b - 5 * STILES; int cls = bb / QTILES, tl = bb % QTILES;
      src = lq + tl * TILE; matchval = cls + 1;
    }
    int cnt = 0;
    for (int k = 0; k < TILE; k += 256) cnt += (src[k + tid] == matchval) ? 1 : 0;
    __shared__ int red[256];
    red[tid] = cnt; __syncthreads();
    for (int s = 128; s > 0; s >>= 1) { if (tid < s) red[tid] += red[tid + s]; __syncthreads(); }
    if (tid == 0) cnts[b] = red[0];
  } else if (b < NBLK_C + 10) {
    int t = b - NBLK_C; int cls = t % 5; int isq = t / 5;
    unsigned int seed = (unsigned)(1000 + isq * 1000 + cls + 1);
    unsigned long long cap64 = isq ? CAPQ64 : CAPS64;
    unsigned int* dst = draws + (isq ? (10ull * CAPS64 + (unsigned long long)cls * 2 * CAPQ64)
                                     : ((unsigned long long)cls * 2 * CAPS64));
    Pcg64 rng; pcg_seed(&rng, seed);
    unsigned long long C = cap64 / 256ull;     // 96 or 384
    unsigned long long k0 = (unsigned long long)tid * C;
    pcg_advance(&rng, k0);
    uint2* d2 = (uint2*)dst;
    for (unsigned long long m = 0; m < C; ++m) {
      unsigned long long o = pcg_next64(&rng);
      d2[k0 + m] = make_uint2((unsigned int)o, (unsigned int)(o >> 32));
    }
  } else {
    for (int k = tid; k < zwords; k += 256) zbuf[k] = 0u;
  }
}

// ============================================================================
// K1b: tiny scan: exclusive offsets per class + meta totals
// ============================================================================
__global__ void k_scan(const int* __restrict__ cnts, int* __restrict__ offs,
                       int* __restrict__ meta) {
  int t = threadIdx.x;
  if (t < 5) {
    int base = 0;
    for (int k = 0; k < STILES; ++k) {
      offs[t * STILES + k] = base; base += cnts[t * STILES + k];
    }
    meta[t] = base;
    meta[10 + t] = base < MAXS ? base : MAXS;
  } else if (t < 10) {
    int c = t - 5; int base = 0;
    for (int k = 0; k < QTILES; ++k) {
      int idx = 5 * STILES + c * QTILES + k;
      offs[idx] = base; base += cnts[idx];
    }
    meta[5 + c] = base;
    meta[15 + c] = base < MAXS ? base : MAXS;
  }
}

// ============================================================================
// consume device body (R10 config: depth-8 pipeline + LDS J ring; 336 us)
// ============================================================================
__device__ __forceinline__ bool consume_chunk(unsigned int v, int& i, int n, int lane,
                                              unsigned long long lmask,
                                              unsigned long long lbit,
                                              unsigned int* __restrict__ ring) {
  unsigned long long rej = 0ull, acc = 0ull;
  for (;;) {
    unsigned long long unc = ~(rej | acc);
    int rbelow = __popcll(rej & lmask);
    int ubelow = __popcll(unc & lmask);
    int il_min = i - lane + rbelow;          // >= 193 always
    int il_max = il_min + ubelow;
    bool unres = (unc & lbit) != 0ull;
    unsigned int mlo = 0xFFFFFFFFu >> __clz(il_min);
    unsigned int mhi = 0xFFFFFFFFu >> __clz(il_max);
    unsigned int w = v & mlo;
    bool def_rej, hard;
    if (mlo == mhi) {
      def_rej = w > (unsigned int)il_max;
      hard = !def_rej && (w > (unsigned int)il_min);   // middle band
    } else if (ubelow == 0) {                // octave boundary: exact resolve
      def_rej = w > (unsigned int)il_min;
      hard = false;
    } else {
      def_rej = false;
      hard = true;                           // boundary-spanning, wait
    }
    def_rej = def_rej && unres;
    hard = hard && unres;
    unsigned long long nr = __ballot(def_rej);
    unsigned long long hd = __ballot(hard);
    rej |= nr;
    acc |= unc & ~nr & ~hd;
    if (!hd) break;
  }
  int rbelow = __popcll(rej & lmask);
  int il = i - lane + rbelow;
  int totAcc = 64 - __popcll(rej);
  if ((acc & lbit) && il >= MAXS) {
    int g = (n - 1) - il;
    ring[g & 4095] = v & (0xFFFFFFFFu >> __clz(il));
  }
  int needed = i - (MAXS - 1);
  if (totAcc >= needed) return true;
  i -= totAcc;
  return false;
}

__device__ void consume_body(int t, const int* __restrict__ meta,
                             const unsigned int* __restrict__ draws,
                             int* Jsup, int* Jqry,
                             unsigned int* __restrict__ ring) {
  int cls = t % 5; int isq = t / 5;
  int n = meta[isq * 5 + cls];
  if (n <= MAXS) return;
  const unsigned int* d = draws + (isq ? (10ull * CAPS64 + (unsigned long long)cls * 2 * CAPQ64)
                                       : ((unsigned long long)cls * 2 * CAPS64));
  int* J = isq ? (Jqry + (size_t)cls * Q_TOT) : (Jsup + cls * S_LEN);
  int lane = threadIdx.x;                    // 0..63 (wave 0 only)
  unsigned long long lmask = (1ull << lane) - 1ull;
  unsigned long long lbit  = (1ull << lane);
  int i = n - 1;
  size_t p = 0;
  int flushed = 0;
  const int cap = n - MAXS;                 // J entries with il in [256, n-1]
  unsigned int v0 = d[lane],       v1 = d[64 + lane];
  unsigned int v2 = d[128 + lane], v3 = d[192 + lane];
  unsigned int v4 = d[256 + lane], v5 = d[320 + lane];
  unsigned int v6 = d[384 + lane], v7 = d[448 + lane];
  for (;;) {
    unsigned int nv0 = d[p + 512 + lane];
    unsigned int nv1 = d[p + 576 + lane];
    unsigned int nv2 = d[p + 640 + lane];
    unsigned int nv3 = d[p + 704 + lane];
    unsigned int nv4 = d[p + 768 + lane];
    unsigned int nv5 = d[p + 832 + lane];
    unsigned int nv6 = d[p + 896 + lane];
    unsigned int nv7 = d[p + 960 + lane];
    bool done;
    if      (consume_chunk(v0, i, n, lane, lmask, lbit, ring)) done = true;
    else if (consume_chunk(v1, i, n, lane, lmask, lbit, ring)) done = true;
    else if (consume_chunk(v2, i, n, lane, lmask, lbit, ring)) done = true;
    else if (consume_chunk(v3, i, n, lane, lmask, lbit, ring)) done = true;
    else if (consume_chunk(v4, i, n, lane, lmask, lbit, ring)) done = true;
    else if (consume_chunk(v5, i, n, lane, lmask, lbit, ring)) done = true;
    else if (consume_chunk(v6, i, n, lane, lmask, lbit, ring)) done = true;
    else if (consume_chunk(v7, i, n, lane, lmask, lbit, ring)) done = true;
    else done = false;
    if (done) break;
    // flush full 2048-entry blocks (coalesced descending J, fire-and-forget)
    int avail = (n - 1) - i; if (avail > cap) avail = cap;
    while (avail - flushed >= 2048) {
      #pragma unroll
      for (int k = 0; k < 32; ++k) {
        int g = flushed + k * 64 + lane;
        J[(n - 1) - g] = (int)ring[g & 4095];
      }
      flushed += 2048;
    }
    p += 512;
    v0 = nv0; v1 = nv1; v2 = nv2; v3 = nv3;
    v4 = nv4; v5 = nv5; v6 = nv6; v7 = nv7;
  }
  // final flush: every il in [256, n-1] has been staged
  for (int g = flushed + lane; g < cap; g += 64)
    J[(n - 1) - g] = (int)ring[g & 4095];
}

// ============================================================================
// KB (430 blocks x 256): independent work merged for concurrency.
//   blocks 0..419  : stable compaction write (needs offs only)
//   blocks 420..429: consume automaton, wave 0 only (needs meta + draws only)
// ============================================================================
__global__ __launch_bounds__(256) void kB(const int* __restrict__ ls,
                                          const int* __restrict__ lq,
                                          const int* __restrict__ offs,
                                          const int* __restrict__ meta,
                                          const unsigned int* __restrict__ draws,
                                          int* __restrict__ sup_list,
                                          int* __restrict__ qry_list,
                                          int* __restrict__ Jsup,
                                          int* __restrict__ Jqry) {
  __shared__ unsigned int ring[4096];   // used by consume blocks only
  __shared__ int wcnt[4];               // used by write blocks only
  int b = blockIdx.x; int tid = threadIdx.x;
  if (b < NBLK_C) {
    const int* src; int matchval; int* out; int ibase;
    if (b < 5 * STILES) {
      int cls = b / STILES, tl = b % STILES;
      src = ls + cls * S_LEN + tl * TILE; matchval = 1;
      out = sup_list + cls * S_LEN; ibase = tl * TILE;
    } else {
      int bb = b - 5 * STILES; int cls = bb / QTILES, tl = bb % QTILES;
      src = lq + tl * TILE; matchval = cls + 1;
      out = qry_list + (size_t)cls * Q_TOT; ibase = tl * TILE;
    }
    int w = tid >> 6, lane = tid & 63;
    unsigned long long lmask = (1ull << lane) - 1ull;
    int base = offs[b];
    for (int k = 0; k < TILE; k += 256) {
      int i = k + tid;
      bool p = (src[i] == matchval);
      unsigned long long m = __ballot(p);
      if (lane == 0) wcnt[w] = __popcll(m);
      __syncthreads();
      int prev = 0;
      #pragma unroll
      for (int ww = 0; ww < 4; ++ww) prev += (ww < w) ? wcnt[ww] : 0;
      int tot = wcnt[0] + wcnt[1] + wcnt[2] + wcnt[3];
      if (p) out[base + prev + __popcll(m & lmask)] = ibase + i;
      __syncthreads();
      base += tot;
    }
  } else {
    if (tid >= 64) return;               // wave 0 only; no __syncthreads below
    consume_body(b - NBLK_C, meta, draws, Jsup, Jqry, ring);
  }
}

// ============================================================================
// K3a: next-hitter index fill.  H[v] = min{ i > v, i in [256,n) : J[i] == v }
// ============================================================================
__global__ __launch_bounds__(256) void k_hfill(const int* __restrict__ meta,
                                               const int* __restrict__ Jsup,
                                               const int* __restrict__ Jqry,
                                               unsigned int* __restrict__ Hsup,
                                               unsigned int* __restrict__ Hqry) {
  const int SB = 5 * (S_LEN / 256);
  int b = blockIdx.x;
  int cls, i; const int* J; unsigned int* H; int n;
  if (b < SB) {
    cls = b / (S_LEN / 256);
    i = (b % (S_LEN / 256)) * 256 + threadIdx.x;
    n = meta[cls];
    J = Jsup + cls * S_LEN; H = Hsup + cls * S_LEN;
  } else {
    b -= SB;
    cls = b / (Q_TOT / 256);
    i = (b % (Q_TOT / 256)) * 256 + threadIdx.x;
    n = meta[5 + cls];
    J = Jqry + (size_t)cls * Q_TOT; H = Hqry + (size_t)cls * Q_TOT;
  }
  if (i < MAXS || i >= n) return;
  int j = J[i];
  if (j != i) atomicMin(&H[j], (unsigned int)i);
}

// ============================================================================
// K3b: chase.  sel[t][s] = list[ c(s) ]
// ============================================================================
__global__ __launch_bounds__(256) void k_chase(const int* __restrict__ meta,
                                               const int* __restrict__ sup_list,
                                               const int* __restrict__ qry_list,
                                               const unsigned int* __restrict__ Hsup,
                                               const unsigned int* __restrict__ Hqry,
                                               int* sel) {
  int t = blockIdx.x; int tid = threadIdx.x;
  int cls = t % 5; int isq = t / 5;
  int n = meta[isq * 5 + cls];
  const int* list; const unsigned int* H;
  if (!isq) { list = sup_list + cls * S_LEN; H = Hsup + cls * S_LEN; }
  else      { list = qry_list + (size_t)cls * Q_TOT; H = Hqry + (size_t)cls * Q_TOT; }
  int* s = sel + t * MAXS;
  if (n <= MAXS) { if (tid < n) s[tid] = list[tid]; return; }
  unsigned int v = (unsigned int)tid;
  unsigned int h = H[v];
  while (h != 0xFFFFFFFFu) { v = h; h = H[v]; }
  s[tid] = list[v];
}

// ============================================================================
// K4: gather selected feature rows + fused row-norm (x / (||x|| + 1e-12)).
// ============================================================================
__global__ __launch_bounds__(256) void k_gather(const float* __restrict__ f_s,
                                                const float* __restrict__ f_q,
                                                const int* __restrict__ meta,
                                                const int* __restrict__ sel,
                                                float* xa, float* xb) {
  int blk = blockIdx.x;
  int t = blk >> 3;          // class-pair 0..9
  int slab = blk & 7;        // 8 slabs x 32 rows
  int cls = t % 5; int isq = t / 5;
  int n = meta[10 + isq * 5 + cls];
  int tid = threadIdx.x;
  int row = slab * 32 + (tid >> 3);
  int dg = tid & 7;          // 8 d-groups of 32
  if (row >= n) return;      // group-uniform (8 lanes share row)
  int id = sel[t * MAXS + row];
  const float* src; size_t stride; float* dst;
  if (!isq) {
    src = f_s + (size_t)cls * DFEAT * S_LEN + id; stride = S_LEN;
    dst = xa + cls * (MAXS * DFEAT) + row * DFEAT;
  } else {
    int m = id >> 16; int nn = id & 0xFFFF;
    src = f_q + (size_t)m * DFEAT * Q_LEN + nn; stride = Q_LEN;
    dst = xb + cls * (MAXS * DFEAT) + row * DFEAT;
  }
  float v[32];
  #pragma unroll
  for (int dd = 0; dd < 32; ++dd)
    v[dd] = src[(size_t)(dg * 32 + dd) * stride];
  float ss = 0.f;
  #pragma unroll
  for (int dd = 0; dd < 32; ++dd) ss += v[dd] * v[dd];
  ss += __shfl_xor(ss, 1);
  ss += __shfl_xor(ss, 2);
  ss += __shfl_xor(ss, 4);
  float inv = 1.0f / (sqrtf(ss) + 1e-12f);
  #pragma unroll
  for (int dd = 0; dd < 32; ++dd) dst[dg * 32 + dd] = v[dd] * inv;
}

// ============================================================================
// K5: 35 Gram matrices (256x256, K=256), 128x128 tiles -> 140 blocks.
// ============================================================================
__global__ __launch_bounds__(256) void k_gram(const float* __restrict__ xa,
                                              const float* __restrict__ xb,
                                              float* Ga, float* Gb, float* Gab) {
  int b = blockIdx.x;
  int j = b >> 2; int tile = b & 3;
  int tr = (tile >> 1) * 128, tc = (tile & 1) * 128;
  const float *A, *B; float* G;
  if (j < 5)       { A = xa + j * 65536; B = A; G = Ga + j * 65536; }
  else if (j < 10) { int c = j - 5; A = xb + c * 65536; B = A; G = Gb + c * 65536; }
  else             { int p = j - 10; int k = p / 5, c = p % 5;
                     A = xa + k * 65536; B = xb + c * 65536; G = Gab + p * 65536; }
  __shared__ float As[128][33];
  __shared__ float Bs[128][33];
  int tid = threadIdx.x;
  int w = tid >> 6, lane = tid & 63;
  int wr = w >> 1, wc = w & 1;
  int lr = lane >> 3, lc = lane & 7;
  int orow = wr * 64 + lr * 8;     // within-tile output row base
  int ocol = wc * 64 + lc * 8;     // within-tile output col base
  float acc[8][8];
  #pragma unroll
  for (int r = 0; r < 8; ++r)
    #pragma unroll
    for (int s = 0; s < 8; ++s) acc[r][s] = 0.f;

  for (int k0 = 0; k0 < 256; k0 += 32) {
    #pragma unroll
    for (int e = 0; e < 4; ++e) {
      int idx = tid + e * 256;          // 0..1023
      int row = idx >> 3;               // 0..127
      int c4  = idx & 7;                // float4 slot in 32-k chunk
      float4 va = *(const float4*)(A + (size_t)(tr + row) * 256 + k0 + c4 * 4);
      As[row][c4 * 4 + 0] = va.x; As[row][c4 * 4 + 1] = va.y;
      As[row][c4 * 4 + 2] = va.z; As[row][c4 * 4 + 3] = va.w;
      float4 vb = *(const float4*)(B + (size_t)(tc + row) * 256 + k0 + c4 * 4);
      Bs[row][c4 * 4 + 0] = vb.x; Bs[row][c4 * 4 + 1] = vb.y;
      Bs[row][c4 * 4 + 2] = vb.z; Bs[row][c4 * 4 + 3] = vb.w;
    }
    __syncthreads();
    #pragma unroll 4
    for (int kk = 0; kk < 32; ++kk) {
      float a[8], bv[8];
      #pragma unroll
      for (int r = 0; r < 8; ++r) a[r] = As[orow + r][kk];
      #pragma unroll
      for (int s = 0; s < 8; ++s) bv[s] = Bs[ocol + s][kk];
      #pragma unroll
      for (int r = 0; r < 8; ++r)
        #pragma unroll
        for (int s = 0; s < 8; ++s) acc[r][s] += a[r] * bv[s];
    }
    __syncthreads();
  }
  #pragma unroll
  for (int r = 0; r < 8; ++r) {
    float* grow = G + (size_t)(tr + orow + r) * 256 + tc + ocol;
    *(float4*)(grow + 0) = make_float4(acc[r][0], acc[r][1], acc[r][2], acc[r][3]);
    *(float4*)(grow + 4) = make_float4(acc[r][4], acc[r][5], acc[r][6], acc[r][7]);
  }
}

// ============================================================================
// K6: extract Gram diagonals
// ============================================================================
__global__ __launch_bounds__(256) void k_diag(const float* __restrict__ Ga,
                                              const float* __restrict__ Gb,
                                              float* diagA, float* diagB) {
  int t = blockIdx.x; int i = threadIdx.x;
  if (t < 5) diagA[t * 256 + i] = Ga[t * 65536 + i * 257];
  else { int c = t - 5; diagB[c * 256 + i] = Gb[c * 65536 + i * 257]; }
}

// ============================================================================
// K7: G -> D in place (280 blocks: 35 matrices x 8 row-slabs)
// ============================================================================
__global__ __launch_bounds__(256) void k_conv(float* Ga, float* Gb, float* Gab,
                                              const float* __restrict__ diagA,
                                              const float* __restrict__ diagB) {
  int b = blockIdx.x; int j = b >> 3; int slab = b & 7; int tid = threadIdx.x;
  float* G; const float *dA, *dB;
  if (j < 5)       { G = Ga + j * 65536; dA = diagA + j * 256; dB = dA; }
  else if (j < 10) { int c = j - 5; G = Gb + c * 65536; dA = diagB + c * 256; dB = dA; }
  else             { int p = j - 10; int k = p / 5, c = p % 5;
                     G = Gab + p * 65536; dA = diagA + k * 256; dB = diagB + c * 256; }
  float db = dB[tid];
  for (int i = slab * 32; i < slab * 32 + 32; ++i) {
    float g = G[i * 256 + tid];
    float d = dA[i] + db - 2.0f * g;
    G[i * 256 + tid] = d > 0.f ? d : 0.f;
  }
}

// ============================================================================
// K8: grid-parallel 16-ary exact radix-select, one kernel per pass.
// ============================================================================
__device__ __forceinline__ void med_select(const unsigned int* __restrict__ c,
                                           unsigned int lprev, unsigned int bprev,
                                           unsigned int r, int kprev,
                                           unsigned int* lo, unsigned int* base) {
  int j = 15;
  #pragma unroll
  for (int q = 14; q >= 0; --q)
    if (bprev + c[q] > r) j = q;
  *lo = lprev + ((unsigned int)j << kprev);
  *base = (j == 0) ? bprev : bprev + c[j - 1];
}

__global__ __launch_bounds__(256) void k_medpass(int t,
                                                 const int* __restrict__ meta,
                                                 const float* __restrict__ Da_all,
                                                 const float* __restrict__ Db_all,
                                                 const float* __restrict__ Dab_all,
                                                 unsigned int* __restrict__ bufAll,  // [MPASSES][25][16]
                                                 unsigned int* __restrict__ loArr,   // [MPASSES][25]
                                                 unsigned int* __restrict__ baseArr, // [MPASSES][25]
                                                 unsigned int* __restrict__ zcArr) { // [25]
  int b = blockIdx.x;
  int p = b / MSHARDS, sh = b % MSHARDS;
  int kcl = p / 5, ccl = p % 5;
  int tid = threadIdx.x;
  int nsf = meta[kcl], nqf = meta[5 + ccl];
  if (nsf < 2 || nqf < 2) return;
  int na = meta[10 + kcl], nb = meta[15 + ccl];
  const float4* A4 = (const float4*)(Da_all + kcl * 65536);
  const float4* B4 = (const float4*)(Db_all + ccl * 65536);
  const float4* C4 = (const float4*)(Dab_all + p * 65536);

  __shared__ unsigned int sh_lo[1], sh_base[1];
  __shared__ unsigned int wred[4][16];
  __shared__ unsigned int wzc[4];

  int ks = c_kshift[t];
  unsigned int N = (unsigned int)(na + nb) * (unsigned int)(na + nb);

  if (tid == 0) {
    unsigned int lo = 0, base = 0;
    if (t > 0) {
      unsigned int nz = zcArr[p];
      if (nz < N) {
        unsigned int r = nz + (N - nz - 1u) / 2u;
        unsigned int cprev[15];
        const unsigned int* cp = bufAll + ((size_t)(t - 1) * 25 + p) * 16;
        #pragma unroll
        for (int q = 0; q < 15; ++q) cprev[q] = cp[q];
        med_select(cprev, loArr[(t - 1) * 25 + p], baseArr[(t - 1) * 25 + p],
                   r, c_kshift[t - 1], &lo, &base);
      }
    }
    sh_lo[0] = lo; sh_base[0] = base;
    if (sh == 0) { loArr[t * 25 + p] = lo; baseArr[t * 25 + p] = base; }
  }
  __syncthreads();
  unsigned int lo = sh_lo[0];

  unsigned int cnt[15];
  #pragma unroll
  for (int j = 0; j < 15; ++j) cnt[j] = 0;
  unsigned int zc = 0;
  unsigned int span = 16u << ks;   // ks<=27 -> fits u32 (16<<27 = 2^31)

  #define PROC_MAT(M4, nr, nc, W)                                             \
    for (int m = 0; m < 8; ++m) {                                             \
      int fidx = sh * 2048 + m * 256 + tid;                                   \
      float4 v = M4[fidx];                                                    \
      int row = fidx >> 6; int col0 = (fidx & 63) << 2;                       \
      unsigned int kb[4] = {__float_as_uint(v.x), __float_as_uint(v.y),       \
                            __float_as_uint(v.z), __float_as_uint(v.w)};      \
      _Pragma("unroll")                                                       \
      for (int cc = 0; cc < 4; ++cc) {                                        \
        bool valid = (row < (nr)) && (col0 + cc < (nc));                      \
        unsigned int key = kb[cc];                                            \
        if (t == 0) zc += (valid && key == 0u) ? (W) : 0u;                    \
        unsigned int d = key - lo;                                            \
        bool in = valid && (key >= lo) && (d < span);                         \
        _Pragma("unroll")                                                     \
        for (int j = 0; j < 15; ++j)                                          \
          cnt[j] += (in && d < ((unsigned int)(j + 1) << ks)) ? (W) : 0u;     \
      }                                                                       \
    }

  PROC_MAT(A4, na, na, 1u)
  PROC_MAT(B4, nb, nb, 1u)
  PROC_MAT(C4, na, nb, 2u)
  #undef PROC_MAT

  // wave-level reduce then cross-wave
  #pragma unroll
  for (int j = 0; j < 15; ++j)
    for (int o = 32; o > 0; o >>= 1) cnt[j] += __shfl_down(cnt[j], o);
  if (t == 0)
    for (int o = 32; o > 0; o >>= 1) zc += __shfl_down(zc, o);
  int w = tid >> 6, lane = tid & 63;
  if (lane == 0) {
    #pragma unroll
    for (int j = 0; j < 15; ++j) wred[w][j] = cnt[j];
    wzc[w] = zc;
  }
  __syncthreads();
  if (tid < 15) {
    unsigned int s = wred[0][tid] + wred[1][tid] + wred[2][tid] + wred[3][tid];
    atomicAdd(&bufAll[((size_t)t * 25 + p) * 16 + tid], s);
  }
  if (t == 0 && tid == 15) {
    unsigned int s = wzc[0] + wzc[1] + wzc[2] + wzc[3];
    atomicAdd(&zcArr[p], s);
  }
}

// ============================================================================
// K8b: RBF partial sums (200 blocks), sigma from final select
// ============================================================================
__global__ __launch_bounds__(256) void k_rbf(const int* __restrict__ meta,
                                             const float* __restrict__ Da_all,
                                             const float* __restrict__ Db_all,
                                             const float* __restrict__ Dab_all,
                                             const unsigned int* __restrict__ bufAll,
                                             const unsigned int* __restrict__ loArr,
                                             const unsigned int* __restrict__ baseArr,
                                             const unsigned int* __restrict__ zcArr,
                                             double* __restrict__ mmdsum) { // [25][3]
  int b = blockIdx.x;
  int p = b / MSHARDS, sh = b % MSHARDS;
  int kcl = p / 5, ccl = p % 5;
  int tid = threadIdx.x;
  int nsf = meta[kcl], nqf = meta[5 + ccl];
  if (nsf < 2 || nqf < 2) return;
  int na = meta[10 + kcl], nb = meta[15 + ccl];
  const float4* A4 = (const float4*)(Da_all + kcl * 65536);
  const float4* B4 = (const float4*)(Db_all + ccl * 65536);
  const float4* C4 = (const float4*)(Dab_all + p * 65536);

  unsigned int N = (unsigned int)(na + nb) * (unsigned int)(na + nb);
  unsigned int nz = zcArr[p];
  float base_s;
  if (nz >= N) base_s = 1.0f;
  else {
    unsigned int r = nz + (N - nz - 1u) / 2u;
    unsigned int cprev[15];
    const unsigned int* cp = bufAll + ((size_t)(MPASSES - 1) * 25 + p) * 16;
    #pragma unroll
    for (int q = 0; q < 15; ++q) cprev[q] = cp[q];
    unsigned int lo, bs;
    med_select(cprev, loArr[(MPASSES - 1) * 25 + p], baseArr[(MPASSES - 1) * 25 + p],
               r, 0, &lo, &bs);
    base_s = sqrtf(__uint_as_float(lo) + 1e-6f);
  }
  float g2 = base_s * base_s;
  float c0 = 1.0f / (2.0f * g2 * 0.25f);
  float c1 = 1.0f / (2.0f * g2 * 1.0f);
  float c2 = 1.0f / (2.0f * g2 * 4.0f);
  float c3 = 1.0f / (2.0f * g2 * 16.0f);

  double accA = 0.0, accB = 0.0, accAB = 0.0;
  #define RBF_MAT(M4, nr, nc, ACC)                                            \
    for (int m = 0; m < 8; ++m) {                                             \
      int fidx = sh * 2048 + m * 256 + tid;                                   \
      float4 v = M4[fidx];                                                    \
      int row = fidx >> 6; int col0 = (fidx & 63) << 2;                       \
      float vv[4] = {v.x, v.y, v.z, v.w};                                     \
      _Pragma("unroll")                                                       \
      for (int cc = 0; cc < 4; ++cc) {                                        \
        if ((row < (nr)) && (col0 + cc < (nc))) {                             \
          float d = vv[cc];                                                   \
          ACC += (double)(expf(-d * c0) + expf(-d * c1)                       \
                        + expf(-d * c2) + expf(-d * c3));                     \
        }                                                                     \
      }                                                                       \
    }
  RBF_MAT(A4, na, na, accA)
  RBF_MAT(B4, nb, nb, accB)
  RBF_MAT(C4, na, nb, accAB)
  #undef RBF_MAT

  for (int o = 32; o > 0; o >>= 1) {
    accA += __shfl_down(accA, o);
    accB += __shfl_down(accB, o);
    accAB += __shfl_down(accAB, o);
  }
  __shared__ double wsum[4][3];
  int w = tid >> 6, lane = tid & 63;
  if (lane == 0) { wsum[w][0] = accA; wsum[w][1] = accB; wsum[w][2] = accAB; }
  __syncthreads();
  if (tid == 0) {
    double sA = wsum[0][0] + wsum[1][0] + wsum[2][0] + wsum[3][0];
    double sB = wsum[0][1] + wsum[1][1] + wsum[2][1] + wsum[3][1];
    double sC = wsum[0][2] + wsum[1][2] + wsum[2][2] + wsum[3][2];
    atomicAdd(&mmdsum[p * 3 + 0], sA);
    atomicAdd(&mmdsum[p * 3 + 1], sB);
    atomicAdd(&mmdsum[p * 3 + 2], sC);
  }
}

// ============================================================================
// K9: final weighted loss (mmd assembled from sums)
// ============================================================================
__global__ void k_final(const int* __restrict__ meta, const double* __restrict__ mmdsum,
                        float* out) {
  if (threadIdx.x != 0 || blockIdx.x != 0) return;
  double total = 0.0, vw = 0.0;
  for (int c = 0; c < 5; ++c) {
    int nsf = meta[c], nqf = meta[5 + c];
    if (nsf < 2 || nqf < 2) continue;
    int nbq = meta[15 + c];
    double mm[5];
    for (int k = 0; k < 5; ++k) {
      if (meta[k] < 2) { mm[k] = 0.0; continue; }
      int naa = meta[10 + k];
      int pp = k * 5 + c;
      double meanA  = mmdsum[pp * 3 + 0] / ((double)naa * (double)naa);
      double meanB  = mmdsum[pp * 3 + 1] / ((double)nbq * (double)nbq);
      double meanAB = mmdsum[pp * 3 + 2] / ((double)naa * (double)nbq);
      double m = meanA + meanB - 2.0 * meanAB;
      mm[k] = m > 0.0 ? m : 0.0;
    }
    double pos = mm[c];
    bool any = false; double best = 0.0;
    for (int k = 0; k < 5; ++k) {
      if (k == c || meta[k] < 2) continue;
      if (!any || mm[k] < best) { best = mm[k]; any = true; }
    }
    double lc = any ? fmax(pos - best + 0.1, 0.0) : pos;
    double w = sqrt((double)nsf * (double)nqf);
    total += w * lc; vw += w;
  }
  out[0] = (float)(0.1 * total / fmax(vw, 1e-12));
}

// ============================================================================
// host launcher
// ============================================================================
extern "C" void kernel_launch(void* const* d_in, const int* in_sizes, int n_in,
                              void* d_out, int out_size, void* d_ws, size_t ws_size,
                              hipStream_t stream) {
  const float* f_s = (const float*)d_in[0];
  const int*   l_s = (const int*)d_in[1];
  const float* f_q = (const float*)d_in[2];
  const int*   l_q = (const int*)d_in[3];
  float* out = (float*)d_out;
  char* ws = (char*)d_ws;

  size_t off = 0;
  auto take = [&](size_t bytes) -> void* {
    void* p = ws + off;
    off = (off + bytes + 255) & ~(size_t)255;
    return p;
  };
  int*   meta     = (int*)take(32 * 4);
  int*   cnts     = (int*)take(NBLK_C * 4);
  int*   offs     = (int*)take(NBLK_C * 4);
  int*   sup_list = (int*)take((size_t)5 * S_LEN * 4);
  int*   qry_list = (int*)take((size_t)5 * Q_TOT * 4);
  int*   Jsup     = (int*)take((size_t)5 * S_LEN * 4);
  int*   Jqry     = (int*)take((size_t)5 * Q_TOT * 4);
  unsigned int* draws = (unsigned int*)take((10ull * CAPS64 + 10ull * CAPQ64) * 4);
  int*   sel      = (int*)take((size_t)10 * MAXS * 4);
  float* xa       = (float*)take((size_t)5 * 65536 * 4);
  float* xb       = (float*)take((size_t)5 * 65536 * 4);
  float* Ga       = (float*)take((size_t)5 * 65536 * 4);
  float* Gb       = (float*)take((size_t)5 * 65536 * 4);
  float* Gab      = (float*)take((size_t)25 * 65536 * 4);
  float* diagA    = (float*)take((size_t)5 * 256 * 4);
  float* diagB    = (float*)take((size_t)5 * 256 * 4);
  size_t zero0 = off;
  unsigned int* bufAll  = (unsigned int*)take((size_t)MPASSES * 25 * 16 * 4);
  unsigned int* loArr   = (unsigned int*)take((size_t)MPASSES * 25 * 4);
  unsigned int* baseArr = (unsigned int*)take((size_t)MPASSES * 25 * 4);
  unsigned int* zcArr   = (unsigned int*)take(25 * 4);
  double* mmdsum  = (double*)take(25 * 3 * 8);
  size_t zero1 = off;
  if (off > ws_size) return;

  // H (next-hitter) arrays alias the draws buffer — draws dead after kB.
  unsigned int* Hsup = draws;
  unsigned int* Hqry = draws + (size_t)5 * S_LEN;
  size_t hbytes = ((size_t)5 * S_LEN + (size_t)5 * Q_TOT) * 4;
  unsigned int* zbuf = (unsigned int*)(ws + zero0);
  int zwords = (int)((zero1 - zero0) / 4);

  kA<<<NBLK_C + 11, 256, 0, stream>>>(l_s, l_q, cnts, draws, zbuf, zwords);
  k_scan<<<1, 64, 0, stream>>>(cnts, offs, meta);
  kB<<<NBLK_C + 10, 256, 0, stream>>>(l_s, l_q, offs, meta, draws,
                                      sup_list, qry_list, Jsup, Jqry);
  hipMemsetAsync(Hsup, 0xFF, hbytes, stream);
  {
    int nblk = 5 * (S_LEN / 256) + 5 * (Q_TOT / 256);   // 320 + 6400
    k_hfill<<<nblk, 256, 0, stream>>>(meta, Jsup, Jqry, Hsup, Hqry);
  }
  k_chase<<<10, 256, 0, stream>>>(meta, sup_list, qry_list, Hsup, Hqry, sel);
  k_gather<<<80, 256, 0, stream>>>(f_s, f_q, meta, sel, xa, xb);
  k_gram<<<140, 256, 0, stream>>>(xa, xb, Ga, Gb, Gab);
  k_diag<<<10, 256, 0, stream>>>(Ga, Gb, diagA, diagB);
  k_conv<<<280, 256, 0, stream>>>(Ga, Gb, Gab, diagA, diagB);
  for (int t = 0; t < MPASSES; ++t)
    k_medpass<<<25 * MSHARDS, 256, 0, stream>>>(t, meta, Ga, Gb, Gab,
                                                bufAll, loArr, baseArr, zcArr);
  k_rbf<<<25 * MSHARDS, 256, 0, stream>>>(meta, Ga, Gb, Gab,
                                          bufAll, loArr, baseArr, zcArr, mmdsum);
  k_final<<<1, 64, 0, stream>>>(meta, mmdsum, out);
}

// Round 17
// 731.554 us; speedup vs baseline: 1.0906x; 1.0176x over previous
//
#include <hip/hip_runtime.h>

// ============================================================================
// numpy RNG replication: SeedSequence + PCG64 (XSL-RR 128/64), next32 buffering
// ============================================================================
struct U128 { unsigned long long hi, lo; };

__device__ __forceinline__ U128 u128_mul(U128 a, U128 b) {
  U128 r;
  r.lo = a.lo * b.lo;
  r.hi = __umul64hi(a.lo, b.lo) + a.hi * b.lo + a.lo * b.hi;
  return r;
}
__device__ __forceinline__ U128 u128_add(U128 a, U128 b) {
  U128 r; r.lo = a.lo + b.lo; r.hi = a.hi + b.hi + (r.lo < a.lo ? 1ull : 0ull); return r;
}

struct Pcg64 {
  U128 state, inc;
};

__device__ __forceinline__ void pcg_step(Pcg64* r) {
  const U128 M = {0x2360ed051fc65da4ull, 0x4385df649fccf645ull};
  r->state = u128_add(u128_mul(r->state, M), r->inc);
}
__device__ __forceinline__ unsigned long long pcg_next64(Pcg64* r) {
  pcg_step(r);
  unsigned int rot = (unsigned int)(r->state.hi >> 58);   // state >> 122
  unsigned long long x = r->state.hi ^ r->state.lo;       // XSL
  return (x >> rot) | (x << ((64u - rot) & 63u));         // RR
}

// SeedSequence constants (numpy bit_generator.pyx)
__device__ __forceinline__ unsigned int ss_hashmix(unsigned int v, unsigned int* hc) {
  v ^= *hc; *hc = *hc * 0x931e8875u; v *= *hc; v ^= v >> 16; return v;
}
__device__ __forceinline__ unsigned int ss_mix(unsigned int x, unsigned int y) {
  unsigned int r = x * 0xca01f9ddu ^ y * 0x4973f715u; r ^= r >> 16; return r;
}
__device__ void pcg_seed(Pcg64* rng, unsigned int seed) {
  unsigned int pool[4]; unsigned int hc = 0x43b0d7e5u;   // INIT_A
  pool[0] = ss_hashmix(seed, &hc);
  for (int i = 1; i < 4; ++i) pool[i] = ss_hashmix(0u, &hc);
  for (int s = 0; s < 4; ++s)
    for (int d = 0; d < 4; ++d)
      if (s != d) pool[d] = ss_mix(pool[d], ss_hashmix(pool[s], &hc));
  unsigned int hc2 = 0x8b51f9ddu;                        // INIT_B
  unsigned long long w64[4];
  for (int i = 0; i < 4; ++i) {
    unsigned int lo = pool[(2*i) & 3];
    lo ^= hc2; hc2 *= 0x58f38dedu; lo *= hc2; lo ^= lo >> 16;
    unsigned int hi = pool[(2*i+1) & 3];
    hi ^= hc2; hc2 *= 0x58f38dedu; hi *= hc2; hi ^= hi >> 16;
    w64[i] = (unsigned long long)lo | ((unsigned long long)hi << 32);
  }
  U128 initstate = {w64[0], w64[1]};   // PCG_128BIT_CONSTANT(seed[0], seed[1]): [0] is HIGH
  U128 initseq   = {w64[2], w64[3]};
  rng->inc.hi = (initseq.hi << 1) | (initseq.lo >> 63);
  rng->inc.lo = (initseq.lo << 1) | 1ull;
  rng->state.hi = 0; rng->state.lo = 0;
  pcg_step(rng);
  rng->state = u128_add(rng->state, initstate);
  pcg_step(rng);
}

// affine jump-ahead: state <- A^delta * state + (A^delta-1)/(A-1)*inc
__device__ void pcg_advance(Pcg64* r, unsigned long long delta) {
  U128 acc_mult = {0ull, 1ull}, acc_plus = {0ull, 0ull};
  U128 cur_mult = {0x2360ed051fc65da4ull, 0x4385df649fccf645ull};
  U128 cur_plus = r->inc;
  while (delta) {
    if (delta & 1ull) {
      acc_mult = u128_mul(acc_mult, cur_mult);
      acc_plus = u128_add(u128_mul(acc_plus, cur_mult), cur_plus);
    }
    U128 one = {0ull, 1ull};
    U128 cm1 = u128_add(cur_mult, one);
    cur_plus = u128_mul(cm1, cur_plus);
    cur_mult = u128_mul(cur_mult, cur_mult);
    delta >>= 1;
  }
  r->state = u128_add(u128_mul(r->state, acc_mult), acc_plus);
}

// ============================================================================
// Problem constants
// ============================================================================
#define S_LEN   16384
#define Q_LEN   65536
#define Q_TOT   327680     // 5*65536
#define DFEAT   256
#define MAXS    256
#define CAPS64  24576
#define CAPQ64  98304
#define TILE    4096
#define STILES  (S_LEN / TILE)    // 4
#define QTILES  (Q_TOT / TILE)    // 80
#define NBLK_C  (5 * STILES + 5 * QTILES)   // 420
#define MSHARDS 8
#define MPASSES 8
#define HTOT    (5 * S_LEN + 5 * Q_TOT)     // 1,720,320 words

// meta layout: [0..4]=ns_full, [5..9]=nq_full, [10..14]=na, [15..19]=nb

__constant__ int c_kshift[MPASSES] = {27, 23, 19, 15, 11, 7, 3, 0};

// ============================================================================
// KA (443 blocks x 256): independent work merged for concurrency.
//   blocks 0..419  : per-tile label match counts
//   blocks 420..429: PCG draw-stream generation
//   blocks 430..441: H-init to 0xFF (H aliases the Gram region, dead until
//                    k_gram overwrites it -- stream-ordered, race-free)
//   block  442     : zero the med-select buffers
// ============================================================================
__global__ __launch_bounds__(256) void kA(const int* __restrict__ ls,
                                          const int* __restrict__ lq,
                                          int* __restrict__ cnts,
                                          unsigned int* __restrict__ draws,
                                          unsigned int* __restrict__ Hbase,
                                          unsigned int* __restrict__ zbuf,
                                          int zwords) {
  int b = blockIdx.x; int tid = threadIdx.x;
  if (b < NBLK_C) {
    const int* src; int matchval;
    if (b < 5 * STILES) {
      int cls = b / STILES, tl = b % STILES;
      src = ls + cls * S_LEN + tl * TILE; matchval = 1;
    } else {
      int bb = b - 5 * STILES; int cls = bb / QTILES, tl = bb % QTILES;
      src = lq + tl * TILE; matchval = cls + 1;
    }
    int cnt = 0;
    for (int k = 0; k < TILE; k += 256) cnt += (src[k + tid] == matchval) ? 1 : 0;
    __shared__ int red[256];
    red[tid] = cnt; __syncthreads();
    for (int s = 128; s > 0; s >>= 1) { if (tid < s) red[tid] += red[tid + s]; __syncthreads(); }
    if (tid == 0) cnts[b] = red[0];
  } else if (b < NBLK_C + 10) {
    int t = b - NBLK_C; int cls = t % 5; int isq = t / 5;
    unsigned int seed = (unsigned)(1000 + isq * 1000 + cls + 1);
    unsigned long long cap64 = isq ? CAPQ64 : CAPS64;
    unsigned int* dst = draws + (isq ? (10ull * CAPS64 + (unsigned long long)cls * 2 * CAPQ64)
                                     : ((unsigned long long)cls * 2 * CAPS64));
    Pcg64 rng; pcg_seed(&rng, seed);
    unsigned long long C = cap64 / 256ull;     // 96 or 384
    unsigned long long k0 = (unsigned long long)tid * C;
    pcg_advance(&rng, k0);
    uint2* d2 = (uint2*)dst;
    for (unsigned long long m = 0; m < C; ++m) {
      unsigned long long o = pcg_next64(&rng);
      d2[k0 + m] = make_uint2((unsigned int)o, (unsigned int)(o >> 32));
    }
  } else if (b < NBLK_C + 22) {
    int hb = b - (NBLK_C + 10);                // 0..11
    for (int g = hb * 3072 * 48 + tid; ; g += 256) {
      int idx = g;
      if (idx >= (hb + 1) * 3072 * 48 || idx >= HTOT) break;
      Hbase[idx] = 0xFFFFFFFFu;
    }
  } else {
    for (int k = tid; k < zwords; k += 256) zbuf[k] = 0u;
  }
}

// ============================================================================
// K1b: tiny scan: exclusive offsets per class + meta totals
// ============================================================================
__global__ void k_scan(const int* __restrict__ cnts, int* __restrict__ offs,
                       int* __restrict__ meta) {
  int t = threadIdx.x;
  if (t < 5) {
    int base = 0;
    for (int k = 0; k < STILES; ++k) {
      offs[t * STILES + k] = base; base += cnts[t * STILES + k];
    }
    meta[t] = base;
    meta[10 + t] = base < MAXS ? base : MAXS;
  } else if (t < 10) {
    int c = t - 5; int base = 0;
    for (int k = 0; k < QTILES; ++k) {
      int idx = 5 * STILES + c * QTILES + k;
      offs[idx] = base; base += cnts[idx];
    }
    meta[5 + c] = base;
    meta[15 + c] = base < MAXS ? base : MAXS;
  }
}

// ============================================================================
// consume device body (R10 config: depth-8 pipeline + LDS J ring; 336 us)
// ============================================================================
__device__ __forceinline__ bool consume_chunk(unsigned int v, int& i, int n, int lane,
                                              unsigned long long lmask,
                                              unsigned long long lbit,
                                              unsigned int* __restrict__ ring) {
  unsigned long long rej = 0ull, acc = 0ull;
  for (;;) {
    unsigned long long unc = ~(rej | acc);
    int rbelow = __popcll(rej & lmask);
    int ubelow = __popcll(unc & lmask);
    int il_min = i - lane + rbelow;          // >= 193 always
    int il_max = il_min + ubelow;
    bool unres = (unc & lbit) != 0ull;
    unsigned int mlo = 0xFFFFFFFFu >> __clz(il_min);
    unsigned int mhi = 0xFFFFFFFFu >> __clz(il_max);
    unsigned int w = v & mlo;
    bool def_rej, hard;
    if (mlo == mhi) {
      def_rej = w > (unsigned int)il_max;
      hard = !def_rej && (w > (unsigned int)il_min);   // middle band
    } else if (ubelow == 0) {                // octave boundary: exact resolve
      def_rej = w > (unsigned int)il_min;
      hard = false;
    } else {
      def_rej = false;
      hard = true;                           // boundary-spanning, wait
    }
    def_rej = def_rej && unres;
    hard = hard && unres;
    unsigned long long nr = __ballot(def_rej);
    unsigned long long hd = __ballot(hard);
    rej |= nr;
    acc |= unc & ~nr & ~hd;
    if (!hd) break;
  }
  int rbelow = __popcll(rej & lmask);
  int il = i - lane + rbelow;
  int totAcc = 64 - __popcll(rej);
  if ((acc & lbit) && il >= MAXS) {
    int g = (n - 1) - il;
    ring[g & 4095] = v & (0xFFFFFFFFu >> __clz(il));
  }
  int needed = i - (MAXS - 1);
  if (totAcc >= needed) return true;
  i -= totAcc;
  return false;
}

__device__ void consume_body(int t, const int* __restrict__ meta,
                             const unsigned int* __restrict__ draws,
                             int* Jsup, int* Jqry,
                             unsigned int* __restrict__ ring) {
  int cls = t % 5; int isq = t / 5;
  int n = meta[isq * 5 + cls];
  if (n <= MAXS) return;
  const unsigned int* d = draws + (isq ? (10ull * CAPS64 + (unsigned long long)cls * 2 * CAPQ64)
                                       : ((unsigned long long)cls * 2 * CAPS64));
  int* J = isq ? (Jqry + (size_t)cls * Q_TOT) : (Jsup + cls * S_LEN);
  int lane = threadIdx.x;                    // 0..63 (wave 0 only)
  unsigned long long lmask = (1ull << lane) - 1ull;
  unsigned long long lbit  = (1ull << lane);
  int i = n - 1;
  size_t p = 0;
  int flushed = 0;
  const int cap = n - MAXS;                 // J entries with il in [256, n-1]
  unsigned int v0 = d[lane],       v1 = d[64 + lane];
  unsigned int v2 = d[128 + lane], v3 = d[192 + lane];
  unsigned int v4 = d[256 + lane], v5 = d[320 + lane];
  unsigned int v6 = d[384 + lane], v7 = d[448 + lane];
  for (;;) {
    unsigned int nv0 = d[p + 512 + lane];
    unsigned int nv1 = d[p + 576 + lane];
    unsigned int nv2 = d[p + 640 + lane];
    unsigned int nv3 = d[p + 704 + lane];
    unsigned int nv4 = d[p + 768 + lane];
    unsigned int nv5 = d[p + 832 + lane];
    unsigned int nv6 = d[p + 896 + lane];
    unsigned int nv7 = d[p + 960 + lane];
    bool done;
    if      (consume_chunk(v0, i, n, lane, lmask, lbit, ring)) done = true;
    else if (consume_chunk(v1, i, n, lane, lmask, lbit, ring)) done = true;
    else if (consume_chunk(v2, i, n, lane, lmask, lbit, ring)) done = true;
    else if (consume_chunk(v3, i, n, lane, lmask, lbit, ring)) done = true;
    else if (consume_chunk(v4, i, n, lane, lmask, lbit, ring)) done = true;
    else if (consume_chunk(v5, i, n, lane, lmask, lbit, ring)) done = true;
    else if (consume_chunk(v6, i, n, lane, lmask, lbit, ring)) done = true;
    else if (consume_chunk(v7, i, n, lane, lmask, lbit, ring)) done = true;
    else done = false;
    if (done) break;
    // flush full 2048-entry blocks (coalesced descending J, fire-and-forget)
    int avail = (n - 1) - i; if (avail > cap) avail = cap;
    while (avail - flushed >= 2048) {
      #pragma unroll
      for (int k = 0; k < 32; ++k) {
        int g = flushed + k * 64 + lane;
        J[(n - 1) - g] = (int)ring[g & 4095];
      }
      flushed += 2048;
    }
    p += 512;
    v0 = nv0; v1 = nv1; v2 = nv2; v3 = nv3;
    v4 = nv4; v5 = nv5; v6 = nv6; v7 = nv7;
  }
  // final flush: every il in [256, n-1] has been staged
  for (int g = flushed + lane; g < cap; g += 64)
    J[(n - 1) - g] = (int)ring[g & 4095];
}

// ============================================================================
// KB (430 blocks x 256): independent work merged for concurrency.
//   blocks 0..419  : stable compaction write (needs offs only)
//   blocks 420..429: consume automaton, wave 0 only (needs meta + draws only)
// ============================================================================
__global__ __launch_bounds__(256) void kB(const int* __restrict__ ls,
                                          const int* __restrict__ lq,
                                          const int* __restrict__ offs,
                                          const int* __restrict__ meta,
                                          const unsigned int* __restrict__ draws,
                                          int* __restrict__ sup_list,
                                          int* __restrict__ qry_list,
                                          int* __restrict__ Jsup,
                                          int* __restrict__ Jqry) {
  __shared__ unsigned int ring[4096];   // used by consume blocks only
  __shared__ int wcnt[4];               // used by write blocks only
  int b = blockIdx.x; int tid = threadIdx.x;
  if (b < NBLK_C) {
    const int* src; int matchval; int* out; int ibase;
    if (b < 5 * STILES) {
      int cls = b / STILES, tl = b % STILES;
      src = ls + cls * S_LEN + tl * TILE; matchval = 1;
      out = sup_list + cls * S_LEN; ibase = tl * TILE;
    } else {
      int bb = b - 5 * STILES; int cls = bb / QTILES, tl = bb % QTILES;
      src = lq + tl * TILE; matchval = cls + 1;
      out = qry_list + (size_t)cls * Q_TOT; ibase = tl * TILE;
    }
    int w = tid >> 6, lane = tid & 63;
    unsigned long long lmask = (1ull << lane) - 1ull;
    int base = offs[b];
    for (int k = 0; k < TILE; k += 256) {
      int i = k + tid;
      bool p = (src[i] == matchval);
      unsigned long long m = __ballot(p);
      if (lane == 0) wcnt[w] = __popcll(m);
      __syncthreads();
      int prev = 0;
      #pragma unroll
      for (int ww = 0; ww < 4; ++ww) prev += (ww < w) ? wcnt[ww] : 0;
      int tot = wcnt[0] + wcnt[1] + wcnt[2] + wcnt[3];
      if (p) out[base + prev + __popcll(m & lmask)] = ibase + i;
      __syncthreads();
      base += tot;
    }
  } else {
    if (tid >= 64) return;               // wave 0 only; no __syncthreads below
    consume_body(b - NBLK_C, meta, draws, Jsup, Jqry, ring);
  }
}

// ============================================================================
// K3a: next-hitter index fill.  H[v] = min{ i > v, i in [256,n) : J[i] == v }
// ============================================================================
__global__ __launch_bounds__(256) void k_hfill(const int* __restrict__ meta,
                                               const int* __restrict__ Jsup,
                                               const int* __restrict__ Jqry,
                                               unsigned int* __restrict__ Hsup,
                                               unsigned int* __restrict__ Hqry) {
  const int SB = 5 * (S_LEN / 256);
  int b = blockIdx.x;
  int cls, i; const int* J; unsigned int* H; int n;
  if (b < SB) {
    cls = b / (S_LEN / 256);
    i = (b % (S_LEN / 256)) * 256 + threadIdx.x;
    n = meta[cls];
    J = Jsup + cls * S_LEN; H = Hsup + cls * S_LEN;
  } else {
    b -= SB;
    cls = b / (Q_TOT / 256);
    i = (b % (Q_TOT / 256)) * 256 + threadIdx.x;
    n = meta[5 + cls];
    J = Jqry + (size_t)cls * Q_TOT; H = Hqry + (size_t)cls * Q_TOT;
  }
  if (i < MAXS || i >= n) return;
  int j = J[i];
  if (j != i) atomicMin(&H[j], (unsigned int)i);
}

// ============================================================================
// K4: gather + fused chase + fused row-norm (verified in R13).
// ============================================================================
__global__ __launch_bounds__(256) void k_gather(const float* __restrict__ f_s,
                                                const float* __restrict__ f_q,
                                                const int* __restrict__ meta,
                                                const int* __restrict__ sup_list,
                                                const int* __restrict__ qry_list,
                                                const unsigned int* __restrict__ Hsup,
                                                const unsigned int* __restrict__ Hqry,
                                                float* xa, float* xb) {
  int blk = blockIdx.x;
  int t = blk >> 3;          // class-pair 0..9
  int slab = blk & 7;        // 8 slabs x 32 rows
  int cls = t % 5; int isq = t / 5;
  int nfull = meta[isq * 5 + cls];
  int n = meta[10 + isq * 5 + cls];
  int tid = threadIdx.x;
  int row = slab * 32 + (tid >> 3);
  int dg = tid & 7;          // 8 d-groups of 32
  if (row >= n) return;      // group-uniform (8 lanes share row)
  const int* list; const unsigned int* H;
  if (!isq) { list = sup_list + cls * S_LEN; H = Hsup + cls * S_LEN; }
  else      { list = qry_list + (size_t)cls * Q_TOT; H = Hqry + (size_t)cls * Q_TOT; }
  unsigned int v = (unsigned int)row;
  if (nfull > MAXS) {
    unsigned int h = H[v];
    while (h != 0xFFFFFFFFu) { v = h; h = H[v]; }
  }
  int id = list[v];
  const float* src; size_t stride; float* dst;
  if (!isq) {
    src = f_s + (size_t)cls * DFEAT * S_LEN + id; stride = S_LEN;
    dst = xa + cls * (MAXS * DFEAT) + row * DFEAT;
  } else {
    int m = id >> 16; int nn = id & 0xFFFF;
    src = f_q + (size_t)m * DFEAT * Q_LEN + nn; stride = Q_LEN;
    dst = xb + cls * (MAXS * DFEAT) + row * DFEAT;
  }
  float vv[32];
  #pragma unroll
  for (int dd = 0; dd < 32; ++dd)
    vv[dd] = src[(size_t)(dg * 32 + dd) * stride];
  float ss = 0.f;
  #pragma unroll
  for (int dd = 0; dd < 32; ++dd) ss += vv[dd] * vv[dd];
  ss += __shfl_xor(ss, 1);
  ss += __shfl_xor(ss, 2);
  ss += __shfl_xor(ss, 4);
  float inv = 1.0f / (sqrtf(ss) + 1e-12f);
  #pragma unroll
  for (int dd = 0; dd < 32; ++dd) dst[dg * 32 + dd] = vv[dd] * inv;
}

// ============================================================================
// K5: 35 Gram matrices (256x256, K=256), 128x128 tiles -> 140 blocks,
//     fused diag extraction (verified in R13).
// ============================================================================
__global__ __launch_bounds__(256) void k_gram(const float* __restrict__ xa,
                                              const float* __restrict__ xb,
                                              float* Ga, float* Gb, float* Gab,
                                              float* diagA, float* diagB) {
  int b = blockIdx.x;
  int j = b >> 2; int tile = b & 3;
  int tr = (tile >> 1) * 128, tc = (tile & 1) * 128;
  const float *A, *B; float* G;
  if (j < 5)       { A = xa + j * 65536; B = A; G = Ga + j * 65536; }
  else if (j < 10) { int c = j - 5; A = xb + c * 65536; B = A; G = Gb + c * 65536; }
  else             { int p = j - 10; int k = p / 5, c = p % 5;
                     A = xa + k * 65536; B = xb + c * 65536; G = Gab + p * 65536; }
  __shared__ float As[128][33];
  __shared__ float Bs[128][33];
  int tid = threadIdx.x;
  int w = tid >> 6, lane = tid & 63;
  int wr = w >> 1, wc = w & 1;
  int lr = lane >> 3, lc = lane & 7;
  int orow = wr * 64 + lr * 8;
  int ocol = wc * 64 + lc * 8;
  float acc[8][8];
  #pragma unroll
  for (int r = 0; r < 8; ++r)
    #pragma unroll
    for (int s = 0; s < 8; ++s) acc[r][s] = 0.f;

  for (int k0 = 0; k0 < 256; k0 += 32) {
    #pragma unroll
    for (int e = 0; e < 4; ++e) {
      int idx = tid + e * 256;
      int row = idx >> 3;
      int c4  = idx & 7;
      float4 va = *(const float4*)(A + (size_t)(tr + row) * 256 + k0 + c4 * 4);
      As[row][c4 * 4 + 0] = va.x; As[row][c4 * 4 + 1] = va.y;
      As[row][c4 * 4 + 2] = va.z; As[row][c4 * 4 + 3] = va.w;
      float4 vb = *(const float4*)(B + (size_t)(tc + row) * 256 + k0 + c4 * 4);
      Bs[row][c4 * 4 + 0] = vb.x; Bs[row][c4 * 4 + 1] = vb.y;
      Bs[row][c4 * 4 + 2] = vb.z; Bs[row][c4 * 4 + 3] = vb.w;
    }
    __syncthreads();
    #pragma unroll 4
    for (int kk = 0; kk < 32; ++kk) {
      float a[8], bv[8];
      #pragma unroll
      for (int r = 0; r < 8; ++r) a[r] = As[orow + r][kk];
      #pragma unroll
      for (int s = 0; s < 8; ++s) bv[s] = Bs[ocol + s][kk];
      #pragma unroll
      for (int r = 0; r < 8; ++r)
        #pragma unroll
        for (int s = 0; s < 8; ++s) acc[r][s] += a[r] * bv[s];
    }
    __syncthreads();
  }
  #pragma unroll
  for (int r = 0; r < 8; ++r) {
    float* grow = G + (size_t)(tr + orow + r) * 256 + tc + ocol;
    *(float4*)(grow + 0) = make_float4(acc[r][0], acc[r][1], acc[r][2], acc[r][3]);
    *(float4*)(grow + 4) = make_float4(acc[r][4], acc[r][5], acc[r][6], acc[r][7]);
  }
  // fused diag extraction (squared norms) for self-Gram matrices
  if (j < 10 && tr == tc) {
    #pragma unroll
    for (int r = 0; r < 8; ++r)
      #pragma unroll
      for (int s = 0; s < 8; ++s) {
        int gr = orow + r, gc = ocol + s;
        if (gr == gc) {
          int gi = tr + gr;
          if (j < 5) diagA[j * 256 + gi] = acc[r][s];
          else       diagB[(j - 5) * 256 + gi] = acc[r][s];
        }
      }
  }
}

// ============================================================================
// K7: G -> D in place (280 blocks: 35 matrices x 8 row-slabs)
// ============================================================================
__global__ __launch_bounds__(256) void k_conv(float* Ga, float* Gb, float* Gab,
                                              const float* __restrict__ diagA,
                                              const float* __restrict__ diagB) {
  int b = blockIdx.x; int j = b >> 3; int slab = b & 7; int tid = threadIdx.x;
  float* G; const float *dA, *dB;
  if (j < 5)       { G = Ga + j * 65536; dA = diagA + j * 256; dB = dA; }
  else if (j < 10) { int c = j - 5; G = Gb + c * 65536; dA = diagB + c * 256; dB = dA; }
  else             { int p = j - 10; int k = p / 5, c = p % 5;
                     G = Gab + p * 65536; dA = diagA + k * 256; dB = diagB + c * 256; }
  float db = dB[tid];
  for (int i = slab * 32; i < slab * 32 + 32; ++i) {
    float g = G[i * 256 + tid];
    float d = dA[i] + db - 2.0f * g;
    G[i * 256 + tid] = d > 0.f ? d : 0.f;
  }
}

// ============================================================================
// K8: grid-parallel 16-ary exact radix-select, one kernel per pass.
// ============================================================================
__device__ __forceinline__ void med_select(const unsigned int* __restrict__ c,
                                           unsigned int lprev, unsigned int bprev,
                                           unsigned int r, int kprev,
                                           unsigned int* lo, unsigned int* base) {
  int j = 15;
  #pragma unroll
  for (int q = 14; q >= 0; --q)
    if (bprev + c[q] > r) j = q;
  *lo = lprev + ((unsigned int)j << kprev);
  *base = (j == 0) ? bprev : bprev + c[j - 1];
}

__global__ __launch_bounds__(256) void k_medpass(int t,
                                                 const int* __restrict__ meta,
                                                 const float* __restrict__ Da_all,
                                                 const float* __restrict__ Db_all,
                                                 const float* __restrict__ Dab_all,
                                                 unsigned int* __restrict__ bufAll,  // [MPASSES][25][16]
                                                 unsigned int* __restrict__ loArr,   // [MPASSES][25]
                                                 unsigned int* __restrict__ baseArr, // [MPASSES][25]
                                                 unsigned int* __restrict__ zcArr) { // [25]
  int b = blockIdx.x;
  int p = b / MSHARDS, sh = b % MSHARDS;
  int kcl = p / 5, ccl = p % 5;
  int tid = threadIdx.x;
  int nsf = meta[kcl], nqf = meta[5 + ccl];
  if (nsf < 2 || nqf < 2) return;
  int na = meta[10 + kcl], nb = meta[15 + ccl];
  const float4* A4 = (const float4*)(Da_all + kcl * 65536);
  const float4* B4 = (const float4*)(Db_all + ccl * 65536);
  const float4* C4 = (const float4*)(Dab_all + p * 65536);

  __shared__ unsigned int sh_lo[1], sh_base[1];
  __shared__ unsigned int wred[4][16];
  __shared__ unsigned int wzc[4];

  int ks = c_kshift[t];
  unsigned int N = (unsigned int)(na + nb) * (unsigned int)(na + nb);

  if (tid == 0) {
    unsigned int lo = 0, base = 0;
    if (t > 0) {
      unsigned int nz = zcArr[p];
      if (nz < N) {
        unsigned int r = nz + (N - nz - 1u) / 2u;
        unsigned int cprev[15];
        const unsigned int* cp = bufAll + ((size_t)(t - 1) * 25 + p) * 16;
        #pragma unroll
        for (int q = 0; q < 15; ++q) cprev[q] = cp[q];
        med_select(cprev, loArr[(t - 1) * 25 + p], baseArr[(t - 1) * 25 + p],
                   r, c_kshift[t - 1], &lo, &base);
      }
    }
    sh_lo[0] = lo; sh_base[0] = base;
    if (sh == 0) { loArr[t * 25 + p] = lo; baseArr[t * 25 + p] = base; }
  }
  __syncthreads();
  unsigned int lo = sh_lo[0];

  unsigned int cnt[15];
  #pragma unroll
  for (int j = 0; j < 15; ++j) cnt[j] = 0;
  unsigned int zc = 0;
  unsigned int span = 16u << ks;   // ks<=27 -> fits u32 (16<<27 = 2^31)

  #define PROC_MAT(M4, nr, nc, W)                                             \
    for (int m = 0; m < 8; ++m) {                                             \
      int fidx = sh * 2048 + m * 256 + tid;                                   \
      float4 v = M4[fidx];                                                    \
      int row = fidx >> 6; int col0 = (fidx & 63) << 2;                       \
      unsigned int kb[4] = {__float_as_uint(v.x), __float_as_uint(v.y),       \
                            __float_as_uint(v.z), __float_as_uint(v.w)};      \
      _Pragma("unroll")                                                       \
      for (int cc = 0; cc < 4; ++cc) {                                        \
        bool valid = (row < (nr)) && (col0 + cc < (nc));                      \
        unsigned int key = kb[cc];                                            \
        if (t == 0) zc += (valid && key == 0u) ? (W) : 0u;                    \
        unsigned int d = key - lo;                                            \
        bool in = valid && (key >= lo) && (d < span);                         \
        _Pragma("unroll")                                                     \
        for (int j = 0; j < 15; ++j)                                          \
          cnt[j] += (in && d < ((unsigned int)(j + 1) << ks)) ? (W) : 0u;     \
      }                                                                       \
    }

  PROC_MAT(A4, na, na, 1u)
  PROC_MAT(B4, nb, nb, 1u)
  PROC_MAT(C4, na, nb, 2u)
  #undef PROC_MAT

  // wave-level reduce then cross-wave
  #pragma unroll
  for (int j = 0; j < 15; ++j)
    for (int o = 32; o > 0; o >>= 1) cnt[j] += __shfl_down(cnt[j], o);
  if (t == 0)
    for (int o = 32; o > 0; o >>= 1) zc += __shfl_down(zc, o);
  int w = tid >> 6, lane = tid & 63;
  if (lane == 0) {
    #pragma unroll
    for (int j = 0; j < 15; ++j) wred[w][j] = cnt[j];
    wzc[w] = zc;
  }
  __syncthreads();
  if (tid < 15) {
    unsigned int s = wred[0][tid] + wred[1][tid] + wred[2][tid] + wred[3][tid];
    atomicAdd(&bufAll[((size_t)t * 25 + p) * 16 + tid], s);
  }
  if (t == 0 && tid == 15) {
    unsigned int s = wzc[0] + wzc[1] + wzc[2] + wzc[3];
    atomicAdd(&zcArr[p], s);
  }
}

// ============================================================================
// K8b: RBF partial sums (200 blocks), sigma from final select
// ============================================================================
__global__ __launch_bounds__(256) void k_rbf(const int* __restrict__ meta,
                                             const float* __restrict__ Da_all,
                                             const float* __restrict__ Db_all,
                                             const float* __restrict__ Dab_all,
                                             const unsigned int* __restrict__ bufAll,
                                             const unsigned int* __restrict__ loArr,
                                             const unsigned int* __restrict__ baseArr,
                                             const unsigned int* __restrict__ zcArr,
                                             double* __restrict__ mmdsum) { // [25][3]
  int b = blockIdx.x;
  int p = b / MSHARDS, sh = b % MSHARDS;
  int kcl = p / 5, ccl = p % 5;
  int tid = threadIdx.x;
  int nsf = meta[kcl], nqf = meta[5 + ccl];
  if (nsf < 2 || nqf < 2) return;
  int na = meta[10 + kcl], nb = meta[15 + ccl];
  const float4* A4 = (const float4*)(Da_all + kcl * 65536);
  const float4* B4 = (const float4*)(Db_all + ccl * 65536);
  const float4* C4 = (const float4*)(Dab_all + p * 65536);

  unsigned int N = (unsigned int)(na + nb) * (unsigned int)(na + nb);
  unsigned int nz = zcArr[p];
  float base_s;
  if (nz >= N) base_s = 1.0f;
  else {
    unsigned int r = nz + (N - nz - 1u) / 2u;
    unsigned int cprev[15];
    const unsigned int* cp = bufAll + ((size_t)(MPASSES - 1) * 25 + p) * 16;
    #pragma unroll
    for (int q = 0; q < 15; ++q) cprev[q] = cp[q];
    unsigned int lo, bs;
    med_select(cprev, loArr[(MPASSES - 1) * 25 + p], baseArr[(MPASSES - 1) * 25 + p],
               r, 0, &lo, &bs);
    base_s = sqrtf(__uint_as_float(lo) + 1e-6f);
  }
  float g2 = base_s * base_s;
  float c0 = 1.0f / (2.0f * g2 * 0.25f);
  float c1 = 1.0f / (2.0f * g2 * 1.0f);
  float c2 = 1.0f / (2.0f * g2 * 4.0f);
  float c3 = 1.0f / (2.0f * g2 * 16.0f);

  double accA = 0.0, accB = 0.0, accAB = 0.0;
  #define RBF_MAT(M4, nr, nc, ACC)                                            \
    for (int m = 0; m < 8; ++m) {                                             \
      int fidx = sh * 2048 + m * 256 + tid;                                   \
      float4 v = M4[fidx];                                                    \
      int row = fidx >> 6; int col0 = (fidx & 63) << 2;                       \
      float vv[4] = {v.x, v.y, v.z, v.w};                                     \
      _Pragma("unroll")                                                       \
      for (int cc = 0; cc < 4; ++cc) {                                        \
        if ((row < (nr)) && (col0 + cc < (nc))) {                             \
          float d = vv[cc];                                                   \
          ACC += (double)(expf(-d * c0) + expf(-d * c1)                       \
                        + expf(-d * c2) + expf(-d * c3));                     \
        }                                                                     \
      }                                                                       \
    }
  RBF_MAT(A4, na, na, accA)
  RBF_MAT(B4, nb, nb, accB)
  RBF_MAT(C4, na, nb, accAB)
  #undef RBF_MAT

  for (int o = 32; o > 0; o >>= 1) {
    accA += __shfl_down(accA, o);
    accB += __shfl_down(accB, o);
    accAB += __shfl_down(accAB, o);
  }
  __shared__ double wsum[4][3];
  int w = tid >> 6, lane = tid & 63;
  if (lane == 0) { wsum[w][0] = accA; wsum[w][1] = accB; wsum[w][2] = accAB; }
  __syncthreads();
  if (tid == 0) {
    double sA = wsum[0][0] + wsum[1][0] + wsum[2][0] + wsum[3][0];
    double sB = wsum[0][1] + wsum[1][1] + wsum[2][1] + wsum[3][1];
    double sC = wsum[0][2] + wsum[1][2] + wsum[2][2] + wsum[3][2];
    atomicAdd(&mmdsum[p * 3 + 0], sA);
    atomicAdd(&mmdsum[p * 3 + 1], sB);
    atomicAdd(&mmdsum[p * 3 + 2], sC);
  }
}

// ============================================================================
// K9: final weighted loss (mmd assembled from sums)
// ============================================================================
__global__ void k_final(const int* __restrict__ meta, const double* __restrict__ mmdsum,
                        float* out) {
  if (threadIdx.x != 0 || blockIdx.x != 0) return;
  double total = 0.0, vw = 0.0;
  for (int c = 0; c < 5; ++c) {
    int nsf = meta[c], nqf = meta[5 + c];
    if (nsf < 2 || nqf < 2) continue;
    int nbq = meta[15 + c];
    double mm[5];
    for (int k = 0; k < 5; ++k) {
      if (meta[k] < 2) { mm[k] = 0.0; continue; }
      int naa = meta[10 + k];
      int pp = k * 5 + c;
      double meanA  = mmdsum[pp * 3 + 0] / ((double)naa * (double)naa);
      double meanB  = mmdsum[pp * 3 + 1] / ((double)nbq * (double)nbq);
      double meanAB = mmdsum[pp * 3 + 2] / ((double)naa * (double)nbq);
      double m = meanA + meanB - 2.0 * meanAB;
      mm[k] = m > 0.0 ? m : 0.0;
    }
    double pos = mm[c];
    bool any = false; double best = 0.0;
    for (int k = 0; k < 5; ++k) {
      if (k == c || meta[k] < 2) continue;
      if (!any || mm[k] < best) { best = mm[k]; any = true; }
    }
    double lc = any ? fmax(pos - best + 0.1, 0.0) : pos;
    double w = sqrt((double)nsf * (double)nqf);
    total += w * lc; vw += w;
  }
  out[0] = (float)(0.1 * total / fmax(vw, 1e-12));
}

// ============================================================================
// host launcher
// ============================================================================
extern "C" void kernel_launch(void* const* d_in, const int* in_sizes, int n_in,
                              void* d_out, int out_size, void* d_ws, size_t ws_size,
                              hipStream_t stream) {
  const float* f_s = (const float*)d_in[0];
  const int*   l_s = (const int*)d_in[1];
  const float* f_q = (const float*)d_in[2];
  const int*   l_q = (const int*)d_in[3];
  float* out = (float*)d_out;
  char* ws = (char*)d_ws;

  size_t off = 0;
  auto take = [&](size_t bytes) -> void* {
    void* p = ws + off;
    off = (off + bytes + 255) & ~(size_t)255;
    return p;
  };
  int*   meta     = (int*)take(32 * 4);
  int*   cnts     = (int*)take(NBLK_C * 4);
  int*   offs     = (int*)take(NBLK_C * 4);
  int*   sup_list = (int*)take((size_t)5 * S_LEN * 4);
  int*   qry_list = (int*)take((size_t)5 * Q_TOT * 4);
  int*   Jsup     = (int*)take((size_t)5 * S_LEN * 4);
  int*   Jqry     = (int*)take((size_t)5 * Q_TOT * 4);
  unsigned int* draws = (unsigned int*)take((10ull * CAPS64 + 10ull * CAPQ64) * 4);
  float* xa       = (float*)take((size_t)5 * 65536 * 4);
  float* xb       = (float*)take((size_t)5 * 65536 * 4);
  float* Ga       = (float*)take((size_t)5 * 65536 * 4);   // G region also hosts H
  float* Gb       = (float*)take((size_t)5 * 65536 * 4);   // (contiguous, 256B-mult sizes)
  float* Gab      = (float*)take((size_t)25 * 65536 * 4);
  float* diagA    = (float*)take((size_t)5 * 256 * 4);
  float* diagB    = (float*)take((size_t)5 * 256 * 4);
  size_t zero0 = off;
  unsigned int* bufAll  = (unsigned int*)take((size_t)MPASSES * 25 * 16 * 4);
  unsigned int* loArr   = (unsigned int*)take((size_t)MPASSES * 25 * 4);
  unsigned int* baseArr = (unsigned int*)take((size_t)MPASSES * 25 * 4);
  unsigned int* zcArr   = (unsigned int*)take(25 * 4);
  double* mmdsum  = (double*)take(25 * 3 * 8);
  size_t zero1 = off;
  if (off > ws_size) return;

  // H (next-hitter) arrays alias the GRAM region (dead until k_gram writes it;
  // H itself is dead after k_gather's chase) -- 6.88 MB <= 9.17 MB available.
  unsigned int* Hsup = (unsigned int*)Ga;
  unsigned int* Hqry = ((unsigned int*)Ga) + (size_t)5 * S_LEN;
  unsigned int* zbuf = (unsigned int*)(ws + zero0);
  int zwords = (int)((zero1 - zero0) / 4);

  kA<<<NBLK_C + 23, 256, 0, stream>>>(l_s, l_q, cnts, draws,
                                      (unsigned int*)Ga, zbuf, zwords);
  k_scan<<<1, 64, 0, stream>>>(cnts, offs, meta);
  kB<<<NBLK_C + 10, 256, 0, stream>>>(l_s, l_q, offs, meta, draws,
                                      sup_list, qry_list, Jsup, Jqry);
  {
    int nblk = 5 * (S_LEN / 256) + 5 * (Q_TOT / 256);   // 320 + 6400
    k_hfill<<<nblk, 256, 0, stream>>>(meta, Jsup, Jqry, Hsup, Hqry);
  }
  k_gather<<<80, 256, 0, stream>>>(f_s, f_q, meta, sup_list, qry_list,
                                   Hsup, Hqry, xa, xb);
  k_gram<<<140, 256, 0, stream>>>(xa, xb, Ga, Gb, Gab, diagA, diagB);
  k_conv<<<280, 256, 0, stream>>>(Ga, Gb, Gab, diagA, diagB);
  for (int t = 0; t < MPASSES; ++t)
    k_medpass<<<25 * MSHARDS, 256, 0, stream>>>(t, meta, Ga, Gb, Gab,
                                                bufAll, loArr, baseArr, zcArr);
  k_rbf<<<25 * MSHARDS, 256, 0, stream>>>(meta, Ga, Gb, Gab,
                                          bufAll, loArr, baseArr, zcArr, mmdsum);
  k_final<<<1, 64, 0, stream>>>(meta, mmdsum, out);
}